// Round 5
// baseline (2384.978 us; speedup 1.0000x reference)
//
#include <hip/hip_runtime.h>
#include <hip/hip_bf16.h>

#define TLEN 16000
#define NPSI 36
#define NBATCH 64
#define NOUT 250
#define NCH 37
#define DHALF 176            // Gaussian lowpass half-width (6.05 sigma, sigma_t=29.1)
#define CBMAX 3264           // max band width (5 sigma of filter 0 = 3233)
#define KMAX 8000
#define TWO_PI 6.283185307179586
#define CN1 12               // n1-columns per chunk in k_scatter
#define NCHUNK 11            // ceil(125/12)

__device__ __forceinline__ int brev7(int q){ return (int)(__brev((unsigned)q) >> 25); }

// ---- K1 (fused): forward 16000-pt FFT per batch, emit k<8000 -------------
// n = 128*n1 + n2, k = m + 125*j.  X[k] = sum_n2 W128^{j n2} [ W16000^{m n2}
// * sum_n1 x[128 n1 + n2] W125^{m n1} ]   (all forward/minus sign)
// Verified on-device (round-4 probe A: direct-DFT match at k=777, 5601).
__global__ __launch_bounds__(256) void k_fft(const float* __restrict__ x,
                                             float2* __restrict__ Xf){
    __shared__ float xs[32 * 125];            // 16.0 KB
    __shared__ float ar_[128 * 25];           // 12.8 KB
    __shared__ float ai_[128 * 25];           // 12.8 KB
    __shared__ float w125r[125], w125i[125];
    __shared__ float w16r[125],  w16i[125];
    __shared__ float w128r[128], w128i[128];
    const int b = blockIdx.x, tid = threadIdx.x;

    for (int j = tid; j < 125; j += 256){
        double a = -TWO_PI * (double)j / 125.0;
        w125r[j] = (float)cos(a); w125i[j] = (float)sin(a);
        double a2 = -TWO_PI * (double)j / 16000.0;
        w16r[j] = (float)cos(a2); w16i[j] = (float)sin(a2);
    }
    for (int j = tid; j < 128; j += 256){
        double a = -TWO_PI * (double)j / 128.0;
        w128r[j] = (float)cos(a); w128i[j] = (float)sin(a);
    }
    for (int mc = 0; mc < 5; ++mc){
        const int m0 = mc * 25;
        for (int g = 0; g < 4; ++g){
            __syncthreads();                  // tables ready / xs reuse / ar_ consumed
            for (int i = tid; i < 32 * 125; i += 256){
                int n1 = i / 32, lr = i % 32;
                xs[lr * 125 + n1] = x[b * TLEN + 128 * n1 + g * 32 + lr];
            }
            __syncthreads();
            for (int i = tid; i < 32 * 25; i += 256){
                int ml = i / 32, lr = i % 32;
                int m = m0 + ml, n2 = g * 32 + lr;
                const float* xr = &xs[lr * 125];
                float ar = 0.0f, ai = 0.0f;
                int jj = 0;
                for (int n1 = 0; n1 < 125; ++n1){
                    float xv = xr[n1];
                    ar += xv * w125r[jj]; ai += xv * w125i[jj];
                    jj += m; if (jj >= 125) jj -= 125;
                }
                int a = n2 * m;               // <= 15748 = 125*q + r2, q <= 125
                int q = a / 125, r2 = a - q * 125;
                float tr = w16r[r2] * w128r[q] - w16i[r2] * w128i[q];
                float ti = w16r[r2] * w128i[q] + w16i[r2] * w128r[q];
                ar_[n2 * 25 + ml] = ar * tr - ai * ti;
                ai_[n2 * 25 + ml] = ar * ti + ai * tr;
            }
        }
        __syncthreads();                      // ar_ complete for all n2
        for (int i = tid; i < 25 * 64; i += 256){
            int ml = i / 64, j = i % 64;
            float Ar = 0.0f, Ai = 0.0f;
            int jj = 0;
            for (int n2 = 0; n2 < 128; ++n2){
                float wr = w128r[jj], wi = w128i[jj];
                float cr = ar_[n2 * 25 + ml], ci = ai_[n2 * 25 + ml];
                Ar += cr * wr - ci * wi;
                Ai += cr * wi + ci * wr;
                jj += j; jj &= 127;
            }
            Xf[(size_t)b * KMAX + (m0 + ml) + 125 * j] = make_float2(Ar, Ai);
        }
    }
}

// ---- K2: per (b,filter): band-sparse inverse FFT -> |z| -> Gaussian conv
__global__ __launch_bounds__(256) void k_scatter(const float2* __restrict__ Xf,
                                                 float* __restrict__ Schan){
    __shared__ float Br[128 * CN1], Bi[128 * CN1];      // 12.3 KB
    __shared__ float ps[CBMAX];                         // 13.1 KB
    __shared__ float w125r[125], w125i[125];            // e^{+2pi i j/125}
    __shared__ float w128r[128], w128i[128];            // e^{+2pi i j/128}
    __shared__ float w16r[125],  w16i[125];             // e^{+2pi i j/16000}
    __shared__ float hwin[DHALF + 1];
    __shared__ float Sacc[NOUT];

    const int blk = blockIdx.x;
    const int fi = blk % NPSI;
    const int b = blk / NPSI;
    const int tid = threadIdx.x;
    const float2* __restrict__ Xfb = Xf + (size_t)b * KMAX;

    const double xi_d = 0.35 * exp2(-(double)fi / 6.0);
    const double r_d  = exp2(1.0 / 6.0);
    const double sig_d = xi_d * (r_d - 1.0) / (r_d + 1.0);
    const float xi = (float)xi_d;
    const float centerT = (float)(xi_d * (double)TLEN);
    const float sigT = (float)(sig_d * (double)TLEN);
    int klo = (int)floorf(centerT - 5.0f * sigT); if (klo < 1) klo = 1;
    int khi = (int)ceilf(centerT + 5.0f * sigT);  if (khi > KMAX - 1) khi = KMAX - 1;
    if (khi - klo + 1 > CBMAX) khi = klo + CBMAX - 1;
    const int W = khi - klo + 1;
    const float inv2s2 = (float)(1.0 / (2.0 * sig_d * sig_d));

    for (int j = tid; j < 125; j += 256){
        double a = TWO_PI * (double)j / 125.0;
        w125r[j] = (float)cos(a); w125i[j] = (float)sin(a);
        double a2 = TWO_PI * (double)j / 16000.0;
        w16r[j] = (float)cos(a2); w16i[j] = (float)sin(a2);
    }
    for (int j = tid; j < 128; j += 256){
        double a = TWO_PI * (double)j / 128.0;
        w128r[j] = (float)cos(a); w128i[j] = (float)sin(a);
    }
    for (int j = tid; j <= DHALF; j += 256){
        double st = 1.0 / (TWO_PI * (0.35 / 64.0));
        hwin[j] = (float)((0.35 / 64.0) * sqrt(TWO_PI) * exp(-0.5 * (double)(j * j) / (st * st)));
    }
    if (tid < NOUT) Sacc[tid] = 0.0f;
    for (int idx = tid; idx < W; idx += 256){
        int k = klo + idx;
        float fr = (float)k * (1.0f / (float)TLEN);
        float d = fr - xi;
        ps[idx] = expf(-d * d * inv2s2) * (1.0f / (float)TLEN);
    }
    __syncthreads();

    for (int cc = 0; cc < NCHUNK; ++cc){
        // step 1: sparse gather over k1 (W125^+), fused k2*n1 twiddle
        for (int idx = tid; idx < 128 * CN1; idx += 256){
            int k2 = idx / CN1, col = idx % CN1;
            int n1 = cc * CN1 + col;
            float outr = 0.0f, outi = 0.0f;
            if (n1 < 125){
                int k1min = (klo - k2 + 127) >> 7;
                int k1max = (khi - k2) >> 7;
                float ar = 0.0f, ai = 0.0f;
                int jj = (k1min * n1) % 125;
                int k = k2 + (k1min << 7);
                for (int k1 = k1min; k1 <= k1max; ++k1){
                    float wr = w125r[jj], wi = w125i[jj];
                    float2 Xv = Xfb[k];
                    float p = ps[k - klo];
                    float cr = Xv.x * p, ci = Xv.y * p;
                    ar += cr * wr - ci * wi;
                    ai += cr * wi + ci * wr;
                    jj += n1; if (jj >= 125) jj -= 125;
                    k += 128;
                }
                int a = k2 * n1;
                int q = a / 125, r2 = a - q * 125;
                float tr = w16r[r2] * w128r[q] - w16i[r2] * w128i[q];
                float ti = w16r[r2] * w128i[q] + w16i[r2] * w128r[q];
                outr = ar * tr - ai * ti;
                outi = ar * ti + ai * tr;
            }
            Br[idx] = outr; Bi[idx] = outi;
        }
        // 128-pt radix-2 DIF (inverse sign) over k2, per column
        for (int span = 64; span >= 1; span >>= 1){
            __syncthreads();
            for (int idx = tid; idx < 64 * CN1; idx += 256){
                int u = idx / CN1, col = idx % CN1;
                int blkq = u / span, mm = u % span;
                int p0 = blkq * 2 * span + mm;
                int i0 = p0 * CN1 + col, i1 = i0 + span * CN1;
                float ar = Br[i0], ai = Bi[i0], br = Br[i1], bi = Bi[i1];
                Br[i0] = ar + br; Bi[i0] = ai + bi;
                float dr = ar - br, di = ai - bi;
                int jt = mm * (64 / span);
                Br[i1] = dr * w128r[jt] - di * w128i[jt];
                Bi[i1] = dr * w128i[jt] + di * w128r[jt];
            }
        }
        __syncthreads();
        // |z| -> accumulate Gaussian taps.  n = n1 + 125*brev7(p)
        for (int idx = tid; idx < 128 * CN1; idx += 256){
            int p = idx / CN1, col = idx % CN1;
            int n1 = cc * CN1 + col;
            if (n1 < 125){
                int n = n1 + 125 * brev7(p);
                float mag = sqrtf(Br[idx] * Br[idx] + Bi[idx] * Bi[idx]);
                int tlo = ((n - DHALF + 16447) >> 6) - 256;   // ceil((n-176)/64)
                int thi = ((n + DHALF + 16384) >> 6) - 256;   // floor((n+176)/64)
                for (int t = tlo; t <= thi; ++t){
                    int d = 64 * t - n;
                    int ad = d < 0 ? -d : d;
                    int tm = t; if (tm < 0) tm += NOUT; if (tm >= NOUT) tm -= NOUT;
                    atomicAdd(&Sacc[tm], mag * hwin[ad]);
                }
            }
        }
        __syncthreads();
    }
    if (tid < NOUT){
        Schan[(b * NCH + 1 + fi) * NOUT + tid] = Sacc[tid];
    }
}

// ---- K3: S0 = (x * gaussian)[::64] directly from x -----------------------
__global__ __launch_bounds__(256) void k_s0(const float* __restrict__ x,
                                            float* __restrict__ Schan){
    __shared__ float hwin[DHALF + 1];
    const int b = blockIdx.x, tid = threadIdx.x;
    for (int j = tid; j <= DHALF; j += 256){
        double st = 1.0 / (TWO_PI * (0.35 / 64.0));
        hwin[j] = (float)((0.35 / 64.0) * sqrt(TWO_PI) * exp(-0.5 * (double)(j * j) / (st * st)));
    }
    __syncthreads();
    if (tid < NOUT){
        float acc = 0.0f;
        int n = 64 * tid - DHALF; if (n < 0) n += TLEN;
        for (int d = -DHALF; d <= DHALF; ++d){
            int ad = d < 0 ? -d : d;
            acc += hwin[ad] * x[b * TLEN + n];
            ++n; if (n == TLEN) n = 0;
        }
        Schan[(b * NCH + 0) * NOUT + tid] = acc;
    }
}

// ---- K4: channel-group means -> FLOAT32 output ---------------------------
__global__ __launch_bounds__(256) void k_reduce(const float* __restrict__ Schan,
                                                float* __restrict__ out){
    int o = blockIdx.x * 256 + threadIdx.x;
    if (o >= NBATCH * 3 * NOUT) return;
    int b = o / (3 * NOUT);
    int rem = o - b * 3 * NOUT;
    int g = rem / NOUT;
    int t = rem - g * NOUT;
    int c0 = (g == 0) ? 0 : (g == 1 ? 12 : 24);
    int c1 = (g == 0) ? 12 : (g == 1 ? 24 : 37);
    float s = 0.0f;
    for (int c = c0; c < c1; ++c) s += Schan[(b * NCH + c) * NOUT + t];
    out[o] = s / (float)(c1 - c0);
}

__global__ void k_fill_f32(float* out, int n, float v){
    int i = blockIdx.x * 256 + threadIdx.x;
    if (i < n) out[i] = v;
}

extern "C" void kernel_launch(void* const* d_in, const int* in_sizes, int n_in,
                              void* d_out, int out_size, void* d_ws, size_t ws_size,
                              hipStream_t stream) {
    const float* x = (const float*)d_in[0];
    float* out = (float*)d_out;                               // reference output is float32
    const size_t xf_bytes = (size_t)NBATCH * KMAX * sizeof(float2);        // 4,096,000
    const size_t schan_bytes = (size_t)NBATCH * NCH * NOUT * sizeof(float); // 2,368,000
    if (ws_size < xf_bytes + schan_bytes){
        k_fill_f32<<<(out_size + 255) / 256, 256, 0, stream>>>(out, out_size, 800.0f);
        return;                                   // sentinel: workspace too small
    }
    float2* Xf = (float2*)d_ws;
    float* Schan = (float*)((char*)d_ws + xf_bytes);

    k_fft<<<NBATCH, 256, 0, stream>>>(x, Xf);
    k_scatter<<<NBATCH * NPSI, 256, 0, stream>>>(Xf, Schan);
    k_s0<<<NBATCH, 256, 0, stream>>>(x, Schan);
    k_reduce<<<(NBATCH * 3 * NOUT + 255) / 256, 256, 0, stream>>>(Schan, out);
}

// Round 6
// 426.093 us; speedup vs baseline: 5.5973x; 5.5973x over previous
//
#include <hip/hip_runtime.h>
#include <hip/hip_bf16.h>

#define TLEN 16000
#define NPSI 36
#define NBATCH 64
#define NOUT 250
#define NCH 37
#define DHALF 176            // Gaussian lowpass half-width (6.05 sigma, sigma_t=29.1)
#define KMAX 8000
#define TWO_PI 6.283185307179586
#define CBPTOT 3490          // padded band buffer (complex): W<=3233 + 256 pad + 1 align

__device__ __forceinline__ int brev7(int q){ return (int)(__brev((unsigned)q) >> 25); }

// ---- K1: forward 16000-pt FFT per (batch, m-chunk); emit k<8000 ----------
// n = 128*n1 + n2, k = m + 125*j.  X[k] = sum_n2 W128^{j n2}[ W16000^{m n2}
// * sum_n1 x[128 n1 + n2] W125^{m n1} ]  (minus sign). 320 blocks.
__global__ __launch_bounds__(256) void k_fft(const float* __restrict__ x,
                                             float2* __restrict__ Xf){
    __shared__ float xs[32 * 125];            // 16.0 KB
    __shared__ float are[128 * 26];           // 13.3 KB (pad 26 vs banks)
    __shared__ float aie[128 * 26];           // 13.3 KB
    __shared__ float w125r[125], w125i[125];
    __shared__ float w16r[125],  w16i[125];
    __shared__ float w128r[128], w128i[128];
    const int b = blockIdx.x / 5, mc = blockIdx.x % 5, m0 = mc * 25;
    const int tid = threadIdx.x;

    for (int j = tid; j < 125; j += 256){
        double a = -TWO_PI * (double)j / 125.0;
        w125r[j] = (float)cos(a); w125i[j] = (float)sin(a);
        double a2 = -TWO_PI * (double)j / 16000.0;
        w16r[j] = (float)cos(a2); w16i[j] = (float)sin(a2);
    }
    for (int j = tid; j < 128; j += 256){
        double a = -TWO_PI * (double)j / 128.0;
        w128r[j] = (float)cos(a); w128i[j] = (float)sin(a);
    }
    for (int g = 0; g < 4; ++g){
        __syncthreads();                      // tables ready / xs reuse
        for (int i = tid; i < 32 * 125; i += 256){
            int lr = i & 31, n1 = i >> 5;     // lr fast -> coalesced
            xs[lr * 125 + n1] = x[b * TLEN + 128 * n1 + 32 * g + lr];
        }
        __syncthreads();
        for (int oi = tid; oi < 800; oi += 256){
            int ml = oi >> 5, n2l = oi & 31;
            int m = m0 + ml, n2 = 32 * g + n2l;
            const float* xr = &xs[n2l * 125];
            float ar = 0.0f, ai = 0.0f;
            int jj = 0;
            for (int n1 = 0; n1 < 125; ++n1){
                float xv = xr[n1];
                ar += xv * w125r[jj]; ai += xv * w125i[jj];
                jj += m; if (jj >= 125) jj -= 125;
            }
            int a = m * n2;                   // <= 15748 = 125*q + rr
            int q = a / 125, rr = a - q * 125;
            float tr = w16r[rr] * w128r[q] - w16i[rr] * w128i[q];
            float ti = w16r[rr] * w128i[q] + w16i[rr] * w128r[q];
            are[n2 * 26 + ml] = ar * tr - ai * ti;
            aie[n2 * 26 + ml] = ar * ti + ai * tr;
        }
    }
    // radix-2 DIF over n2 (minus tables), 25 columns
    for (int span = 64; span >= 1; span >>= 1){
        __syncthreads();
        for (int idx = tid; idx < 1600; idx += 256){
            int u = idx & 63, ml = idx >> 6;
            int blkq = u / span, mm = u % span;
            int p0 = blkq * 2 * span + mm;
            int i0 = p0 * 26 + ml, i1 = i0 + span * 26;
            float ar = are[i0], ai = aie[i0], br = are[i1], bi = aie[i1];
            are[i0] = ar + br; aie[i0] = ai + bi;
            float dr = ar - br, di = ai - bi;
            int jt = mm * (64 / span);
            are[i1] = dr * w128r[jt] - di * w128i[jt];
            aie[i1] = dr * w128i[jt] + di * w128r[jt];
        }
    }
    __syncthreads();
    for (int idx = tid; idx < 1600; idx += 256){
        int u = idx & 63, ml = idx >> 6;
        int p = 2 * u;                        // even slots -> j < 64 -> k < 8000
        int k = (m0 + ml) + 125 * brev7(p);
        Xf[(size_t)b * KMAX + k] = make_float2(are[p * 26 + ml], aie[p * 26 + ml]);
    }
}

// ---- K2: per (filter, batch): band inverse FFT -> |z| -> Gaussian conv ---
// Heavy-first grid: fi = blk>>6 (wide bands first), b = blk&63.
__global__ __launch_bounds__(256) void k_scatter(const float2* __restrict__ Xf,
                                                 float* __restrict__ Schan){
    __shared__ float cbp[2 * CBPTOT];                   // 27.9 KB padded band
    __shared__ float Br[128 * 16];                      // 8.2 KB
    __shared__ float Bi[16 * 132];                      // 8.45 KB (FFT: first 2048; conv: [rl][132])
    __shared__ float w125r[125], w125i[125];            // e^{+2pi i j/125}
    __shared__ float w128r[128], w128i[128];            // e^{+2pi i j/128}
    __shared__ float w16r[125],  w16i[125];             // e^{+2pi i j/16000}
    __shared__ float hfull[DHALF * 2 + 1];              // 353 taps

    const int blk = blockIdx.x;
    const int fi = blk >> 6;                  // heavy (wide-band) filters first
    const int b = blk & 63;
    const int tid = threadIdx.x;
    const float2* __restrict__ Xfb = Xf + (size_t)b * KMAX;

    const double xi_d = 0.35 * exp2(-(double)fi / 6.0);
    const double r_d  = exp2(1.0 / 6.0);
    const double sig_d = xi_d * (r_d - 1.0) / (r_d + 1.0);
    const float xi = (float)xi_d;
    const float centerT = (float)(xi_d * (double)TLEN);
    const float sigT = (float)(sig_d * (double)TLEN);
    int klo = (int)floorf(centerT - 5.0f * sigT); if (klo < 1) klo = 1;
    int khi = (int)ceilf(centerT + 5.0f * sigT);  if (khi > KMAX - 1) khi = KMAX - 1;
    const int W = khi - klo + 1;
    const float inv2s2 = (float)(1.0 / (2.0 * sig_d * sig_d));
    const int k1lo = klo >> 7, k1hi = khi >> 7;
    const int PAD = 128 + (klo & 1);          // keeps band base even -> b128-aligned

    for (int j = tid; j < 125; j += 256){
        double a = TWO_PI * (double)j / 125.0;
        w125r[j] = (float)cos(a); w125i[j] = (float)sin(a);
        double a2 = TWO_PI * (double)j / 16000.0;
        w16r[j] = (float)cos(a2); w16i[j] = (float)sin(a2);
    }
    for (int j = tid; j < 128; j += 256){
        double a = TWO_PI * (double)j / 128.0;
        w128r[j] = (float)cos(a); w128i[j] = (float)sin(a);
    }
    for (int j = tid; j <= 2 * DHALF; j += 256){
        double st = 1.0 / (TWO_PI * (0.35 / 64.0));
        double dd = (double)(j - DHALF);
        hfull[j] = (float)((0.35 / 64.0) * sqrt(TWO_PI) * exp(-0.5 * dd * dd / (st * st)));
    }
    for (int idx = tid; idx < CBPTOT; idx += 256){ cbp[2*idx] = 0.0f; cbp[2*idx+1] = 0.0f; }
    __syncthreads();
    for (int idx = tid; idx < W; idx += 256){
        int k = klo + idx;
        float fr = (float)k * (1.0f / (float)TLEN);
        float d = fr - xi;
        float p = __expf(-d * d * inv2s2) * (1.0f / (float)TLEN);
        float2 Xv = Xfb[k];
        cbp[2*(PAD+idx)]   = Xv.x * p;
        cbp[2*(PAD+idx)+1] = Xv.y * p;
    }
    __syncthreads();

    const int g = tid >> 3;                   // 0..31 -> k2 = 4g..4g+3
    const int pr = tid & 7;                   // 0..7  -> n1 = 16cc+2pr+{0,1}
    float sreg = 0.0f;                        // conv accumulator (thread owns t=tid)

    for (int cc = 0; cc < 8; ++cc){
        // ---- gather: B[k2][n1] = sum_k1 cb[k2+128k1] W125^{k1 n1} --------
        int n1a = cc * 16 + 2 * pr;
        float wr0, wi0, wr1, wi1, sr0, si0, sr1, si1;
        {
            int n1c0 = n1a     < 125 ? n1a     : 124;
            int n1c1 = n1a + 1 < 125 ? n1a + 1 : 124;
            int j0 = (k1lo * n1c0) % 125, j1 = (k1lo * n1c1) % 125;
            wr0 = w125r[j0]; wi0 = w125i[j0]; wr1 = w125r[j1]; wi1 = w125i[j1];
            sr0 = w125r[n1c0]; si0 = w125i[n1c0]; sr1 = w125r[n1c1]; si1 = w125i[n1c1];
        }
        float ar0q0=0,ai0q0=0, ar1q0=0,ai1q0=0, ar2q0=0,ai2q0=0, ar3q0=0,ai3q0=0;
        float ar0q1=0,ai0q1=0, ar1q1=0,ai1q1=0, ar2q1=0,ai2q1=0, ar3q1=0,ai3q1=0;
        int ic = 4 * g + 128 * k1lo - klo + PAD;          // even
        for (int k1 = k1lo; k1 <= k1hi; ++k1){
            float4 c01 = *reinterpret_cast<const float4*>(&cbp[2 * ic]);
            float4 c23 = *reinterpret_cast<const float4*>(&cbp[2 * ic + 4]);
            ar0q0 += c01.x*wr0 - c01.y*wi0;  ai0q0 += c01.x*wi0 + c01.y*wr0;
            ar1q0 += c01.z*wr0 - c01.w*wi0;  ai1q0 += c01.z*wi0 + c01.w*wr0;
            ar2q0 += c23.x*wr0 - c23.y*wi0;  ai2q0 += c23.x*wi0 + c23.y*wr0;
            ar3q0 += c23.z*wr0 - c23.w*wi0;  ai3q0 += c23.z*wi0 + c23.w*wr0;
            ar0q1 += c01.x*wr1 - c01.y*wi1;  ai0q1 += c01.x*wi1 + c01.y*wr1;
            ar1q1 += c01.z*wr1 - c01.w*wi1;  ai1q1 += c01.z*wi1 + c01.w*wr1;
            ar2q1 += c23.x*wr1 - c23.y*wi1;  ai2q1 += c23.x*wi1 + c23.y*wr1;
            ar3q1 += c23.z*wr1 - c23.w*wi1;  ai3q1 += c23.z*wi1 + c23.w*wr1;
            float t0 = wr0*sr0 - wi0*si0; wi0 = wr0*si0 + wi0*sr0; wr0 = t0;
            float t1 = wr1*sr1 - wi1*si1; wi1 = wr1*si1 + wi1*sr1; wr1 = t1;
            ic += 128;
        }
        // twiddle W16000^{+k2 n1} and write Br/Bi [128][16]
        {
            float accr[4][2] = {{ar0q0,ar0q1},{ar1q0,ar1q1},{ar2q0,ar2q1},{ar3q0,ar3q1}};
            float acci[4][2] = {{ai0q0,ai0q1},{ai1q0,ai1q1},{ai2q0,ai2q1},{ai3q0,ai3q1}};
            #pragma unroll
            for (int j = 0; j < 4; ++j){
                #pragma unroll
                for (int q = 0; q < 2; ++q){
                    int k2 = 4 * g + j;
                    int n1 = n1a + q, n1t = n1 < 125 ? n1 : 124;
                    int a = k2 * n1t;
                    int qq = a / 125, rr = a - qq * 125;
                    float tr = w16r[rr] * w128r[qq] - w16i[rr] * w128i[qq];
                    float ti = w16r[rr] * w128i[qq] + w16i[rr] * w128r[qq];
                    int o = k2 * 16 + 2 * pr + q;
                    Br[o] = accr[j][q] * tr - acci[j][q] * ti;
                    Bi[o] = accr[j][q] * ti + acci[j][q] * tr;
                }
            }
        }
        // ---- 128-pt radix-2 DIF over k2 (plus tables), 16 columns --------
        for (int span = 64; span >= 1; span >>= 1){
            __syncthreads();
            for (int idx = tid; idx < 1024; idx += 256){
                int u = idx >> 4, col = idx & 15;
                int blkq = u / span, mm = u % span;
                int p0 = blkq * 2 * span + mm;
                int i0 = p0 * 16 + col, i1 = i0 + span * 16;
                float ar = Br[i0], ai = Bi[i0], br = Br[i1], bi = Bi[i1];
                Br[i0] = ar + br; Bi[i0] = ai + bi;
                float dr = ar - br, di = ai - bi;
                int jt = mm * (64 / span);
                Br[i1] = dr * w128r[jt] - di * w128i[jt];
                Bi[i1] = dr * w128i[jt] + di * w128r[jt];
            }
        }
        __syncthreads();
        // ---- |z| -> transpose to Bi[rl][n2] (n2 = brev7(p)) --------------
        float mag[8];
        #pragma unroll
        for (int e = 0; e < 8; ++e){
            int idx = tid + 256 * e;
            mag[e] = sqrtf(Br[idx] * Br[idx] + Bi[idx] * Bi[idx]);
        }
        __syncthreads();
        #pragma unroll
        for (int e = 0; e < 8; ++e){
            int idx = tid + 256 * e;
            int p = idx >> 4, rl = idx & 15;
            Bi[rl * 132 + brev7(p)] = mag[e];
        }
        __syncthreads();
        // ---- conv partial: thread t gathers taps with n%125 in this chunk
        if (tid < NOUT){
            int lo = 64 * tid - DHALF;
            #pragma unroll
            for (int rl = 0; rl < 16; ++rl){
                int r = cc * 16 + rl;
                if (r < 125){
                    int dm = (r - lo) % 125; if (dm < 0) dm += 125;
                    for (int n = lo + dm; n <= lo + 2 * DHALF; n += 125){
                        int d = n - lo;
                        int nm = n; if (nm < 0) nm += TLEN; if (nm >= TLEN) nm -= TLEN;
                        int n2 = (nm - r) / 125;
                        sreg += hfull[d] * Bi[rl * 132 + n2];
                    }
                }
            }
        }
        __syncthreads();                      // Br/Bi reuse next chunk
    }
    if (tid < NOUT){
        Schan[(b * NCH + 1 + fi) * NOUT + tid] = sreg;
    }
}

// ---- K3: S0 = (x * gaussian)[::64] directly from x -----------------------
__global__ __launch_bounds__(256) void k_s0(const float* __restrict__ x,
                                            float* __restrict__ Schan){
    __shared__ float hwin[DHALF + 1];
    const int b = blockIdx.x, tid = threadIdx.x;
    for (int j = tid; j <= DHALF; j += 256){
        double st = 1.0 / (TWO_PI * (0.35 / 64.0));
        hwin[j] = (float)((0.35 / 64.0) * sqrt(TWO_PI) * exp(-0.5 * (double)(j * j) / (st * st)));
    }
    __syncthreads();
    if (tid < NOUT){
        float acc = 0.0f;
        int n = 64 * tid - DHALF; if (n < 0) n += TLEN;
        for (int d = -DHALF; d <= DHALF; ++d){
            int ad = d < 0 ? -d : d;
            acc += hwin[ad] * x[b * TLEN + n];
            ++n; if (n == TLEN) n = 0;
        }
        Schan[(b * NCH + 0) * NOUT + tid] = acc;
    }
}

// ---- K4: channel-group means -> f32 --------------------------------------
__global__ __launch_bounds__(256) void k_reduce(const float* __restrict__ Schan,
                                                float* __restrict__ out){
    int o = blockIdx.x * 256 + threadIdx.x;
    if (o >= NBATCH * 3 * NOUT) return;
    int b = o / (3 * NOUT);
    int rem = o - b * 3 * NOUT;
    int g = rem / NOUT;
    int t = rem - g * NOUT;
    int c0 = (g == 0) ? 0 : (g == 1 ? 12 : 24);
    int c1 = (g == 0) ? 12 : (g == 1 ? 24 : 37);
    float s = 0.0f;
    for (int c = c0; c < c1; ++c) s += Schan[(b * NCH + c) * NOUT + t];
    out[o] = s / (float)(c1 - c0);
}

__global__ void k_fill_f32(float* out, int n, float v){
    int i = blockIdx.x * 256 + threadIdx.x;
    if (i < n) out[i] = v;
}

extern "C" void kernel_launch(void* const* d_in, const int* in_sizes, int n_in,
                              void* d_out, int out_size, void* d_ws, size_t ws_size,
                              hipStream_t stream) {
    const float* x = (const float*)d_in[0];
    float* out = (float*)d_out;
    const size_t xf_bytes = (size_t)NBATCH * KMAX * sizeof(float2);         // 4.10 MB
    const size_t schan_bytes = (size_t)NBATCH * NCH * NOUT * sizeof(float); // 2.37 MB
    if (ws_size < xf_bytes + schan_bytes){
        k_fill_f32<<<(out_size + 255) / 256, 256, 0, stream>>>(out, out_size, 800.0f);
        return;
    }
    float2* Xf = (float2*)d_ws;
    float* Schan = (float*)((char*)d_ws + xf_bytes);

    k_fft<<<NBATCH * 5, 256, 0, stream>>>(x, Xf);
    k_scatter<<<NBATCH * NPSI, 256, 0, stream>>>(Xf, Schan);
    k_s0<<<NBATCH, 256, 0, stream>>>(x, Schan);
    k_reduce<<<(NBATCH * 3 * NOUT + 255) / 256, 256, 0, stream>>>(Schan, out);
}

// Round 7
// 302.885 us; speedup vs baseline: 7.8742x; 1.4068x over previous
//
#include <hip/hip_runtime.h>
#include <hip/hip_bf16.h>

#define TLEN 16000
#define NPSI 36
#define NBATCH 64
#define NOUT 250
#define NCH 37
#define DHALF 176            // Gaussian lowpass half-width (6.05 sigma, sigma_t=29.1)
#define KMAX 8000
#define TWO_PI 6.283185307179586

__device__ __forceinline__ int brev7(int q){ return (int)(__brev((unsigned)q) >> 25); }

// ---- K1: forward 16000-pt FFT per (batch, m-chunk); emit k<8000 ----------
// (unchanged from round 6 — verified)
__global__ __launch_bounds__(256) void k_fft(const float* __restrict__ x,
                                             float2* __restrict__ Xf){
    __shared__ float xs[32 * 125];
    __shared__ float are[128 * 26];
    __shared__ float aie[128 * 26];
    __shared__ float w125r[125], w125i[125];
    __shared__ float w16r[125],  w16i[125];
    __shared__ float w128r[128], w128i[128];
    const int b = blockIdx.x / 5, mc = blockIdx.x % 5, m0 = mc * 25;
    const int tid = threadIdx.x;

    for (int j = tid; j < 125; j += 256){
        double a = -TWO_PI * (double)j / 125.0;
        w125r[j] = (float)cos(a); w125i[j] = (float)sin(a);
        double a2 = -TWO_PI * (double)j / 16000.0;
        w16r[j] = (float)cos(a2); w16i[j] = (float)sin(a2);
    }
    for (int j = tid; j < 128; j += 256){
        double a = -TWO_PI * (double)j / 128.0;
        w128r[j] = (float)cos(a); w128i[j] = (float)sin(a);
    }
    for (int g = 0; g < 4; ++g){
        __syncthreads();
        for (int i = tid; i < 32 * 125; i += 256){
            int lr = i & 31, n1 = i >> 5;
            xs[lr * 125 + n1] = x[b * TLEN + 128 * n1 + 32 * g + lr];
        }
        __syncthreads();
        for (int oi = tid; oi < 800; oi += 256){
            int ml = oi >> 5, n2l = oi & 31;
            int m = m0 + ml, n2 = 32 * g + n2l;
            const float* xr = &xs[n2l * 125];
            float ar = 0.0f, ai = 0.0f;
            int jj = 0;
            for (int n1 = 0; n1 < 125; ++n1){
                float xv = xr[n1];
                ar += xv * w125r[jj]; ai += xv * w125i[jj];
                jj += m; if (jj >= 125) jj -= 125;
            }
            int a = m * n2;
            int q = a / 125, rr = a - q * 125;
            float tr = w16r[rr] * w128r[q] - w16i[rr] * w128i[q];
            float ti = w16r[rr] * w128i[q] + w16i[rr] * w128r[q];
            are[n2 * 26 + ml] = ar * tr - ai * ti;
            aie[n2 * 26 + ml] = ar * ti + ai * tr;
        }
    }
    for (int span = 64; span >= 1; span >>= 1){
        __syncthreads();
        for (int idx = tid; idx < 1600; idx += 256){
            int u = idx & 63, ml = idx >> 6;
            int blkq = u / span, mm = u % span;
            int p0 = blkq * 2 * span + mm;
            int i0 = p0 * 26 + ml, i1 = i0 + span * 26;
            float ar = are[i0], ai = aie[i0], br = are[i1], bi = aie[i1];
            are[i0] = ar + br; aie[i0] = ai + bi;
            float dr = ar - br, di = ai - bi;
            int jt = mm * (64 / span);
            are[i1] = dr * w128r[jt] - di * w128i[jt];
            aie[i1] = dr * w128i[jt] + di * w128r[jt];
        }
    }
    __syncthreads();
    for (int idx = tid; idx < 1600; idx += 256){
        int u = idx & 63, ml = idx >> 6;
        int p = 2 * u;
        int k = (m0 + ml) + 125 * brev7(p);
        Xf[(size_t)b * KMAX + k] = make_float2(are[p * 26 + ml], aie[p * 26 + ml]);
    }
}

// ---- K2 (decimated): per (filter,batch): band ifft_N (N=T/D) -> |z| ->
// Gaussian conv at decimated rate (x D) -> 250 outputs ---------------------
// Chain identical to round-6 proven dataflow, parameterized (P, Q):
//   B[k2][n1] = sum_j C[k2+Q j] W_P^{+j n1};  *= W_N^{+k2 n1};
//   radix-2 DIF over k2 (W_Q^+), n2 = brev(p);  z_dec[n1 + P n2].
// Bands never wrap mod N (khi < N for every class) -> fold is identity.
template<int P, int LOG2Q, int CN1, int CBPC>
__global__ __launch_bounds__(256) void k_env(const float2* __restrict__ Xf,
                                             float* __restrict__ Schan,
                                             int fi0){
    constexpr int Q = 1 << LOG2Q;
    constexpr int N = P * Q;
    constexpr int D = TLEN / N;
    constexpr int NCHK = (P + CN1 - 1) / CN1;
    constexpr int MAGSZ = N + N / 32 + 2;
    __shared__ __align__(16) float cbp[2 * CBPC];       // zero-padded band
    __shared__ float Br[Q * CN1], Bi[Q * CN1];
    __shared__ float Mag[MAGSZ];                        // padded: addr = n' + (n'>>5)
    __shared__ float wPr[P], wPi[P];                    // e^{+2pi j/P}
    __shared__ float wQr[Q], wQi[Q];                    // e^{+2pi j/Q}
    __shared__ float wNr[P], wNi[P];                    // e^{+2pi j/N}
    __shared__ float hfull[2 * DHALF + 1];

    const int fi = fi0 + (int)(blockIdx.x >> 6);
    const int b = blockIdx.x & 63;
    const int tid = threadIdx.x;
    const float2* __restrict__ Xfb = Xf + (size_t)b * KMAX;

    const double xi_d = 0.35 * exp2(-(double)fi / 6.0);
    const double r_d  = exp2(1.0 / 6.0);
    const double sig_d = xi_d * (r_d - 1.0) / (r_d + 1.0);
    const float xi = (float)xi_d;
    const float centerT = (float)(xi_d * (double)TLEN);
    const float sigT = (float)(sig_d * (double)TLEN);
    int klo = (int)floorf(centerT - 5.0f * sigT); if (klo < 1) klo = 1;
    int khi = (int)ceilf(centerT + 5.0f * sigT);  if (khi > KMAX - 1) khi = KMAX - 1;
    const int W = khi - klo + 1;
    const float inv2s2 = (float)(1.0 / (2.0 * sig_d * sig_d));
    const int PADc = 128 + (klo & 1);                   // keeps gather base even

    for (int j = tid; j < P; j += 256){
        double a = TWO_PI * (double)j / (double)P;
        wPr[j] = (float)cos(a); wPi[j] = (float)sin(a);
        double a2 = TWO_PI * (double)j / (double)N;
        wNr[j] = (float)cos(a2); wNi[j] = (float)sin(a2);
    }
    for (int j = tid; j < Q; j += 256){
        double a = TWO_PI * (double)j / (double)Q;
        wQr[j] = (float)cos(a); wQi[j] = (float)sin(a);
    }
    for (int j = tid; j <= 2 * DHALF; j += 256){
        double st = 1.0 / (TWO_PI * (0.35 / 64.0));
        double dd = (double)(j - DHALF);
        hfull[j] = (float)((0.35 / 64.0) * sqrt(TWO_PI) * exp(-0.5 * dd * dd / (st * st)));
    }
    for (int j = tid; j < 2 * CBPC; j += 256) cbp[j] = 0.0f;
    __syncthreads();
    for (int idx = tid; idx < W; idx += 256){
        int k = klo + idx;
        float fr = (float)k * (1.0f / (float)TLEN);
        float d = fr - xi;
        float p = __expf(-d * d * inv2s2) * (1.0f / (float)TLEN);
        float2 Xv = Xfb[k];
        cbp[2 * (PADc + idx)]     = Xv.x * p;
        cbp[2 * (PADc + idx) + 1] = Xv.y * p;
    }
    __syncthreads();

    for (int cc = 0; cc < NCHK; ++cc){
        const int ncols = (P - cc * CN1 < CN1) ? (P - cc * CN1) : CN1;
        // ---- gather: 4 consecutive k2 per task, shared phase recurrence --
        for (int task = tid; task < (Q / 4) * CN1; task += 256){
            int gq = task / CN1, col = task % CN1;
            if (col < ncols){
                int n1 = cc * CN1 + col;
                int k2 = 4 * gq;
                int jlo = (klo - k2 + Q - 1) >> LOG2Q;
                int jhi = (khi - k2) >> LOG2Q;
                int jj0 = (jlo * n1) % P;
                float wr = wPr[jj0], wi = wPi[jj0];
                float sr = wPr[n1], si = wPi[n1];
                float ar0=0,ai0=0, ar1=0,ai1=0, ar2=0,ai2=0, ar3=0,ai3=0;
                int ic = k2 + (jlo << LOG2Q) - klo + PADc;      // even
                for (int j = jlo; j <= jhi; ++j){
                    float4 c01 = *reinterpret_cast<const float4*>(&cbp[2 * ic]);
                    float4 c23 = *reinterpret_cast<const float4*>(&cbp[2 * ic + 4]);
                    ar0 += c01.x*wr - c01.y*wi;  ai0 += c01.x*wi + c01.y*wr;
                    ar1 += c01.z*wr - c01.w*wi;  ai1 += c01.z*wi + c01.w*wr;
                    ar2 += c23.x*wr - c23.y*wi;  ai2 += c23.x*wi + c23.y*wr;
                    ar3 += c23.z*wr - c23.w*wi;  ai3 += c23.z*wi + c23.w*wr;
                    float t = wr*sr - wi*si; wi = wr*si + wi*sr; wr = t;
                    ic += Q;
                }
                float accr[4] = {ar0, ar1, ar2, ar3};
                float acci[4] = {ai0, ai1, ai2, ai3};
                #pragma unroll
                for (int jj = 0; jj < 4; ++jj){
                    int a = (k2 + jj) * n1;                     // < N
                    int q = a / P, rr = a - q * P;
                    float tr = wQr[q] * wNr[rr] - wQi[q] * wNi[rr];
                    float ti = wQr[q] * wNi[rr] + wQi[q] * wNr[rr];
                    int o = (k2 + jj) * CN1 + col;
                    Br[o] = accr[jj] * tr - acci[jj] * ti;
                    Bi[o] = accr[jj] * ti + acci[jj] * tr;
                }
            }
        }
        // ---- Q-pt radix-2 DIF over k2 (plus tables), per column ----------
        for (int span = Q / 2; span >= 1; span >>= 1){
            __syncthreads();
            for (int idx = tid; idx < (Q / 2) * CN1; idx += 256){
                int u = idx / CN1, col = idx % CN1;
                int blkq = u / span, mm = u % span;
                int p0 = blkq * 2 * span + mm;
                int i0 = p0 * CN1 + col, i1 = i0 + span * CN1;
                float ar = Br[i0], ai = Bi[i0], br = Br[i1], bi = Bi[i1];
                Br[i0] = ar + br; Bi[i0] = ai + bi;
                float dr = ar - br, di = ai - bi;
                int jt = mm * ((Q / 2) / span);
                Br[i1] = dr * wQr[jt] - di * wQi[jt];
                Bi[i1] = dr * wQi[jt] + di * wQr[jt];
            }
        }
        __syncthreads();
        // ---- |z| -> Mag[n'] (padded), n' = n1 + P*brev(p) ----------------
        for (int idx = tid; idx < Q * CN1; idx += 256){
            int p = idx / CN1, col = idx % CN1;
            if (col < ncols){
                int n1 = cc * CN1 + col;
                int n2 = (int)(__brev((unsigned)p) >> (32 - LOG2Q));
                int np = n1 + P * n2;
                Mag[np + (np >> 5)] = sqrtf(Br[idx] * Br[idx] + Bi[idx] * Bi[idx]);
            }
        }
        __syncthreads();                                 // Br/Bi reuse
    }
    // ---- conv: S1[t] = D * sum_{n'} phi(64t - D n') U_dec[n'] ------------
    if (tid < NOUT){
        int m0 = 64 * tid;
        int lo = m0 - DHALF;
        int nlo = (lo >= 0) ? ((lo + D - 1) / D) : -((-lo) / D);
        int nhi = (m0 + DHALF) / D;
        int np = nlo % N; if (np < 0) np += N;
        float acc = 0.0f;
        int d = m0 - D * nlo + DHALF;                    // start index, steps -D
        for (int n = nlo; n <= nhi; ++n){
            acc += hfull[d] * Mag[np + (np >> 5)];
            d -= D;
            ++np; if (np == N) np = 0;
        }
        Schan[(b * NCH + 1 + fi) * NOUT + tid] = acc * (float)D;
    }
}

// ---- K3: S0 = (x * gaussian)[::64] directly from x -----------------------
__global__ __launch_bounds__(256) void k_s0(const float* __restrict__ x,
                                            float* __restrict__ Schan){
    __shared__ float hwin[DHALF + 1];
    const int b = blockIdx.x, tid = threadIdx.x;
    for (int j = tid; j <= DHALF; j += 256){
        double st = 1.0 / (TWO_PI * (0.35 / 64.0));
        hwin[j] = (float)((0.35 / 64.0) * sqrt(TWO_PI) * exp(-0.5 * (double)(j * j) / (st * st)));
    }
    __syncthreads();
    if (tid < NOUT){
        float acc = 0.0f;
        int n = 64 * tid - DHALF; if (n < 0) n += TLEN;
        for (int d = -DHALF; d <= DHALF; ++d){
            int ad = d < 0 ? -d : d;
            acc += hwin[ad] * x[b * TLEN + n];
            ++n; if (n == TLEN) n = 0;
        }
        Schan[(b * NCH + 0) * NOUT + tid] = acc;
    }
}

// ---- K4: channel-group means -> f32 --------------------------------------
__global__ __launch_bounds__(256) void k_reduce(const float* __restrict__ Schan,
                                                float* __restrict__ out){
    int o = blockIdx.x * 256 + threadIdx.x;
    if (o >= NBATCH * 3 * NOUT) return;
    int b = o / (3 * NOUT);
    int rem = o - b * 3 * NOUT;
    int g = rem / NOUT;
    int t = rem - g * NOUT;
    int c0 = (g == 0) ? 0 : (g == 1 ? 12 : 24);
    int c1 = (g == 0) ? 12 : (g == 1 ? 24 : 37);
    float s = 0.0f;
    for (int c = c0; c < c1; ++c) s += Schan[(b * NCH + c) * NOUT + t];
    out[o] = s / (float)(c1 - c0);
}

__global__ void k_fill_f32(float* out, int n, float v){
    int i = blockIdx.x * 256 + threadIdx.x;
    if (i < n) out[i] = v;
}

extern "C" void kernel_launch(void* const* d_in, const int* in_sizes, int n_in,
                              void* d_out, int out_size, void* d_ws, size_t ws_size,
                              hipStream_t stream) {
    const float* x = (const float*)d_in[0];
    float* out = (float*)d_out;
    const size_t xf_bytes = (size_t)NBATCH * KMAX * sizeof(float2);
    const size_t schan_bytes = (size_t)NBATCH * NCH * NOUT * sizeof(float);
    if (ws_size < xf_bytes + schan_bytes){
        k_fill_f32<<<(out_size + 255) / 256, 256, 0, stream>>>(out, out_size, 800.0f);
        return;
    }
    float2* Xf = (float2*)d_ws;
    float* Schan = (float*)((char*)d_ws + xf_bytes);

    k_fft<<<NBATCH * 5, 256, 0, stream>>>(x, Xf);
    // filter classes: N = T/D chosen with alias guard N - 2W >= ~1090 bins
    k_env<125, 6, 16, 3380><<< 7 * 64, 256, 0, stream>>>(Xf, Schan,  0); // N=8000 D=2
    k_env<125, 5, 32, 1600><<< 3 * 64, 256, 0, stream>>>(Xf, Schan,  7); // N=4000 D=4
    k_env< 25, 7, 25, 1176><<< 7 * 64, 256, 0, stream>>>(Xf, Schan, 10); // N=3200 D=5
    k_env<125, 4, 64,  608><<< 5 * 64, 256, 0, stream>>>(Xf, Schan, 17); // N=2000 D=8
    k_env< 25, 6, 25,  408><<<14 * 64, 256, 0, stream>>>(Xf, Schan, 22); // N=1600 D=10
    k_s0<<<NBATCH, 256, 0, stream>>>(x, Schan);
    k_reduce<<<(NBATCH * 3 * NOUT + 255) / 256, 256, 0, stream>>>(Schan, out);
}

// Round 8
// 247.402 us; speedup vs baseline: 9.6401x; 1.2243x over previous
//
#include <hip/hip_runtime.h>
#include <hip/hip_bf16.h>

#define TLEN 16000
#define NPSI 36
#define NBATCH 64
#define NOUT 250
#define NCH 37
#define DHALF 176            // Gaussian lowpass half-width (6.05 sigma, sigma_t=29.1)
#define KMAX 8000
#define TWO_PI 6.283185307179586

__device__ __forceinline__ int brev7(int q){ return (int)(__brev((unsigned)q) >> 25); }
__device__ __forceinline__ int drev125(int p){
    return (p % 5) * 25 + ((p / 5) % 5) * 5 + (p / 25);
}

// ---- K1 (fused, radix-5): forward 16000-pt FFT per batch, emit k<8000 ----
// n = 128*n1 + n2, k = m + 125*j (m=drev125(p)).  Full plane in LDS.
// X[m+125j] = sum_n2 W128^{j n2}[ W16000^{m n2} * DFT125_n1(x[128n1+n2]) ]
__global__ __launch_bounds__(512) void k_fft(const float* __restrict__ x,
                                             float2* __restrict__ Xf){
    __shared__ float re[128 * 126];           // [n2][p], pad 126
    __shared__ float im[128 * 126];
    __shared__ float w125r[125], w125i[125];  // e^{-2pi j/125}
    __shared__ float w16r[125],  w16i[125];   // e^{-2pi j/16000}
    __shared__ float w128r[128], w128i[128];  // e^{-2pi j/128}
    const int b = blockIdx.x, tid = threadIdx.x;

    for (int j = tid; j < 125; j += 512){
        double a = -TWO_PI * (double)j / 125.0;
        w125r[j] = (float)cos(a); w125i[j] = (float)sin(a);
        double a2 = -TWO_PI * (double)j / 16000.0;
        w16r[j] = (float)cos(a2); w16i[j] = (float)sin(a2);
    }
    for (int j = tid; j < 128; j += 512){
        double a = -TWO_PI * (double)j / 128.0;
        w128r[j] = (float)cos(a); w128i[j] = (float)sin(a);
    }
    for (int gi = tid; gi < TLEN; gi += 512){
        int n2 = gi & 127, n1 = gi >> 7;
        re[n2 * 126 + n1] = x[b * TLEN + gi];
        im[n2 * 126 + n1] = 0.0f;
    }
    // 3 radix-5 DIF stages over n1 (minus sign); output digit-reversed p
    int f = 1;
    for (int s = 25; s >= 1; s /= 5, f *= 5){
        __syncthreads();
        for (int task = tid; task < 25 * 128; task += 512){
            int u = task >> 7, n2 = task & 127;
            int blk = u / s, m = u - blk * s;
            int base = n2 * 126 + blk * 5 * s + m;
            float xr[5], xi5[5];
            #pragma unroll
            for (int r = 0; r < 5; ++r){ xr[r] = re[base + r * s]; xi5[r] = im[base + r * s]; }
            #pragma unroll
            for (int q = 0; q < 5; ++q){
                float cr = xr[0], ci = xi5[0];
                #pragma unroll
                for (int r = 1; r < 5; ++r){
                    int w5 = 25 * ((q * r) % 5);
                    float wr = w125r[w5], wi = w125i[w5];
                    cr += xr[r] * wr - xi5[r] * wi;
                    ci += xr[r] * wi + xi5[r] * wr;
                }
                int jt = (m * q * f) % 125;
                float tr = w125r[jt], ti = w125i[jt];
                re[base + q * s] = cr * tr - ci * ti;
                im[base + q * s] = cr * ti + ci * tr;
            }
        }
    }
    __syncthreads();
    // twiddle W16000^{-m n2}, m = drev125(p)
    for (int idx = tid; idx < TLEN; idx += 512){
        int n2 = idx & 127, p = idx >> 7;
        int m = drev125(p);
        int a = n2 * m;                       // <= 15748 = 125*qq + rr
        int qq = a / 125, rr = a - qq * 125;
        float tr = w16r[rr] * w128r[qq] - w16i[rr] * w128i[qq];
        float ti = w16r[rr] * w128i[qq] + w16i[rr] * w128r[qq];
        int ad = n2 * 126 + p;
        float ar = re[ad], ai = im[ad];
        re[ad] = ar * tr - ai * ti;
        im[ad] = ar * ti + ai * tr;
    }
    // 7 radix-2 DIF stages over n2 (minus sign), per column p
    for (int span = 64; span >= 1; span >>= 1){
        __syncthreads();
        for (int idx = tid; idx < 64 * 125; idx += 512){
            int u = idx / 125, p = idx - (idx / 125) * 125;
            int blkq = u / span, mm = u % span;
            int i0 = (blkq * 2 * span + mm) * 126 + p, i1 = i0 + span * 126;
            float ar = re[i0], ai = im[i0], br = re[i1], bi = im[i1];
            re[i0] = ar + br; im[i0] = ai + bi;
            float dr = ar - br, di = ai - bi;
            int jt = mm * (64 / span);
            re[i1] = dr * w128r[jt] - di * w128i[jt];
            im[i1] = dr * w128i[jt] + di * w128r[jt];
        }
    }
    __syncthreads();
    // even phys slots hold j = brev7(2u) < 64 -> k = drev125(p) + 125 j
    for (int idx = tid; idx < 64 * 125; idx += 512){
        int u = idx / 125, p = idx - (idx / 125) * 125;
        int k = drev125(p) + 125 * brev7(2 * u);
        int ad = (2 * u) * 126 + p;
        Xf[(size_t)b * KMAX + k] = make_float2(re[ad], im[ad]);
    }
}

// ---- K2a (P=125 classes, radix-5): band ifft_N -> |z| -> conv ------------
// B[j][k2] init = psi-weighted C[k2+Qj]; radix-5 over j (plus sign) ->
// phys p holds n1=drev125(p); twiddle W_N^{+k2 n1}; radix-2 over k2 ->
// n2 = brevQ(slot); Mag[n1 + 125 n2]; Gaussian conv at stride D.
template<int LOG2Q>
__global__ __launch_bounds__(256) void k_env5(const float2* __restrict__ Xf,
                                              float* __restrict__ Schan,
                                              int fi0){
    constexpr int Q = 1 << LOG2Q;
    constexpr int N = 125 * Q;
    constexpr int D = TLEN / N;
    __shared__ float Br[125 * Q], Bi[125 * Q];          // [p][k2]
    __shared__ float Mag[N + N / 32 + 2];
    __shared__ float wPr[125], wPi[125];                // e^{+2pi j/125}
    __shared__ float wNr[125], wNi[125];                // e^{+2pi j/N}
    __shared__ float wQr[Q], wQi[Q];                    // e^{+2pi j/Q}
    __shared__ float hfull[2 * DHALF + 1];

    const int fi = fi0 + (int)(blockIdx.x >> 6);
    const int b = blockIdx.x & 63;
    const int tid = threadIdx.x;
    const float2* __restrict__ Xfb = Xf + (size_t)b * KMAX;

    const double xi_d = 0.35 * exp2(-(double)fi / 6.0);
    const double r_d  = exp2(1.0 / 6.0);
    const double sig_d = xi_d * (r_d - 1.0) / (r_d + 1.0);
    const float xi = (float)xi_d;
    const float centerT = (float)(xi_d * (double)TLEN);
    const float sigT = (float)(sig_d * (double)TLEN);
    int klo = (int)floorf(centerT - 5.0f * sigT); if (klo < 1) klo = 1;
    int khi = (int)ceilf(centerT + 5.0f * sigT);  if (khi > KMAX - 1) khi = KMAX - 1;
    const float inv2s2 = (float)(1.0 / (2.0 * sig_d * sig_d));

    for (int j = tid; j < 125; j += 256){
        double a = TWO_PI * (double)j / 125.0;
        wPr[j] = (float)cos(a); wPi[j] = (float)sin(a);
        double a2 = TWO_PI * (double)j / (double)N;
        wNr[j] = (float)cos(a2); wNi[j] = (float)sin(a2);
    }
    for (int j = tid; j < Q; j += 256){
        double a = TWO_PI * (double)j / (double)Q;
        wQr[j] = (float)cos(a); wQi[j] = (float)sin(a);
    }
    for (int j = tid; j <= 2 * DHALF; j += 256){
        double st = 1.0 / (TWO_PI * (0.35 / 64.0));
        double dd = (double)(j - DHALF);
        hfull[j] = (float)((0.35 / 64.0) * sqrt(TWO_PI) * exp(-0.5 * dd * dd / (st * st)));
    }
    __syncthreads();
    // init B[j][k2] from global (L2) with on-the-fly psi weight
    for (int idx = tid; idx < 125 * Q; idx += 256){
        int j = idx >> LOG2Q, k2 = idx & (Q - 1);
        int gk = k2 + (j << LOG2Q);
        float vr = 0.0f, vi = 0.0f;
        if (gk >= klo && gk <= khi){
            float fr = (float)gk * (1.0f / (float)TLEN);
            float d = fr - xi;
            float p = __expf(-d * d * inv2s2) * (1.0f / (float)TLEN);
            float2 Xv = Xfb[gk];
            vr = Xv.x * p; vi = Xv.y * p;
        }
        Br[idx] = vr; Bi[idx] = vi;
    }
    // 3 radix-5 DIF stages over j (plus sign)
    int f = 1;
    for (int s = 25; s >= 1; s /= 5, f *= 5){
        __syncthreads();
        for (int task = tid; task < 25 * Q; task += 256){
            int u = task >> LOG2Q, k2 = task & (Q - 1);
            int blk = u / s, m = u - blk * s;
            int base = (blk * 5 * s + m) * Q + k2;
            float xr[5], xi5[5];
            #pragma unroll
            for (int r = 0; r < 5; ++r){ xr[r] = Br[base + r * s * Q]; xi5[r] = Bi[base + r * s * Q]; }
            #pragma unroll
            for (int q = 0; q < 5; ++q){
                float cr = xr[0], ci = xi5[0];
                #pragma unroll
                for (int r = 1; r < 5; ++r){
                    int w5 = 25 * ((q * r) % 5);
                    float wr = wPr[w5], wi = wPi[w5];
                    cr += xr[r] * wr - xi5[r] * wi;
                    ci += xr[r] * wi + xi5[r] * wr;
                }
                int jt = (m * q * f) % 125;
                float tr = wPr[jt], ti = wPi[jt];
                Br[base + q * s * Q] = cr * tr - ci * ti;
                Bi[base + q * s * Q] = cr * ti + ci * tr;
            }
        }
    }
    __syncthreads();
    // twiddle W_N^{+k2 n1}, n1 = drev125(p).  W_N^{125} = W_Q.
    for (int idx = tid; idx < 125 * Q; idx += 256){
        int p = idx >> LOG2Q, k2 = idx & (Q - 1);
        int n1 = drev125(p);
        int a = k2 * n1;                      // < N = 125*qq + rr
        int qq = a / 125, rr = a - qq * 125;
        float tr = wQr[qq] * wNr[rr] - wQi[qq] * wNi[rr];
        float ti = wQr[qq] * wNi[rr] + wQi[qq] * wNr[rr];
        float ar = Br[idx], ai = Bi[idx];
        Br[idx] = ar * tr - ai * ti;
        Bi[idx] = ar * ti + ai * tr;
    }
    // radix-2 DIF over k2 (plus sign), per row p
    for (int span = Q / 2; span >= 1; span >>= 1){
        __syncthreads();
        for (int idx = tid; idx < 125 * (Q / 2); idx += 256){
            int p = idx / (Q / 2), u = idx - p * (Q / 2);
            int blkq = u / span, mm = u % span;
            int i0 = p * Q + blkq * 2 * span + mm, i1 = i0 + span;
            float ar = Br[i0], ai = Bi[i0], br = Br[i1], bi = Bi[i1];
            Br[i0] = ar + br; Bi[i0] = ai + bi;
            float dr = ar - br, di = ai - bi;
            int jt = mm * ((Q / 2) / span);
            Br[i1] = dr * wQr[jt] - di * wQi[jt];
            Bi[i1] = dr * wQi[jt] + di * wQr[jt];
        }
    }
    __syncthreads();
    // |z| -> Mag[n'], n' = drev125(p) + 125*brevQ(u)
    for (int idx = tid; idx < 125 * Q; idx += 256){
        int p = idx >> LOG2Q, u = idx & (Q - 1);
        int n2 = (int)(__brev((unsigned)u) >> (32 - LOG2Q));
        int np = drev125(p) + 125 * n2;
        Mag[np + (np >> 5)] = sqrtf(Br[idx] * Br[idx] + Bi[idx] * Bi[idx]);
    }
    __syncthreads();
    // conv: S1[t] = D * sum_{n'} phi(64t - D n') U_dec[n']
    if (tid < NOUT){
        int m0 = 64 * tid;
        int lo = m0 - DHALF;
        int nlo = (lo >= 0) ? ((lo + D - 1) / D) : -((-lo) / D);
        int nhi = (m0 + DHALF) / D;
        int np = nlo % N; if (np < 0) np += N;
        float acc = 0.0f;
        int d = m0 - D * nlo + DHALF;
        for (int n = nlo; n <= nhi; ++n){
            acc += hfull[d] * Mag[np + (np >> 5)];
            d -= D;
            ++np; if (np == N) np = 0;
        }
        Schan[(b * NCH + 1 + fi) * NOUT + tid] = acc * (float)D;
    }
}

// ---- K2b (P=25 classes): round-7 direct-gather kernel, verbatim ----------
template<int P, int LOG2Q, int CN1, int CBPC>
__global__ __launch_bounds__(256) void k_env(const float2* __restrict__ Xf,
                                             float* __restrict__ Schan,
                                             int fi0){
    constexpr int Q = 1 << LOG2Q;
    constexpr int N = P * Q;
    constexpr int D = TLEN / N;
    constexpr int NCHK = (P + CN1 - 1) / CN1;
    constexpr int MAGSZ = N + N / 32 + 2;
    __shared__ __align__(16) float cbp[2 * CBPC];
    __shared__ float Br[Q * CN1], Bi[Q * CN1];
    __shared__ float Mag[MAGSZ];
    __shared__ float wPr[P], wPi[P];
    __shared__ float wQr[Q], wQi[Q];
    __shared__ float wNr[P], wNi[P];
    __shared__ float hfull[2 * DHALF + 1];

    const int fi = fi0 + (int)(blockIdx.x >> 6);
    const int b = blockIdx.x & 63;
    const int tid = threadIdx.x;
    const float2* __restrict__ Xfb = Xf + (size_t)b * KMAX;

    const double xi_d = 0.35 * exp2(-(double)fi / 6.0);
    const double r_d  = exp2(1.0 / 6.0);
    const double sig_d = xi_d * (r_d - 1.0) / (r_d + 1.0);
    const float xi = (float)xi_d;
    const float centerT = (float)(xi_d * (double)TLEN);
    const float sigT = (float)(sig_d * (double)TLEN);
    int klo = (int)floorf(centerT - 5.0f * sigT); if (klo < 1) klo = 1;
    int khi = (int)ceilf(centerT + 5.0f * sigT);  if (khi > KMAX - 1) khi = KMAX - 1;
    const int W = khi - klo + 1;
    const float inv2s2 = (float)(1.0 / (2.0 * sig_d * sig_d));
    const int PADc = 128 + (klo & 1);

    for (int j = tid; j < P; j += 256){
        double a = TWO_PI * (double)j / (double)P;
        wPr[j] = (float)cos(a); wPi[j] = (float)sin(a);
        double a2 = TWO_PI * (double)j / (double)N;
        wNr[j] = (float)cos(a2); wNi[j] = (float)sin(a2);
    }
    for (int j = tid; j < Q; j += 256){
        double a = TWO_PI * (double)j / (double)Q;
        wQr[j] = (float)cos(a); wQi[j] = (float)sin(a);
    }
    for (int j = tid; j <= 2 * DHALF; j += 256){
        double st = 1.0 / (TWO_PI * (0.35 / 64.0));
        double dd = (double)(j - DHALF);
        hfull[j] = (float)((0.35 / 64.0) * sqrt(TWO_PI) * exp(-0.5 * dd * dd / (st * st)));
    }
    for (int j = tid; j < 2 * CBPC; j += 256) cbp[j] = 0.0f;
    __syncthreads();
    for (int idx = tid; idx < W; idx += 256){
        int k = klo + idx;
        float fr = (float)k * (1.0f / (float)TLEN);
        float d = fr - xi;
        float p = __expf(-d * d * inv2s2) * (1.0f / (float)TLEN);
        float2 Xv = Xfb[k];
        cbp[2 * (PADc + idx)]     = Xv.x * p;
        cbp[2 * (PADc + idx) + 1] = Xv.y * p;
    }
    __syncthreads();

    for (int cc = 0; cc < NCHK; ++cc){
        const int ncols = (P - cc * CN1 < CN1) ? (P - cc * CN1) : CN1;
        for (int task = tid; task < (Q / 4) * CN1; task += 256){
            int gq = task / CN1, col = task % CN1;
            if (col < ncols){
                int n1 = cc * CN1 + col;
                int k2 = 4 * gq;
                int jlo = (klo - k2 + Q - 1) >> LOG2Q;
                int jhi = (khi - k2) >> LOG2Q;
                int jj0 = (jlo * n1) % P;
                float wr = wPr[jj0], wi = wPi[jj0];
                float sr = wPr[n1], si = wPi[n1];
                float ar0=0,ai0=0, ar1=0,ai1=0, ar2=0,ai2=0, ar3=0,ai3=0;
                int ic = k2 + (jlo << LOG2Q) - klo + PADc;
                for (int j = jlo; j <= jhi; ++j){
                    float4 c01 = *reinterpret_cast<const float4*>(&cbp[2 * ic]);
                    float4 c23 = *reinterpret_cast<const float4*>(&cbp[2 * ic + 4]);
                    ar0 += c01.x*wr - c01.y*wi;  ai0 += c01.x*wi + c01.y*wr;
                    ar1 += c01.z*wr - c01.w*wi;  ai1 += c01.z*wi + c01.w*wr;
                    ar2 += c23.x*wr - c23.y*wi;  ai2 += c23.x*wi + c23.y*wr;
                    ar3 += c23.z*wr - c23.w*wi;  ai3 += c23.z*wi + c23.w*wr;
                    float t = wr*sr - wi*si; wi = wr*si + wi*sr; wr = t;
                    ic += Q;
                }
                float accr[4] = {ar0, ar1, ar2, ar3};
                float acci[4] = {ai0, ai1, ai2, ai3};
                #pragma unroll
                for (int jj = 0; jj < 4; ++jj){
                    int a = (k2 + jj) * n1;
                    int q = a / P, rr = a - q * P;
                    float tr = wQr[q] * wNr[rr] - wQi[q] * wNi[rr];
                    float ti = wQr[q] * wNi[rr] + wQi[q] * wNr[rr];
                    int o = (k2 + jj) * CN1 + col;
                    Br[o] = accr[jj] * tr - acci[jj] * ti;
                    Bi[o] = accr[jj] * ti + acci[jj] * tr;
                }
            }
        }
        for (int span = Q / 2; span >= 1; span >>= 1){
            __syncthreads();
            for (int idx = tid; idx < (Q / 2) * CN1; idx += 256){
                int u = idx / CN1, col = idx % CN1;
                int blkq = u / span, mm = u % span;
                int p0 = blkq * 2 * span + mm;
                int i0 = p0 * CN1 + col, i1 = i0 + span * CN1;
                float ar = Br[i0], ai = Bi[i0], br = Br[i1], bi = Bi[i1];
                Br[i0] = ar + br; Bi[i0] = ai + bi;
                float dr = ar - br, di = ai - bi;
                int jt = mm * ((Q / 2) / span);
                Br[i1] = dr * wQr[jt] - di * wQi[jt];
                Bi[i1] = dr * wQi[jt] + di * wQr[jt];
            }
        }
        __syncthreads();
        for (int idx = tid; idx < Q * CN1; idx += 256){
            int p = idx / CN1, col = idx % CN1;
            if (col < ncols){
                int n1 = cc * CN1 + col;
                int n2 = (int)(__brev((unsigned)p) >> (32 - LOG2Q));
                int np = n1 + P * n2;
                Mag[np + (np >> 5)] = sqrtf(Br[idx] * Br[idx] + Bi[idx] * Bi[idx]);
            }
        }
        __syncthreads();
    }
    if (tid < NOUT){
        int m0 = 64 * tid;
        int lo = m0 - DHALF;
        int nlo = (lo >= 0) ? ((lo + D - 1) / D) : -((-lo) / D);
        int nhi = (m0 + DHALF) / D;
        int np = nlo % N; if (np < 0) np += N;
        float acc = 0.0f;
        int d = m0 - D * nlo + DHALF;
        for (int n = nlo; n <= nhi; ++n){
            acc += hfull[d] * Mag[np + (np >> 5)];
            d -= D;
            ++np; if (np == N) np = 0;
        }
        Schan[(b * NCH + 1 + fi) * NOUT + tid] = acc * (float)D;
    }
}

// ---- K3: S0 = (x * gaussian)[::64] directly from x -----------------------
__global__ __launch_bounds__(256) void k_s0(const float* __restrict__ x,
                                            float* __restrict__ Schan){
    __shared__ float hwin[DHALF + 1];
    const int b = blockIdx.x, tid = threadIdx.x;
    for (int j = tid; j <= DHALF; j += 256){
        double st = 1.0 / (TWO_PI * (0.35 / 64.0));
        hwin[j] = (float)((0.35 / 64.0) * sqrt(TWO_PI) * exp(-0.5 * (double)(j * j) / (st * st)));
    }
    __syncthreads();
    if (tid < NOUT){
        float acc = 0.0f;
        int n = 64 * tid - DHALF; if (n < 0) n += TLEN;
        for (int d = -DHALF; d <= DHALF; ++d){
            int ad = d < 0 ? -d : d;
            acc += hwin[ad] * x[b * TLEN + n];
            ++n; if (n == TLEN) n = 0;
        }
        Schan[(b * NCH + 0) * NOUT + tid] = acc;
    }
}

// ---- K4: channel-group means -> f32 --------------------------------------
__global__ __launch_bounds__(256) void k_reduce(const float* __restrict__ Schan,
                                                float* __restrict__ out){
    int o = blockIdx.x * 256 + threadIdx.x;
    if (o >= NBATCH * 3 * NOUT) return;
    int b = o / (3 * NOUT);
    int rem = o - b * 3 * NOUT;
    int g = rem / NOUT;
    int t = rem - g * NOUT;
    int c0 = (g == 0) ? 0 : (g == 1 ? 12 : 24);
    int c1 = (g == 0) ? 12 : (g == 1 ? 24 : 37);
    float s = 0.0f;
    for (int c = c0; c < c1; ++c) s += Schan[(b * NCH + c) * NOUT + t];
    out[o] = s / (float)(c1 - c0);
}

__global__ void k_fill_f32(float* out, int n, float v){
    int i = blockIdx.x * 256 + threadIdx.x;
    if (i < n) out[i] = v;
}

extern "C" void kernel_launch(void* const* d_in, const int* in_sizes, int n_in,
                              void* d_out, int out_size, void* d_ws, size_t ws_size,
                              hipStream_t stream) {
    const float* x = (const float*)d_in[0];
    float* out = (float*)d_out;
    const size_t xf_bytes = (size_t)NBATCH * KMAX * sizeof(float2);
    const size_t schan_bytes = (size_t)NBATCH * NCH * NOUT * sizeof(float);
    if (ws_size < xf_bytes + schan_bytes){
        k_fill_f32<<<(out_size + 255) / 256, 256, 0, stream>>>(out, out_size, 800.0f);
        return;
    }
    float2* Xf = (float2*)d_ws;
    float* Schan = (float*)((char*)d_ws + xf_bytes);

    k_fft<<<NBATCH, 512, 0, stream>>>(x, Xf);
    // P=125 classes (radix-5 stage 1):
    k_env5<6><<< 7 * 64, 256, 0, stream>>>(Xf, Schan,  0);   // N=8000  D=2  fi 0-6
    k_env5<5><<< 3 * 64, 256, 0, stream>>>(Xf, Schan,  7);   // N=4000  D=4  fi 7-9
    k_env5<4><<< 5 * 64, 256, 0, stream>>>(Xf, Schan, 17);   // N=2000  D=8  fi 17-21
    // P=25 classes (direct gather, round-7 verbatim):
    k_env< 25, 7, 25, 1176><<< 7 * 64, 256, 0, stream>>>(Xf, Schan, 10); // N=3200 D=5
    k_env< 25, 6, 25,  408><<<14 * 64, 256, 0, stream>>>(Xf, Schan, 22); // N=1600 D=10
    k_s0<<<NBATCH, 256, 0, stream>>>(x, Schan);
    k_reduce<<<(NBATCH * 3 * NOUT + 255) / 256, 256, 0, stream>>>(Schan, out);
}

// Round 9
// 219.420 us; speedup vs baseline: 10.8695x; 1.1275x over previous
//
#include <hip/hip_runtime.h>
#include <hip/hip_bf16.h>

#define TLEN 16000
#define NPSI 36
#define NBATCH 64
#define NOUT 250
#define NCH 37
#define DHALF 176            // Gaussian lowpass half-width (6.05 sigma, sigma_t=29.1)
#define KMAX 8000
#define TWO_PI 6.283185307179586

__device__ __forceinline__ int brev7(int q){ return (int)(__brev((unsigned)q) >> 25); }
__device__ __forceinline__ int drev125(int p){
    return (p % 5) * 25 + ((p / 5) % 5) * 5 + (p / 25);
}

// ---- K1a (split): radix-5 over n1 for 32 n2-rows + W16000 twiddle --------
// Writes Gtmp[(b*125 + p)*128 + n2], phys col p holds m = drev125(p).
__global__ __launch_bounds__(256) void k_ffta(const float* __restrict__ x,
                                              float2* __restrict__ Gtmp){
    __shared__ float xr[32 * 126], xi[32 * 126];
    __shared__ float w125r[125], w125i[125];  // e^{-2pi j/125}
    __shared__ float w16r[125],  w16i[125];   // e^{-2pi j/16000}
    __shared__ float w128r[128], w128i[128];  // e^{-2pi j/128}
    const int b = blockIdx.x >> 2, g = blockIdx.x & 3, row0 = 32 * g;
    const int tid = threadIdx.x;

    for (int j = tid; j < 125; j += 256){
        double a = -TWO_PI * (double)j / 125.0;
        w125r[j] = (float)cos(a); w125i[j] = (float)sin(a);
        double a2 = -TWO_PI * (double)j / 16000.0;
        w16r[j] = (float)cos(a2); w16i[j] = (float)sin(a2);
    }
    for (int j = tid; j < 128; j += 256){
        double a = -TWO_PI * (double)j / 128.0;
        w128r[j] = (float)cos(a); w128i[j] = (float)sin(a);
    }
    for (int i = tid; i < 32 * 125; i += 256){
        int n1 = i >> 5, lr = i & 31;
        xr[lr * 126 + n1] = x[b * TLEN + 128 * n1 + row0 + lr];
        xi[lr * 126 + n1] = 0.0f;
    }
    int f = 1;
    for (int s = 25; s >= 1; s /= 5, f *= 5){
        __syncthreads();
        for (int task = tid; task < 25 * 32; task += 256){
            int u = task >> 5, lr = task & 31;
            int blk = u / s, m = u - blk * s;
            int base = lr * 126 + blk * 5 * s + m;
            float vr[5], vi[5];
            #pragma unroll
            for (int r = 0; r < 5; ++r){ vr[r] = xr[base + r * s]; vi[r] = xi[base + r * s]; }
            #pragma unroll
            for (int q = 0; q < 5; ++q){
                float cr = vr[0], ci = vi[0];
                #pragma unroll
                for (int r = 1; r < 5; ++r){
                    int w5 = 25 * ((q * r) % 5);
                    float wr = w125r[w5], wi = w125i[w5];
                    cr += vr[r] * wr - vi[r] * wi;
                    ci += vr[r] * wi + vi[r] * wr;
                }
                int jt = (m * q * f) % 125;
                float tr = w125r[jt], ti = w125i[jt];
                xr[base + q * s] = cr * tr - ci * ti;
                xi[base + q * s] = cr * ti + ci * tr;
            }
        }
    }
    __syncthreads();
    for (int i = tid; i < 125 * 32; i += 256){
        int p = i >> 5, lr = i & 31;
        int n2 = row0 + lr;
        int m = drev125(p);
        int a = m * n2;                       // <= 15748 = 125*qq + rr
        int qq = a / 125, rr = a - qq * 125;
        float tr = w16r[rr] * w128r[qq] - w16i[rr] * w128i[qq];
        float ti = w16r[rr] * w128i[qq] + w16i[rr] * w128r[qq];
        float ar = xr[lr * 126 + p], ai = xi[lr * 126 + p];
        Gtmp[((size_t)b * 125 + p) * 128 + n2] =
            make_float2(ar * tr - ai * ti, ar * ti + ai * tr);
    }
}

// ---- K1b (split): radix-2 over n2 for 25 phys cols; emit k<8000 ----------
__global__ __launch_bounds__(256) void k_fftb(const float2* __restrict__ Gtmp,
                                              float2* __restrict__ Xf){
    __shared__ float gr[128 * 26], gi[128 * 26];
    __shared__ float w128r[128], w128i[128];
    const int b = blockIdx.x / 5, p0 = (blockIdx.x % 5) * 25;
    const int tid = threadIdx.x;
    for (int j = tid; j < 128; j += 256){
        double a = -TWO_PI * (double)j / 128.0;
        w128r[j] = (float)cos(a); w128i[j] = (float)sin(a);
    }
    for (int i = tid; i < 25 * 128; i += 256){
        int ml = i >> 7, n2 = i & 127;
        float2 v = Gtmp[((size_t)b * 125 + p0 + ml) * 128 + n2];
        gr[n2 * 26 + ml] = v.x; gi[n2 * 26 + ml] = v.y;
    }
    for (int span = 64; span >= 1; span >>= 1){
        __syncthreads();
        for (int idx = tid; idx < 1600; idx += 256){
            int u = idx / 25, ml = idx - u * 25;
            int blkq = u / span, mm = u % span;
            int i0 = (blkq * 2 * span + mm) * 26 + ml, i1 = i0 + span * 26;
            float ar = gr[i0], ai = gi[i0], br = gr[i1], bi = gi[i1];
            gr[i0] = ar + br; gi[i0] = ai + bi;
            float dr = ar - br, di = ai - bi;
            int jt = mm * (64 / span);
            gr[i1] = dr * w128r[jt] - di * w128i[jt];
            gi[i1] = dr * w128i[jt] + di * w128r[jt];
        }
    }
    __syncthreads();
    for (int idx = tid; idx < 1600; idx += 256){
        int u = idx / 25, ml = idx - u * 25;
        int ad = (2 * u) * 26 + ml;
        int k = drev125(p0 + ml) + 125 * brev7(2 * u);
        Xf[(size_t)b * KMAX + k] = make_float2(gr[ad], gi[ad]);
    }
}

// ---- K1 fused fallback (round-8 verbatim; used only if ws too small) -----
__global__ __launch_bounds__(512) void k_fft(const float* __restrict__ x,
                                             float2* __restrict__ Xf){
    __shared__ float re[128 * 126];
    __shared__ float im[128 * 126];
    __shared__ float w125r[125], w125i[125];
    __shared__ float w16r[125],  w16i[125];
    __shared__ float w128r[128], w128i[128];
    const int b = blockIdx.x, tid = threadIdx.x;

    for (int j = tid; j < 125; j += 512){
        double a = -TWO_PI * (double)j / 125.0;
        w125r[j] = (float)cos(a); w125i[j] = (float)sin(a);
        double a2 = -TWO_PI * (double)j / 16000.0;
        w16r[j] = (float)cos(a2); w16i[j] = (float)sin(a2);
    }
    for (int j = tid; j < 128; j += 512){
        double a = -TWO_PI * (double)j / 128.0;
        w128r[j] = (float)cos(a); w128i[j] = (float)sin(a);
    }
    for (int gi = tid; gi < TLEN; gi += 512){
        int n2 = gi & 127, n1 = gi >> 7;
        re[n2 * 126 + n1] = x[b * TLEN + gi];
        im[n2 * 126 + n1] = 0.0f;
    }
    int f = 1;
    for (int s = 25; s >= 1; s /= 5, f *= 5){
        __syncthreads();
        for (int task = tid; task < 25 * 128; task += 512){
            int u = task >> 7, n2 = task & 127;
            int blk = u / s, m = u - blk * s;
            int base = n2 * 126 + blk * 5 * s + m;
            float xr[5], xi5[5];
            #pragma unroll
            for (int r = 0; r < 5; ++r){ xr[r] = re[base + r * s]; xi5[r] = im[base + r * s]; }
            #pragma unroll
            for (int q = 0; q < 5; ++q){
                float cr = xr[0], ci = xi5[0];
                #pragma unroll
                for (int r = 1; r < 5; ++r){
                    int w5 = 25 * ((q * r) % 5);
                    float wr = w125r[w5], wi = w125i[w5];
                    cr += xr[r] * wr - xi5[r] * wi;
                    ci += xr[r] * wi + xi5[r] * wr;
                }
                int jt = (m * q * f) % 125;
                float tr = w125r[jt], ti = w125i[jt];
                re[base + q * s] = cr * tr - ci * ti;
                im[base + q * s] = cr * ti + ci * tr;
            }
        }
    }
    __syncthreads();
    for (int idx = tid; idx < TLEN; idx += 512){
        int n2 = idx & 127, p = idx >> 7;
        int m = drev125(p);
        int a = n2 * m;
        int qq = a / 125, rr = a - qq * 125;
        float tr = w16r[rr] * w128r[qq] - w16i[rr] * w128i[qq];
        float ti = w16r[rr] * w128i[qq] + w16i[rr] * w128r[qq];
        int ad = n2 * 126 + p;
        float ar = re[ad], ai = im[ad];
        re[ad] = ar * tr - ai * ti;
        im[ad] = ar * ti + ai * tr;
    }
    for (int span = 64; span >= 1; span >>= 1){
        __syncthreads();
        for (int idx = tid; idx < 64 * 125; idx += 512){
            int u = idx / 125, p = idx - (idx / 125) * 125;
            int blkq = u / span, mm = u % span;
            int i0 = (blkq * 2 * span + mm) * 126 + p, i1 = i0 + span * 126;
            float ar = re[i0], ai = im[i0], br = re[i1], bi = im[i1];
            re[i0] = ar + br; im[i0] = ai + bi;
            float dr = ar - br, di = ai - bi;
            int jt = mm * (64 / span);
            re[i1] = dr * w128r[jt] - di * w128i[jt];
            im[i1] = dr * w128i[jt] + di * w128r[jt];
        }
    }
    __syncthreads();
    for (int idx = tid; idx < 64 * 125; idx += 512){
        int u = idx / 125, p = idx - (idx / 125) * 125;
        int k = drev125(p) + 125 * brev7(2 * u);
        int ad = (2 * u) * 126 + p;
        Xf[(size_t)b * KMAX + k] = make_float2(re[ad], im[ad]);
    }
}

// ---- K2a (P=125 classes): band ifft_N -> conv reading |z| in place -------
// No Mag array: conv maps tap n' -> (p = drev125(n'%125), s = brevQ(n'/125))
// and reads Br/Bi[p*Q+s] directly.  2 blocks/CU, 16 waves/CU target.
template<int LOG2Q, int NT>
__global__ __launch_bounds__(NT, 4) void k_env5(const float2* __restrict__ Xf,
                                                float* __restrict__ Schan,
                                                int fi0){
    constexpr int Q = 1 << LOG2Q;
    constexpr int N = 125 * Q;
    constexpr int D = TLEN / N;
    constexpr int SPL = (NT >= 512) ? 2 : 1;
    __shared__ float Br[125 * Q], Bi[125 * Q];          // [p][k2]
    __shared__ float wPr[125], wPi[125];                // e^{+2pi j/125}
    __shared__ float wNr[125], wNi[125];                // e^{+2pi j/N}
    __shared__ float wQr[Q], wQi[Q];                    // e^{+2pi j/Q}
    __shared__ float hfull[2 * DHALF + 1];
    __shared__ int   drevT[125];
    __shared__ float sred[250 * SPL];

    const int fi = fi0 + (int)(blockIdx.x >> 6);
    const int b = blockIdx.x & 63;
    const int tid = threadIdx.x;
    const float2* __restrict__ Xfb = Xf + (size_t)b * KMAX;

    const double xi_d = 0.35 * exp2(-(double)fi / 6.0);
    const double r_d  = exp2(1.0 / 6.0);
    const double sig_d = xi_d * (r_d - 1.0) / (r_d + 1.0);
    const float xi = (float)xi_d;
    const float centerT = (float)(xi_d * (double)TLEN);
    const float sigT = (float)(sig_d * (double)TLEN);
    int klo = (int)floorf(centerT - 5.0f * sigT); if (klo < 1) klo = 1;
    int khi = (int)ceilf(centerT + 5.0f * sigT);  if (khi > KMAX - 1) khi = KMAX - 1;
    const float inv2s2 = (float)(1.0 / (2.0 * sig_d * sig_d));

    for (int j = tid; j < 125; j += NT){
        double a = TWO_PI * (double)j / 125.0;
        wPr[j] = (float)cos(a); wPi[j] = (float)sin(a);
        double a2 = TWO_PI * (double)j / (double)N;
        wNr[j] = (float)cos(a2); wNi[j] = (float)sin(a2);
        drevT[j] = drev125(j);
    }
    for (int j = tid; j < Q; j += NT){
        double a = TWO_PI * (double)j / (double)Q;
        wQr[j] = (float)cos(a); wQi[j] = (float)sin(a);
    }
    for (int j = tid; j <= 2 * DHALF; j += NT){
        double st = 1.0 / (TWO_PI * (0.35 / 64.0));
        double dd = (double)(j - DHALF);
        hfull[j] = (float)((0.35 / 64.0) * sqrt(TWO_PI) * exp(-0.5 * dd * dd / (st * st)));
    }
    __syncthreads();
    for (int idx = tid; idx < 125 * Q; idx += NT){
        int j = idx >> LOG2Q, k2 = idx & (Q - 1);
        int gk = k2 + (j << LOG2Q);
        float vr = 0.0f, vi = 0.0f;
        if (gk >= klo && gk <= khi){
            float fr = (float)gk * (1.0f / (float)TLEN);
            float d = fr - xi;
            float p = __expf(-d * d * inv2s2) * (1.0f / (float)TLEN);
            float2 Xv = Xfb[gk];
            vr = Xv.x * p; vi = Xv.y * p;
        }
        Br[idx] = vr; Bi[idx] = vi;
    }
    // 3 radix-5 DIF stages over j (plus sign)
    int f = 1;
    for (int s = 25; s >= 1; s /= 5, f *= 5){
        __syncthreads();
        for (int task = tid; task < 25 * Q; task += NT){
            int u = task >> LOG2Q, k2 = task & (Q - 1);
            int blk = u / s, m = u - blk * s;
            int base = (blk * 5 * s + m) * Q + k2;
            float xr[5], xi5[5];
            #pragma unroll
            for (int r = 0; r < 5; ++r){ xr[r] = Br[base + r * s * Q]; xi5[r] = Bi[base + r * s * Q]; }
            #pragma unroll
            for (int q = 0; q < 5; ++q){
                float cr = xr[0], ci = xi5[0];
                #pragma unroll
                for (int r = 1; r < 5; ++r){
                    int w5 = 25 * ((q * r) % 5);
                    float wr = wPr[w5], wi = wPi[w5];
                    cr += xr[r] * wr - xi5[r] * wi;
                    ci += xr[r] * wi + xi5[r] * wr;
                }
                int jt = (m * q * f) % 125;
                float tr = wPr[jt], ti = wPi[jt];
                Br[base + q * s * Q] = cr * tr - ci * ti;
                Bi[base + q * s * Q] = cr * ti + ci * tr;
            }
        }
    }
    __syncthreads();
    // twiddle W_N^{+k2 n1}, n1 = drev125(p)
    for (int idx = tid; idx < 125 * Q; idx += NT){
        int p = idx >> LOG2Q, k2 = idx & (Q - 1);
        int n1 = drevT[p];
        int a = k2 * n1;                      // < N = 125*qq + rr
        int qq = a / 125, rr = a - qq * 125;
        float tr = wQr[qq] * wNr[rr] - wQi[qq] * wNi[rr];
        float ti = wQr[qq] * wNi[rr] + wQi[qq] * wNr[rr];
        float ar = Br[idx], ai = Bi[idx];
        Br[idx] = ar * tr - ai * ti;
        Bi[idx] = ar * ti + ai * tr;
    }
    // radix-2 DIF over k2 (plus sign), per row p
    for (int span = Q / 2; span >= 1; span >>= 1){
        __syncthreads();
        for (int idx = tid; idx < 125 * (Q / 2); idx += NT){
            int p = idx / (Q / 2), u = idx - p * (Q / 2);
            int blkq = u / span, mm = u % span;
            int i0 = p * Q + blkq * 2 * span + mm, i1 = i0 + span;
            float ar = Br[i0], ai = Bi[i0], br = Br[i1], bi = Bi[i1];
            Br[i0] = ar + br; Bi[i0] = ai + bi;
            float dr = ar - br, di = ai - bi;
            int jt = mm * ((Q / 2) / span);
            Br[i1] = dr * wQr[jt] - di * wQi[jt];
            Bi[i1] = dr * wQi[jt] + di * wQr[jt];
        }
    }
    __syncthreads();
    // conv: S1[t] = D * sum_n phi(64t - D n) |z[n]|, taps split SPL ways
    float acc = 0.0f;
    int t = tid;
    if (tid < 250 * SPL){
        t = (SPL == 2) ? (tid & 255) % 250 : tid;       // t = tid % 250
        if (SPL == 2) t = tid - 250 * (tid / 250);
        int q = (SPL == 2) ? (tid / 250) : 0;
        int m0 = 64 * t;
        int lo = m0 - DHALF;
        int nlo = (lo >= 0) ? ((lo + D - 1) / D) : -((-lo) / D);
        int nhi = (m0 + DHALF) / D;
        int n = nlo + q;
        if (n <= nhi){
            int np = n % N; if (np < 0) np += N;
            int n1 = np % 125, n2 = np / 125;
            int d = m0 - D * n + DHALF;
            for (; n <= nhi; n += SPL){
                int p = drevT[n1];
                int s = (int)(__brev((unsigned)n2) >> (32 - LOG2Q));
                int a = (p << LOG2Q) + s;
                float vr = Br[a], vi = Bi[a];
                acc += hfull[d] * sqrtf(vr * vr + vi * vi);
                d -= D * SPL;
                n1 += SPL; if (n1 >= 125){ n1 -= 125; ++n2; if (n2 == Q) n2 = 0; }
            }
        }
    }
    if (SPL == 2){
        if (tid < 500) sred[tid] = acc;
        __syncthreads();
        if (tid < 250)
            Schan[(b * NCH + 1 + fi) * NOUT + tid] = (sred[tid] + sred[tid + 250]) * (float)D;
    } else {
        if (tid < 250)
            Schan[(b * NCH + 1 + fi) * NOUT + t] = acc * (float)D;
    }
}

// ---- K2b (P=25 classes): round-7 direct-gather kernel, verbatim ----------
template<int P, int LOG2Q, int CN1, int CBPC>
__global__ __launch_bounds__(256) void k_env(const float2* __restrict__ Xf,
                                             float* __restrict__ Schan,
                                             int fi0){
    constexpr int Q = 1 << LOG2Q;
    constexpr int N = P * Q;
    constexpr int D = TLEN / N;
    constexpr int NCHK = (P + CN1 - 1) / CN1;
    constexpr int MAGSZ = N + N / 32 + 2;
    __shared__ __align__(16) float cbp[2 * CBPC];
    __shared__ float Br[Q * CN1], Bi[Q * CN1];
    __shared__ float Mag[MAGSZ];
    __shared__ float wPr[P], wPi[P];
    __shared__ float wQr[Q], wQi[Q];
    __shared__ float wNr[P], wNi[P];
    __shared__ float hfull[2 * DHALF + 1];

    const int fi = fi0 + (int)(blockIdx.x >> 6);
    const int b = blockIdx.x & 63;
    const int tid = threadIdx.x;
    const float2* __restrict__ Xfb = Xf + (size_t)b * KMAX;

    const double xi_d = 0.35 * exp2(-(double)fi / 6.0);
    const double r_d  = exp2(1.0 / 6.0);
    const double sig_d = xi_d * (r_d - 1.0) / (r_d + 1.0);
    const float xi = (float)xi_d;
    const float centerT = (float)(xi_d * (double)TLEN);
    const float sigT = (float)(sig_d * (double)TLEN);
    int klo = (int)floorf(centerT - 5.0f * sigT); if (klo < 1) klo = 1;
    int khi = (int)ceilf(centerT + 5.0f * sigT);  if (khi > KMAX - 1) khi = KMAX - 1;
    const int W = khi - klo + 1;
    const float inv2s2 = (float)(1.0 / (2.0 * sig_d * sig_d));
    const int PADc = 128 + (klo & 1);

    for (int j = tid; j < P; j += 256){
        double a = TWO_PI * (double)j / (double)P;
        wPr[j] = (float)cos(a); wPi[j] = (float)sin(a);
        double a2 = TWO_PI * (double)j / (double)N;
        wNr[j] = (float)cos(a2); wNi[j] = (float)sin(a2);
    }
    for (int j = tid; j < Q; j += 256){
        double a = TWO_PI * (double)j / (double)Q;
        wQr[j] = (float)cos(a); wQi[j] = (float)sin(a);
    }
    for (int j = tid; j <= 2 * DHALF; j += 256){
        double st = 1.0 / (TWO_PI * (0.35 / 64.0));
        double dd = (double)(j - DHALF);
        hfull[j] = (float)((0.35 / 64.0) * sqrt(TWO_PI) * exp(-0.5 * dd * dd / (st * st)));
    }
    for (int j = tid; j < 2 * CBPC; j += 256) cbp[j] = 0.0f;
    __syncthreads();
    for (int idx = tid; idx < W; idx += 256){
        int k = klo + idx;
        float fr = (float)k * (1.0f / (float)TLEN);
        float d = fr - xi;
        float p = __expf(-d * d * inv2s2) * (1.0f / (float)TLEN);
        float2 Xv = Xfb[k];
        cbp[2 * (PADc + idx)]     = Xv.x * p;
        cbp[2 * (PADc + idx) + 1] = Xv.y * p;
    }
    __syncthreads();

    for (int cc = 0; cc < NCHK; ++cc){
        const int ncols = (P - cc * CN1 < CN1) ? (P - cc * CN1) : CN1;
        for (int task = tid; task < (Q / 4) * CN1; task += 256){
            int gq = task / CN1, col = task % CN1;
            if (col < ncols){
                int n1 = cc * CN1 + col;
                int k2 = 4 * gq;
                int jlo = (klo - k2 + Q - 1) >> LOG2Q;
                int jhi = (khi - k2) >> LOG2Q;
                int jj0 = (jlo * n1) % P;
                float wr = wPr[jj0], wi = wPi[jj0];
                float sr = wPr[n1], si = wPi[n1];
                float ar0=0,ai0=0, ar1=0,ai1=0, ar2=0,ai2=0, ar3=0,ai3=0;
                int ic = k2 + (jlo << LOG2Q) - klo + PADc;
                for (int j = jlo; j <= jhi; ++j){
                    float4 c01 = *reinterpret_cast<const float4*>(&cbp[2 * ic]);
                    float4 c23 = *reinterpret_cast<const float4*>(&cbp[2 * ic + 4]);
                    ar0 += c01.x*wr - c01.y*wi;  ai0 += c01.x*wi + c01.y*wr;
                    ar1 += c01.z*wr - c01.w*wi;  ai1 += c01.z*wi + c01.w*wr;
                    ar2 += c23.x*wr - c23.y*wi;  ai2 += c23.x*wi + c23.y*wr;
                    ar3 += c23.z*wr - c23.w*wi;  ai3 += c23.z*wi + c23.w*wr;
                    float t = wr*sr - wi*si; wi = wr*si + wi*sr; wr = t;
                    ic += Q;
                }
                float accr[4] = {ar0, ar1, ar2, ar3};
                float acci[4] = {ai0, ai1, ai2, ai3};
                #pragma unroll
                for (int jj = 0; jj < 4; ++jj){
                    int a = (k2 + jj) * n1;
                    int q = a / P, rr = a - q * P;
                    float tr = wQr[q] * wNr[rr] - wQi[q] * wNi[rr];
                    float ti = wQr[q] * wNi[rr] + wQi[q] * wNr[rr];
                    int o = (k2 + jj) * CN1 + col;
                    Br[o] = accr[jj] * tr - acci[jj] * ti;
                    Bi[o] = accr[jj] * ti + acci[jj] * tr;
                }
            }
        }
        for (int span = Q / 2; span >= 1; span >>= 1){
            __syncthreads();
            for (int idx = tid; idx < (Q / 2) * CN1; idx += 256){
                int u = idx / CN1, col = idx % CN1;
                int blkq = u / span, mm = u % span;
                int p0 = blkq * 2 * span + mm;
                int i0 = p0 * CN1 + col, i1 = i0 + span * CN1;
                float ar = Br[i0], ai = Bi[i0], br = Br[i1], bi = Bi[i1];
                Br[i0] = ar + br; Bi[i0] = ai + bi;
                float dr = ar - br, di = ai - bi;
                int jt = mm * ((Q / 2) / span);
                Br[i1] = dr * wQr[jt] - di * wQi[jt];
                Bi[i1] = dr * wQi[jt] + di * wQr[jt];
            }
        }
        __syncthreads();
        for (int idx = tid; idx < Q * CN1; idx += 256){
            int p = idx / CN1, col = idx % CN1;
            if (col < ncols){
                int n1 = cc * CN1 + col;
                int n2 = (int)(__brev((unsigned)p) >> (32 - LOG2Q));
                int np = n1 + P * n2;
                Mag[np + (np >> 5)] = sqrtf(Br[idx] * Br[idx] + Bi[idx] * Bi[idx]);
            }
        }
        __syncthreads();
    }
    if (tid < NOUT){
        int m0 = 64 * tid;
        int lo = m0 - DHALF;
        int nlo = (lo >= 0) ? ((lo + D - 1) / D) : -((-lo) / D);
        int nhi = (m0 + DHALF) / D;
        int np = nlo % N; if (np < 0) np += N;
        float acc = 0.0f;
        int d = m0 - D * nlo + DHALF;
        for (int n = nlo; n <= nhi; ++n){
            acc += hfull[d] * Mag[np + (np >> 5)];
            d -= D;
            ++np; if (np == N) np = 0;
        }
        Schan[(b * NCH + 1 + fi) * NOUT + tid] = acc * (float)D;
    }
}

// ---- K3: S0 = (x * gaussian)[::64] directly from x -----------------------
__global__ __launch_bounds__(256) void k_s0(const float* __restrict__ x,
                                            float* __restrict__ Schan){
    __shared__ float hwin[DHALF + 1];
    const int b = blockIdx.x, tid = threadIdx.x;
    for (int j = tid; j <= DHALF; j += 256){
        double st = 1.0 / (TWO_PI * (0.35 / 64.0));
        hwin[j] = (float)((0.35 / 64.0) * sqrt(TWO_PI) * exp(-0.5 * (double)(j * j) / (st * st)));
    }
    __syncthreads();
    if (tid < NOUT){
        float acc = 0.0f;
        int n = 64 * tid - DHALF; if (n < 0) n += TLEN;
        for (int d = -DHALF; d <= DHALF; ++d){
            int ad = d < 0 ? -d : d;
            acc += hwin[ad] * x[b * TLEN + n];
            ++n; if (n == TLEN) n = 0;
        }
        Schan[(b * NCH + 0) * NOUT + tid] = acc;
    }
}

// ---- K4: channel-group means -> f32 --------------------------------------
__global__ __launch_bounds__(256) void k_reduce(const float* __restrict__ Schan,
                                                float* __restrict__ out){
    int o = blockIdx.x * 256 + threadIdx.x;
    if (o >= NBATCH * 3 * NOUT) return;
    int b = o / (3 * NOUT);
    int rem = o - b * 3 * NOUT;
    int g = rem / NOUT;
    int t = rem - g * NOUT;
    int c0 = (g == 0) ? 0 : (g == 1 ? 12 : 24);
    int c1 = (g == 0) ? 12 : (g == 1 ? 24 : 37);
    float s = 0.0f;
    for (int c = c0; c < c1; ++c) s += Schan[(b * NCH + c) * NOUT + t];
    out[o] = s / (float)(c1 - c0);
}

__global__ void k_fill_f32(float* out, int n, float v){
    int i = blockIdx.x * 256 + threadIdx.x;
    if (i < n) out[i] = v;
}

extern "C" void kernel_launch(void* const* d_in, const int* in_sizes, int n_in,
                              void* d_out, int out_size, void* d_ws, size_t ws_size,
                              hipStream_t stream) {
    const float* x = (const float*)d_in[0];
    float* out = (float*)d_out;
    const size_t xf_bytes = (size_t)NBATCH * KMAX * sizeof(float2);          // 4.10 MB
    const size_t schan_bytes = (size_t)NBATCH * NCH * NOUT * sizeof(float);  // 2.37 MB
    const size_t gtmp_bytes = (size_t)NBATCH * 16000 * sizeof(float2);       // 8.19 MB
    if (ws_size < xf_bytes + schan_bytes){
        k_fill_f32<<<(out_size + 255) / 256, 256, 0, stream>>>(out, out_size, 800.0f);
        return;
    }
    float2* Xf = (float2*)d_ws;
    float* Schan = (float*)((char*)d_ws + xf_bytes);

    if (ws_size >= xf_bytes + schan_bytes + gtmp_bytes){
        float2* Gtmp = (float2*)((char*)d_ws + xf_bytes + schan_bytes);
        k_ffta<<<NBATCH * 4, 256, 0, stream>>>(x, Gtmp);
        k_fftb<<<NBATCH * 5, 256, 0, stream>>>(Gtmp, Xf);
    } else {
        k_fft<<<NBATCH, 512, 0, stream>>>(x, Xf);
    }
    // P=125 classes (radix-5 + in-place conv):
    k_env5<6, 512><<< 7 * 64, 512, 0, stream>>>(Xf, Schan,  0);  // N=8000 D=2  fi 0-6
    k_env5<5, 512><<< 3 * 64, 512, 0, stream>>>(Xf, Schan,  7);  // N=4000 D=4  fi 7-9
    k_env5<4, 256><<< 5 * 64, 256, 0, stream>>>(Xf, Schan, 17);  // N=2000 D=8  fi 17-21
    // P=25 classes (direct gather, verbatim):
    k_env< 25, 7, 25, 1176><<< 7 * 64, 256, 0, stream>>>(Xf, Schan, 10); // N=3200 D=5
    k_env< 25, 6, 25,  408><<<14 * 64, 256, 0, stream>>>(Xf, Schan, 22); // N=1600 D=10
    k_s0<<<NBATCH, 256, 0, stream>>>(x, Schan);
    k_reduce<<<(NBATCH * 3 * NOUT + 255) / 256, 256, 0, stream>>>(Schan, out);
}

// Round 10
// 183.715 us; speedup vs baseline: 12.9819x; 1.1943x over previous
//
#include <hip/hip_runtime.h>
#include <hip/hip_bf16.h>

#define TLEN 16000
#define NPSI 36
#define NBATCH 64
#define NOUT 250
#define NCH 37
#define DHALF 176            // Gaussian lowpass half-width (6.05 sigma, sigma_t=29.1)
#define KMAX 8000
#define TWO_PI 6.283185307179586

__device__ __forceinline__ int brev7(int q){ return (int)(__brev((unsigned)q) >> 25); }
__device__ __forceinline__ int drev125(int p){
    return (p % 5) * 25 + ((p / 5) % 5) * 5 + (p / 25);
}

// ---- K1a (split): radix-5 over n1 for 32 n2-rows + W16000 twiddle --------
__global__ __launch_bounds__(256) void k_ffta(const float* __restrict__ x,
                                              float2* __restrict__ Gtmp){
    __shared__ float xr[32 * 126], xi[32 * 126];
    __shared__ float w125r[125], w125i[125];  // e^{-2pi j/125}
    __shared__ float w16r[125],  w16i[125];   // e^{-2pi j/16000}
    __shared__ float w128r[128], w128i[128];  // e^{-2pi j/128}
    const int b = blockIdx.x >> 2, g = blockIdx.x & 3, row0 = 32 * g;
    const int tid = threadIdx.x;

    for (int j = tid; j < 125; j += 256){
        double a = -TWO_PI * (double)j / 125.0;
        w125r[j] = (float)cos(a); w125i[j] = (float)sin(a);
        double a2 = -TWO_PI * (double)j / 16000.0;
        w16r[j] = (float)cos(a2); w16i[j] = (float)sin(a2);
    }
    for (int j = tid; j < 128; j += 256){
        double a = -TWO_PI * (double)j / 128.0;
        w128r[j] = (float)cos(a); w128i[j] = (float)sin(a);
    }
    for (int i = tid; i < 32 * 125; i += 256){
        int n1 = i >> 5, lr = i & 31;
        xr[lr * 126 + n1] = x[b * TLEN + 128 * n1 + row0 + lr];
        xi[lr * 126 + n1] = 0.0f;
    }
    int f = 1;
    for (int s = 25; s >= 1; s /= 5, f *= 5){
        __syncthreads();
        for (int task = tid; task < 25 * 32; task += 256){
            int u = task >> 5, lr = task & 31;
            int blk = u / s, m = u - blk * s;
            int base = lr * 126 + blk * 5 * s + m;
            float vr[5], vi[5];
            #pragma unroll
            for (int r = 0; r < 5; ++r){ vr[r] = xr[base + r * s]; vi[r] = xi[base + r * s]; }
            #pragma unroll
            for (int q = 0; q < 5; ++q){
                float cr = vr[0], ci = vi[0];
                #pragma unroll
                for (int r = 1; r < 5; ++r){
                    int w5 = 25 * ((q * r) % 5);
                    float wr = w125r[w5], wi = w125i[w5];
                    cr += vr[r] * wr - vi[r] * wi;
                    ci += vr[r] * wi + vi[r] * wr;
                }
                int jt = (m * q * f) % 125;
                float tr = w125r[jt], ti = w125i[jt];
                xr[base + q * s] = cr * tr - ci * ti;
                xi[base + q * s] = cr * ti + ci * tr;
            }
        }
    }
    __syncthreads();
    for (int i = tid; i < 125 * 32; i += 256){
        int p = i >> 5, lr = i & 31;
        int n2 = row0 + lr;
        int m = drev125(p);
        int a = m * n2;
        int qq = a / 125, rr = a - qq * 125;
        float tr = w16r[rr] * w128r[qq] - w16i[rr] * w128i[qq];
        float ti = w16r[rr] * w128i[qq] + w16i[rr] * w128r[qq];
        float ar = xr[lr * 126 + p], ai = xi[lr * 126 + p];
        Gtmp[((size_t)b * 125 + p) * 128 + n2] =
            make_float2(ar * tr - ai * ti, ar * ti + ai * tr);
    }
}

// ---- K1b (split): radix-2 over n2 for 25 phys cols; emit k<8000 ----------
__global__ __launch_bounds__(256) void k_fftb(const float2* __restrict__ Gtmp,
                                              float2* __restrict__ Xf){
    __shared__ float gr[128 * 26], gi[128 * 26];
    __shared__ float w128r[128], w128i[128];
    const int b = blockIdx.x / 5, p0 = (blockIdx.x % 5) * 25;
    const int tid = threadIdx.x;
    for (int j = tid; j < 128; j += 256){
        double a = -TWO_PI * (double)j / 128.0;
        w128r[j] = (float)cos(a); w128i[j] = (float)sin(a);
    }
    for (int i = tid; i < 25 * 128; i += 256){
        int ml = i >> 7, n2 = i & 127;
        float2 v = Gtmp[((size_t)b * 125 + p0 + ml) * 128 + n2];
        gr[n2 * 26 + ml] = v.x; gi[n2 * 26 + ml] = v.y;
    }
    for (int span = 64; span >= 1; span >>= 1){
        __syncthreads();
        for (int idx = tid; idx < 1600; idx += 256){
            int u = idx / 25, ml = idx - u * 25;
            int blkq = u / span, mm = u % span;
            int i0 = (blkq * 2 * span + mm) * 26 + ml, i1 = i0 + span * 26;
            float ar = gr[i0], ai = gi[i0], br = gr[i1], bi = gi[i1];
            gr[i0] = ar + br; gi[i0] = ai + bi;
            float dr = ar - br, di = ai - bi;
            int jt = mm * (64 / span);
            gr[i1] = dr * w128r[jt] - di * w128i[jt];
            gi[i1] = dr * w128i[jt] + di * w128r[jt];
        }
    }
    __syncthreads();
    for (int idx = tid; idx < 1600; idx += 256){
        int u = idx / 25, ml = idx - u * 25;
        int ad = (2 * u) * 26 + ml;
        int k = drev125(p0 + ml) + 125 * brev7(2 * u);
        Xf[(size_t)b * KMAX + k] = make_float2(gr[ad], gi[ad]);
    }
}

// ---- K1 fused fallback (used only if ws too small) -----------------------
__global__ __launch_bounds__(512) void k_fft(const float* __restrict__ x,
                                             float2* __restrict__ Xf){
    __shared__ float re[128 * 126];
    __shared__ float im[128 * 126];
    __shared__ float w125r[125], w125i[125];
    __shared__ float w16r[125],  w16i[125];
    __shared__ float w128r[128], w128i[128];
    const int b = blockIdx.x, tid = threadIdx.x;

    for (int j = tid; j < 125; j += 512){
        double a = -TWO_PI * (double)j / 125.0;
        w125r[j] = (float)cos(a); w125i[j] = (float)sin(a);
        double a2 = -TWO_PI * (double)j / 16000.0;
        w16r[j] = (float)cos(a2); w16i[j] = (float)sin(a2);
    }
    for (int j = tid; j < 128; j += 512){
        double a = -TWO_PI * (double)j / 128.0;
        w128r[j] = (float)cos(a); w128i[j] = (float)sin(a);
    }
    for (int gi = tid; gi < TLEN; gi += 512){
        int n2 = gi & 127, n1 = gi >> 7;
        re[n2 * 126 + n1] = x[b * TLEN + gi];
        im[n2 * 126 + n1] = 0.0f;
    }
    int f = 1;
    for (int s = 25; s >= 1; s /= 5, f *= 5){
        __syncthreads();
        for (int task = tid; task < 25 * 128; task += 512){
            int u = task >> 7, n2 = task & 127;
            int blk = u / s, m = u - blk * s;
            int base = n2 * 126 + blk * 5 * s + m;
            float xr[5], xi5[5];
            #pragma unroll
            for (int r = 0; r < 5; ++r){ xr[r] = re[base + r * s]; xi5[r] = im[base + r * s]; }
            #pragma unroll
            for (int q = 0; q < 5; ++q){
                float cr = xr[0], ci = xi5[0];
                #pragma unroll
                for (int r = 1; r < 5; ++r){
                    int w5 = 25 * ((q * r) % 5);
                    float wr = w125r[w5], wi = w125i[w5];
                    cr += xr[r] * wr - xi5[r] * wi;
                    ci += xr[r] * wi + xi5[r] * wr;
                }
                int jt = (m * q * f) % 125;
                float tr = w125r[jt], ti = w125i[jt];
                re[base + q * s] = cr * tr - ci * ti;
                im[base + q * s] = cr * ti + ci * tr;
            }
        }
    }
    __syncthreads();
    for (int idx = tid; idx < TLEN; idx += 512){
        int n2 = idx & 127, p = idx >> 7;
        int m = drev125(p);
        int a = n2 * m;
        int qq = a / 125, rr = a - qq * 125;
        float tr = w16r[rr] * w128r[qq] - w16i[rr] * w128i[qq];
        float ti = w16r[rr] * w128i[qq] + w16i[rr] * w128r[qq];
        int ad = n2 * 126 + p;
        float ar = re[ad], ai = im[ad];
        re[ad] = ar * tr - ai * ti;
        im[ad] = ar * ti + ai * tr;
    }
    for (int span = 64; span >= 1; span >>= 1){
        __syncthreads();
        for (int idx = tid; idx < 64 * 125; idx += 512){
            int u = idx / 125, p = idx - (idx / 125) * 125;
            int blkq = u / span, mm = u % span;
            int i0 = (blkq * 2 * span + mm) * 126 + p, i1 = i0 + span * 126;
            float ar = re[i0], ai = im[i0], br = re[i1], bi = im[i1];
            re[i0] = ar + br; im[i0] = ai + bi;
            float dr = ar - br, di = ai - bi;
            int jt = mm * (64 / span);
            re[i1] = dr * w128r[jt] - di * w128i[jt];
            im[i1] = dr * w128i[jt] + di * w128r[jt];
        }
    }
    __syncthreads();
    for (int idx = tid; idx < 64 * 125; idx += 512){
        int u = idx / 125, p = idx - (idx / 125) * 125;
        int k = drev125(p) + 125 * brev7(2 * u);
        int ad = (2 * u) * 126 + p;
        Xf[(size_t)b * KMAX + k] = make_float2(re[ad], im[ad]);
    }
}

// ---- env5 body (P=125 classes): templated on LOG2Q so all strength
// reduction stays compile-time; w5tab + no-mod twiddle + in-place |z| ------
template<int LQ>
__device__ __forceinline__ void env5_body(const float2* __restrict__ Xfb,
                                          float* __restrict__ Schan,
                                          int fi, int b, int tid,
                                          float* Br, float* Bi,
                                          float* wPr, float* wPi,
                                          float* wNr, float* wNi,
                                          float* wQr, float* wQi,
                                          float* w5tr, float* w5ti,
                                          float* hfull, int* drevT, float* sred){
    constexpr int Q = 1 << LQ;
    constexpr int N = 125 * Q;
    constexpr int D = TLEN / N;

    const double xi_d = 0.35 * exp2(-(double)fi / 6.0);
    const double r_d  = exp2(1.0 / 6.0);
    const double sig_d = xi_d * (r_d - 1.0) / (r_d + 1.0);
    const float xi = (float)xi_d;
    const float centerT = (float)(xi_d * (double)TLEN);
    const float sigT = (float)(sig_d * (double)TLEN);
    int klo = (int)floorf(centerT - 5.0f * sigT); if (klo < 1) klo = 1;
    int khi = (int)ceilf(centerT + 5.0f * sigT);  if (khi > KMAX - 1) khi = KMAX - 1;
    const float inv2s2 = (float)(1.0 / (2.0 * sig_d * sig_d));

    for (int j = tid; j < 125; j += 512){
        double a = TWO_PI * (double)j / 125.0;
        wPr[j] = (float)cos(a); wPi[j] = (float)sin(a);
        double a2 = TWO_PI * (double)j / (double)N;
        wNr[j] = (float)cos(a2); wNi[j] = (float)sin(a2);
        drevT[j] = drev125(j);
    }
    for (int j = tid; j < Q; j += 512){
        double a = TWO_PI * (double)j / (double)Q;
        wQr[j] = (float)cos(a); wQi[j] = (float)sin(a);
    }
    for (int j = tid; j < 25; j += 512){
        double a = TWO_PI * (double)(((j / 5) * (j % 5)) % 5) / 5.0;   // e^{+2pi(qr%5)/5}
        w5tr[j] = (float)cos(a); w5ti[j] = (float)sin(a);
    }
    for (int j = tid; j <= 2 * DHALF; j += 512){
        double st = 1.0 / (TWO_PI * (0.35 / 64.0));
        double dd = (double)(j - DHALF);
        hfull[j] = (float)((0.35 / 64.0) * sqrt(TWO_PI) * exp(-0.5 * dd * dd / (st * st)));
    }
    __syncthreads();
    for (int idx = tid; idx < 125 * Q; idx += 512){
        int j = idx >> LQ, k2 = idx & (Q - 1);
        int gk = k2 + (j << LQ);
        float vr = 0.0f, vi = 0.0f;
        if (gk >= klo && gk <= khi){
            float fr = (float)gk * (1.0f / (float)TLEN);
            float d = fr - xi;
            float p = __expf(-d * d * inv2s2) * (1.0f / (float)TLEN);
            float2 Xv = Xfb[gk];
            vr = Xv.x * p; vi = Xv.y * p;
        }
        Br[idx] = vr; Bi[idx] = vi;
    }
    // 3 radix-5 DIF stages over j (plus sign); jt = m*q*f < 125 always
    int f = 1;
    for (int s = 25; s >= 1; s /= 5, f *= 5){
        __syncthreads();
        for (int task = tid; task < 25 * Q; task += 512){
            int u = task >> LQ, k2 = task & (Q - 1);
            int blk = u / s, m = u - blk * s;
            int base = (blk * 5 * s + m) * Q + k2;
            float xr[5], xi5[5];
            #pragma unroll
            for (int r = 0; r < 5; ++r){ xr[r] = Br[base + r * s * Q]; xi5[r] = Bi[base + r * s * Q]; }
            #pragma unroll
            for (int q = 0; q < 5; ++q){
                float cr = xr[0], ci = xi5[0];
                #pragma unroll
                for (int r = 1; r < 5; ++r){
                    float wr = w5tr[q * 5 + r], wi = w5ti[q * 5 + r];
                    cr += xr[r] * wr - xi5[r] * wi;
                    ci += xr[r] * wi + xi5[r] * wr;
                }
                int jt = m * q * f;           // < 125, no mod needed
                float tr = wPr[jt], ti = wPi[jt];
                Br[base + q * s * Q] = cr * tr - ci * ti;
                Bi[base + q * s * Q] = cr * ti + ci * tr;
            }
        }
    }
    __syncthreads();
    // twiddle W_N^{+k2 n1}, n1 = drev125(p)
    for (int idx = tid; idx < 125 * Q; idx += 512){
        int p = idx >> LQ, k2 = idx & (Q - 1);
        int n1 = drevT[p];
        int a = k2 * n1;
        int qq = a / 125, rr = a - qq * 125;
        float tr = wQr[qq] * wNr[rr] - wQi[qq] * wNi[rr];
        float ti = wQr[qq] * wNi[rr] + wQi[qq] * wNr[rr];
        float ar = Br[idx], ai = Bi[idx];
        Br[idx] = ar * tr - ai * ti;
        Bi[idx] = ar * ti + ai * tr;
    }
    // radix-2 DIF over k2 (plus sign), per row p
    for (int span = Q / 2; span >= 1; span >>= 1){
        __syncthreads();
        for (int idx = tid; idx < 125 * (Q / 2); idx += 512){
            int p = idx / (Q / 2), u = idx - p * (Q / 2);
            int blkq = u / span, mm = u % span;
            int i0 = p * Q + blkq * 2 * span + mm, i1 = i0 + span;
            float ar = Br[i0], ai = Bi[i0], br = Br[i1], bi = Bi[i1];
            Br[i0] = ar + br; Bi[i0] = ai + bi;
            float dr = ar - br, di = ai - bi;
            int jt = mm * ((Q / 2) / span);
            Br[i1] = dr * wQr[jt] - di * wQi[jt];
            Bi[i1] = dr * wQi[jt] + di * wQr[jt];
        }
    }
    __syncthreads();
    // in-place |z| into Br
    for (int idx = tid; idx < 125 * Q; idx += 512){
        float vr = Br[idx], vi = Bi[idx];
        Br[idx] = sqrtf(vr * vr + vi * vi);
    }
    __syncthreads();
    // conv: S1[t] = D * sum_n phi(64t - Dn) Br[map(n)], taps split 2 ways
    float acc = 0.0f;
    if (tid < 500){
        int t = tid - 250 * (tid / 250);
        int q = tid / 250;
        int m0 = 64 * t;
        int lo = m0 - DHALF;
        int nlo = (lo >= 0) ? ((lo + D - 1) / D) : -((-lo) / D);
        int nhi = (m0 + DHALF) / D;
        int n = nlo + q;
        if (n <= nhi){
            int np = n % N; if (np < 0) np += N;
            int n1 = np % 125, n2 = np / 125;
            int d = m0 - D * n + DHALF;
            for (; n <= nhi; n += 2){
                int p = drevT[n1];
                int s2 = (int)(__brev((unsigned)n2) >> (32 - LQ));
                acc += hfull[d] * Br[(p << LQ) + s2];
                d -= 2 * D;
                n1 += 2; if (n1 >= 125){ n1 -= 125; ++n2; if (n2 >= Q) n2 -= Q; }
            }
        }
        sred[tid] = acc;
    }
    __syncthreads();
    if (tid < 250)
        Schan[(b * NCH + 1 + fi) * NOUT + tid] = (sred[tid] + sred[tid + 250]) * (float)D;
}

// ---- K2a merged dispatch: all P=125 classes in one grid (960 blocks) -----
__global__ __launch_bounds__(512, 4) void k_env5_all(const float2* __restrict__ Xf,
                                                     float* __restrict__ Schan){
    __shared__ float Br[8000], Bi[8000];
    __shared__ float wPr[125], wPi[125];
    __shared__ float wNr[125], wNi[125];
    __shared__ float wQr[64], wQi[64];
    __shared__ float w5tr[25], w5ti[25];
    __shared__ float hfull[2 * DHALF + 1];
    __shared__ int   drevT[125];
    __shared__ float sred[500];

    const int bi = blockIdx.x;
    const int tid = threadIdx.x;
    if (bi < 448){                 // N=8000, D=2, fi 0-6
        int fi = bi >> 6, b = bi & 63;
        env5_body<6>(Xf + (size_t)b * KMAX, Schan, fi, b, tid, Br, Bi,
                     wPr, wPi, wNr, wNi, wQr, wQi, w5tr, w5ti, hfull, drevT, sred);
    } else if (bi < 640){          // N=4000, D=4, fi 7-9
        int t = bi - 448;
        int fi = 7 + (t >> 6), b = t & 63;
        env5_body<5>(Xf + (size_t)b * KMAX, Schan, fi, b, tid, Br, Bi,
                     wPr, wPi, wNr, wNi, wQr, wQi, w5tr, w5ti, hfull, drevT, sred);
    } else {                       // N=2000, D=8, fi 17-21
        int t = bi - 640;
        int fi = 17 + (t >> 6), b = t & 63;
        env5_body<4>(Xf + (size_t)b * KMAX, Schan, fi, b, tid, Br, Bi,
                     wPr, wPi, wNr, wNi, wQr, wQi, w5tr, w5ti, hfull, drevT, sred);
    }
}

// ---- K2b (P=25 classes): round-7 direct-gather kernel, verbatim ----------
template<int P, int LOG2Q, int CN1, int CBPC>
__global__ __launch_bounds__(256) void k_env(const float2* __restrict__ Xf,
                                             float* __restrict__ Schan,
                                             int fi0){
    constexpr int Q = 1 << LOG2Q;
    constexpr int N = P * Q;
    constexpr int D = TLEN / N;
    constexpr int NCHK = (P + CN1 - 1) / CN1;
    constexpr int MAGSZ = N + N / 32 + 2;
    __shared__ __align__(16) float cbp[2 * CBPC];
    __shared__ float Br[Q * CN1], Bi[Q * CN1];
    __shared__ float Mag[MAGSZ];
    __shared__ float wPr[P], wPi[P];
    __shared__ float wQr[Q], wQi[Q];
    __shared__ float wNr[P], wNi[P];
    __shared__ float hfull[2 * DHALF + 1];

    const int fi = fi0 + (int)(blockIdx.x >> 6);
    const int b = blockIdx.x & 63;
    const int tid = threadIdx.x;
    const float2* __restrict__ Xfb = Xf + (size_t)b * KMAX;

    const double xi_d = 0.35 * exp2(-(double)fi / 6.0);
    const double r_d  = exp2(1.0 / 6.0);
    const double sig_d = xi_d * (r_d - 1.0) / (r_d + 1.0);
    const float xi = (float)xi_d;
    const float centerT = (float)(xi_d * (double)TLEN);
    const float sigT = (float)(sig_d * (double)TLEN);
    int klo = (int)floorf(centerT - 5.0f * sigT); if (klo < 1) klo = 1;
    int khi = (int)ceilf(centerT + 5.0f * sigT);  if (khi > KMAX - 1) khi = KMAX - 1;
    const int W = khi - klo + 1;
    const float inv2s2 = (float)(1.0 / (2.0 * sig_d * sig_d));
    const int PADc = 128 + (klo & 1);

    for (int j = tid; j < P; j += 256){
        double a = TWO_PI * (double)j / (double)P;
        wPr[j] = (float)cos(a); wPi[j] = (float)sin(a);
        double a2 = TWO_PI * (double)j / (double)N;
        wNr[j] = (float)cos(a2); wNi[j] = (float)sin(a2);
    }
    for (int j = tid; j < Q; j += 256){
        double a = TWO_PI * (double)j / (double)Q;
        wQr[j] = (float)cos(a); wQi[j] = (float)sin(a);
    }
    for (int j = tid; j <= 2 * DHALF; j += 256){
        double st = 1.0 / (TWO_PI * (0.35 / 64.0));
        double dd = (double)(j - DHALF);
        hfull[j] = (float)((0.35 / 64.0) * sqrt(TWO_PI) * exp(-0.5 * dd * dd / (st * st)));
    }
    for (int j = tid; j < 2 * CBPC; j += 256) cbp[j] = 0.0f;
    __syncthreads();
    for (int idx = tid; idx < W; idx += 256){
        int k = klo + idx;
        float fr = (float)k * (1.0f / (float)TLEN);
        float d = fr - xi;
        float p = __expf(-d * d * inv2s2) * (1.0f / (float)TLEN);
        float2 Xv = Xfb[k];
        cbp[2 * (PADc + idx)]     = Xv.x * p;
        cbp[2 * (PADc + idx) + 1] = Xv.y * p;
    }
    __syncthreads();

    for (int cc = 0; cc < NCHK; ++cc){
        const int ncols = (P - cc * CN1 < CN1) ? (P - cc * CN1) : CN1;
        for (int task = tid; task < (Q / 4) * CN1; task += 256){
            int gq = task / CN1, col = task % CN1;
            if (col < ncols){
                int n1 = cc * CN1 + col;
                int k2 = 4 * gq;
                int jlo = (klo - k2 + Q - 1) >> LOG2Q;
                int jhi = (khi - k2) >> LOG2Q;
                int jj0 = (jlo * n1) % P;
                float wr = wPr[jj0], wi = wPi[jj0];
                float sr = wPr[n1], si = wPi[n1];
                float ar0=0,ai0=0, ar1=0,ai1=0, ar2=0,ai2=0, ar3=0,ai3=0;
                int ic = k2 + (jlo << LOG2Q) - klo + PADc;
                for (int j = jlo; j <= jhi; ++j){
                    float4 c01 = *reinterpret_cast<const float4*>(&cbp[2 * ic]);
                    float4 c23 = *reinterpret_cast<const float4*>(&cbp[2 * ic + 4]);
                    ar0 += c01.x*wr - c01.y*wi;  ai0 += c01.x*wi + c01.y*wr;
                    ar1 += c01.z*wr - c01.w*wi;  ai1 += c01.z*wi + c01.w*wr;
                    ar2 += c23.x*wr - c23.y*wi;  ai2 += c23.x*wi + c23.y*wr;
                    ar3 += c23.z*wr - c23.w*wi;  ai3 += c23.z*wi + c23.w*wr;
                    float t = wr*sr - wi*si; wi = wr*si + wi*sr; wr = t;
                    ic += Q;
                }
                float accr[4] = {ar0, ar1, ar2, ar3};
                float acci[4] = {ai0, ai1, ai2, ai3};
                #pragma unroll
                for (int jj = 0; jj < 4; ++jj){
                    int a = (k2 + jj) * n1;
                    int q = a / P, rr = a - q * P;
                    float tr = wQr[q] * wNr[rr] - wQi[q] * wNi[rr];
                    float ti = wQr[q] * wNi[rr] + wQi[q] * wNr[rr];
                    int o = (k2 + jj) * CN1 + col;
                    Br[o] = accr[jj] * tr - acci[jj] * ti;
                    Bi[o] = accr[jj] * ti + acci[jj] * tr;
                }
            }
        }
        for (int span = Q / 2; span >= 1; span >>= 1){
            __syncthreads();
            for (int idx = tid; idx < (Q / 2) * CN1; idx += 256){
                int u = idx / CN1, col = idx % CN1;
                int blkq = u / span, mm = u % span;
                int p0 = blkq * 2 * span + mm;
                int i0 = p0 * CN1 + col, i1 = i0 + span * CN1;
                float ar = Br[i0], ai = Bi[i0], br = Br[i1], bi = Bi[i1];
                Br[i0] = ar + br; Bi[i0] = ai + bi;
                float dr = ar - br, di = ai - bi;
                int jt = mm * ((Q / 2) / span);
                Br[i1] = dr * wQr[jt] - di * wQi[jt];
                Bi[i1] = dr * wQi[jt] + di * wQr[jt];
            }
        }
        __syncthreads();
        for (int idx = tid; idx < Q * CN1; idx += 256){
            int p = idx / CN1, col = idx % CN1;
            if (col < ncols){
                int n1 = cc * CN1 + col;
                int n2 = (int)(__brev((unsigned)p) >> (32 - LOG2Q));
                int np = n1 + P * n2;
                Mag[np + (np >> 5)] = sqrtf(Br[idx] * Br[idx] + Bi[idx] * Bi[idx]);
            }
        }
        __syncthreads();
    }
    if (tid < NOUT){
        int m0 = 64 * tid;
        int lo = m0 - DHALF;
        int nlo = (lo >= 0) ? ((lo + D - 1) / D) : -((-lo) / D);
        int nhi = (m0 + DHALF) / D;
        int np = nlo % N; if (np < 0) np += N;
        float acc = 0.0f;
        int d = m0 - D * nlo + DHALF;
        for (int n = nlo; n <= nhi; ++n){
            acc += hfull[d] * Mag[np + (np >> 5)];
            d -= D;
            ++np; if (np == N) np = 0;
        }
        Schan[(b * NCH + 1 + fi) * NOUT + tid] = acc * (float)D;
    }
}

// ---- K3: S0 = (x * gaussian)[::64] directly from x -----------------------
__global__ __launch_bounds__(256) void k_s0(const float* __restrict__ x,
                                            float* __restrict__ Schan){
    __shared__ float hwin[DHALF + 1];
    const int b = blockIdx.x, tid = threadIdx.x;
    for (int j = tid; j <= DHALF; j += 256){
        double st = 1.0 / (TWO_PI * (0.35 / 64.0));
        hwin[j] = (float)((0.35 / 64.0) * sqrt(TWO_PI) * exp(-0.5 * (double)(j * j) / (st * st)));
    }
    __syncthreads();
    if (tid < NOUT){
        float acc = 0.0f;
        int n = 64 * tid - DHALF; if (n < 0) n += TLEN;
        for (int d = -DHALF; d <= DHALF; ++d){
            int ad = d < 0 ? -d : d;
            acc += hwin[ad] * x[b * TLEN + n];
            ++n; if (n == TLEN) n = 0;
        }
        Schan[(b * NCH + 0) * NOUT + tid] = acc;
    }
}

// ---- K4: channel-group means -> f32 --------------------------------------
__global__ __launch_bounds__(256) void k_reduce(const float* __restrict__ Schan,
                                                float* __restrict__ out){
    int o = blockIdx.x * 256 + threadIdx.x;
    if (o >= NBATCH * 3 * NOUT) return;
    int b = o / (3 * NOUT);
    int rem = o - b * 3 * NOUT;
    int g = rem / NOUT;
    int t = rem - g * NOUT;
    int c0 = (g == 0) ? 0 : (g == 1 ? 12 : 24);
    int c1 = (g == 0) ? 12 : (g == 1 ? 24 : 37);
    float s = 0.0f;
    for (int c = c0; c < c1; ++c) s += Schan[(b * NCH + c) * NOUT + t];
    out[o] = s / (float)(c1 - c0);
}

__global__ void k_fill_f32(float* out, int n, float v){
    int i = blockIdx.x * 256 + threadIdx.x;
    if (i < n) out[i] = v;
}

extern "C" void kernel_launch(void* const* d_in, const int* in_sizes, int n_in,
                              void* d_out, int out_size, void* d_ws, size_t ws_size,
                              hipStream_t stream) {
    const float* x = (const float*)d_in[0];
    float* out = (float*)d_out;
    const size_t xf_bytes = (size_t)NBATCH * KMAX * sizeof(float2);          // 4.10 MB
    const size_t schan_bytes = (size_t)NBATCH * NCH * NOUT * sizeof(float);  // 2.37 MB
    const size_t gtmp_bytes = (size_t)NBATCH * 16000 * sizeof(float2);       // 8.19 MB
    if (ws_size < xf_bytes + schan_bytes){
        k_fill_f32<<<(out_size + 255) / 256, 256, 0, stream>>>(out, out_size, 800.0f);
        return;
    }
    float2* Xf = (float2*)d_ws;
    float* Schan = (float*)((char*)d_ws + xf_bytes);

    if (ws_size >= xf_bytes + schan_bytes + gtmp_bytes){
        float2* Gtmp = (float2*)((char*)d_ws + xf_bytes + schan_bytes);
        k_ffta<<<NBATCH * 4, 256, 0, stream>>>(x, Gtmp);
        k_fftb<<<NBATCH * 5, 256, 0, stream>>>(Gtmp, Xf);
    } else {
        k_fft<<<NBATCH, 512, 0, stream>>>(x, Xf);
    }
    // P=125 classes, one full-GPU dispatch (N=8000/4000/2000):
    k_env5_all<<<960, 512, 0, stream>>>(Xf, Schan);
    // P=25 classes (direct gather, verbatim):
    k_env< 25, 7, 25, 1176><<< 7 * 64, 256, 0, stream>>>(Xf, Schan, 10); // N=3200 D=5
    k_env< 25, 6, 25,  408><<<14 * 64, 256, 0, stream>>>(Xf, Schan, 22); // N=1600 D=10
    k_s0<<<NBATCH, 256, 0, stream>>>(x, Schan);
    k_reduce<<<(NBATCH * 3 * NOUT + 255) / 256, 256, 0, stream>>>(Schan, out);
}

// Round 11
// 177.254 us; speedup vs baseline: 13.4552x; 1.0365x over previous
//
#include <hip/hip_runtime.h>
#include <hip/hip_bf16.h>

#define TLEN 16000
#define NPSI 36
#define NBATCH 64
#define NOUT 250
#define NCH 37
#define DHALF 176            // Gaussian lowpass half-width (6.05 sigma, sigma_t=29.1)
#define KMAX 8000
#define TWO_PI 6.283185307179586

__device__ __forceinline__ int brev7(int q){ return (int)(__brev((unsigned)q) >> 25); }
__device__ __forceinline__ int drev125(int p){
    return (p % 5) * 25 + ((p / 5) % 5) * 5 + (p / 25);
}

// ---- K1a (split): radix-5 over n1 for 32 n2-rows + W16000 twiddle --------
__global__ __launch_bounds__(256) void k_ffta(const float* __restrict__ x,
                                              float2* __restrict__ Gtmp){
    __shared__ float xr[32 * 126], xi[32 * 126];
    __shared__ float w125r[125], w125i[125];  // e^{-2pi j/125}
    __shared__ float w16r[125],  w16i[125];   // e^{-2pi j/16000}
    __shared__ float w128r[128], w128i[128];  // e^{-2pi j/128}
    const int b = blockIdx.x >> 2, g = blockIdx.x & 3, row0 = 32 * g;
    const int tid = threadIdx.x;

    for (int j = tid; j < 125; j += 256){
        double a = -TWO_PI * (double)j / 125.0;
        w125r[j] = (float)cos(a); w125i[j] = (float)sin(a);
        double a2 = -TWO_PI * (double)j / 16000.0;
        w16r[j] = (float)cos(a2); w16i[j] = (float)sin(a2);
    }
    for (int j = tid; j < 128; j += 256){
        double a = -TWO_PI * (double)j / 128.0;
        w128r[j] = (float)cos(a); w128i[j] = (float)sin(a);
    }
    for (int i = tid; i < 32 * 125; i += 256){
        int n1 = i >> 5, lr = i & 31;
        xr[lr * 126 + n1] = x[b * TLEN + 128 * n1 + row0 + lr];
        xi[lr * 126 + n1] = 0.0f;
    }
    int f = 1;
    for (int s = 25; s >= 1; s /= 5, f *= 5){
        __syncthreads();
        for (int task = tid; task < 25 * 32; task += 256){
            int u = task >> 5, lr = task & 31;
            int blk = u / s, m = u - blk * s;
            int base = lr * 126 + blk * 5 * s + m;
            float vr[5], vi[5];
            #pragma unroll
            for (int r = 0; r < 5; ++r){ vr[r] = xr[base + r * s]; vi[r] = xi[base + r * s]; }
            #pragma unroll
            for (int q = 0; q < 5; ++q){
                float cr = vr[0], ci = vi[0];
                #pragma unroll
                for (int r = 1; r < 5; ++r){
                    int w5 = 25 * ((q * r) % 5);
                    float wr = w125r[w5], wi = w125i[w5];
                    cr += vr[r] * wr - vi[r] * wi;
                    ci += vr[r] * wi + vi[r] * wr;
                }
                int jt = (m * q * f) % 125;
                float tr = w125r[jt], ti = w125i[jt];
                xr[base + q * s] = cr * tr - ci * ti;
                xi[base + q * s] = cr * ti + ci * tr;
            }
        }
    }
    __syncthreads();
    for (int i = tid; i < 125 * 32; i += 256){
        int p = i >> 5, lr = i & 31;
        int n2 = row0 + lr;
        int m = drev125(p);
        int a = m * n2;
        int qq = a / 125, rr = a - qq * 125;
        float tr = w16r[rr] * w128r[qq] - w16i[rr] * w128i[qq];
        float ti = w16r[rr] * w128i[qq] + w16i[rr] * w128r[qq];
        float ar = xr[lr * 126 + p], ai = xi[lr * 126 + p];
        Gtmp[((size_t)b * 125 + p) * 128 + n2] =
            make_float2(ar * tr - ai * ti, ar * ti + ai * tr);
    }
}

// ---- K1b (split): radix-2 over n2 for 25 phys cols; emit k<8000 ----------
__global__ __launch_bounds__(256) void k_fftb(const float2* __restrict__ Gtmp,
                                              float2* __restrict__ Xf){
    __shared__ float gr[128 * 26], gi[128 * 26];
    __shared__ float w128r[128], w128i[128];
    const int b = blockIdx.x / 5, p0 = (blockIdx.x % 5) * 25;
    const int tid = threadIdx.x;
    for (int j = tid; j < 128; j += 256){
        double a = -TWO_PI * (double)j / 128.0;
        w128r[j] = (float)cos(a); w128i[j] = (float)sin(a);
    }
    for (int i = tid; i < 25 * 128; i += 256){
        int ml = i >> 7, n2 = i & 127;
        float2 v = Gtmp[((size_t)b * 125 + p0 + ml) * 128 + n2];
        gr[n2 * 26 + ml] = v.x; gi[n2 * 26 + ml] = v.y;
    }
    for (int span = 64; span >= 1; span >>= 1){
        __syncthreads();
        for (int idx = tid; idx < 1600; idx += 256){
            int u = idx / 25, ml = idx - u * 25;
            int blkq = u / span, mm = u % span;
            int i0 = (blkq * 2 * span + mm) * 26 + ml, i1 = i0 + span * 26;
            float ar = gr[i0], ai = gi[i0], br = gr[i1], bi = gi[i1];
            gr[i0] = ar + br; gi[i0] = ai + bi;
            float dr = ar - br, di = ai - bi;
            int jt = mm * (64 / span);
            gr[i1] = dr * w128r[jt] - di * w128i[jt];
            gi[i1] = dr * w128i[jt] + di * w128r[jt];
        }
    }
    __syncthreads();
    for (int idx = tid; idx < 1600; idx += 256){
        int u = idx / 25, ml = idx - u * 25;
        int ad = (2 * u) * 26 + ml;
        int k = drev125(p0 + ml) + 125 * brev7(2 * u);
        Xf[(size_t)b * KMAX + k] = make_float2(gr[ad], gi[ad]);
    }
}

// ---- K1 fused fallback (used only if ws too small) -----------------------
__global__ __launch_bounds__(512) void k_fft(const float* __restrict__ x,
                                             float2* __restrict__ Xf){
    __shared__ float re[128 * 126];
    __shared__ float im[128 * 126];
    __shared__ float w125r[125], w125i[125];
    __shared__ float w16r[125],  w16i[125];
    __shared__ float w128r[128], w128i[128];
    const int b = blockIdx.x, tid = threadIdx.x;

    for (int j = tid; j < 125; j += 512){
        double a = -TWO_PI * (double)j / 125.0;
        w125r[j] = (float)cos(a); w125i[j] = (float)sin(a);
        double a2 = -TWO_PI * (double)j / 16000.0;
        w16r[j] = (float)cos(a2); w16i[j] = (float)sin(a2);
    }
    for (int j = tid; j < 128; j += 512){
        double a = -TWO_PI * (double)j / 128.0;
        w128r[j] = (float)cos(a); w128i[j] = (float)sin(a);
    }
    for (int gi = tid; gi < TLEN; gi += 512){
        int n2 = gi & 127, n1 = gi >> 7;
        re[n2 * 126 + n1] = x[b * TLEN + gi];
        im[n2 * 126 + n1] = 0.0f;
    }
    int f = 1;
    for (int s = 25; s >= 1; s /= 5, f *= 5){
        __syncthreads();
        for (int task = tid; task < 25 * 128; task += 512){
            int u = task >> 7, n2 = task & 127;
            int blk = u / s, m = u - blk * s;
            int base = n2 * 126 + blk * 5 * s + m;
            float xr[5], xi5[5];
            #pragma unroll
            for (int r = 0; r < 5; ++r){ xr[r] = re[base + r * s]; xi5[r] = im[base + r * s]; }
            #pragma unroll
            for (int q = 0; q < 5; ++q){
                float cr = xr[0], ci = xi5[0];
                #pragma unroll
                for (int r = 1; r < 5; ++r){
                    int w5 = 25 * ((q * r) % 5);
                    float wr = w125r[w5], wi = w125i[w5];
                    cr += xr[r] * wr - xi5[r] * wi;
                    ci += xr[r] * wi + xi5[r] * wr;
                }
                int jt = (m * q * f) % 125;
                float tr = w125r[jt], ti = w125i[jt];
                re[base + q * s] = cr * tr - ci * ti;
                im[base + q * s] = cr * ti + ci * tr;
            }
        }
    }
    __syncthreads();
    for (int idx = tid; idx < TLEN; idx += 512){
        int n2 = idx & 127, p = idx >> 7;
        int m = drev125(p);
        int a = n2 * m;
        int qq = a / 125, rr = a - qq * 125;
        float tr = w16r[rr] * w128r[qq] - w16i[rr] * w128i[qq];
        float ti = w16r[rr] * w128i[qq] + w16i[rr] * w128r[qq];
        int ad = n2 * 126 + p;
        float ar = re[ad], ai = im[ad];
        re[ad] = ar * tr - ai * ti;
        im[ad] = ar * ti + ai * tr;
    }
    for (int span = 64; span >= 1; span >>= 1){
        __syncthreads();
        for (int idx = tid; idx < 64 * 125; idx += 512){
            int u = idx / 125, p = idx - (idx / 125) * 125;
            int blkq = u / span, mm = u % span;
            int i0 = (blkq * 2 * span + mm) * 126 + p, i1 = i0 + span * 126;
            float ar = re[i0], ai = im[i0], br = re[i1], bi = im[i1];
            re[i0] = ar + br; im[i0] = ai + bi;
            float dr = ar - br, di = ai - bi;
            int jt = mm * (64 / span);
            re[i1] = dr * w128r[jt] - di * w128i[jt];
            im[i1] = dr * w128i[jt] + di * w128r[jt];
        }
    }
    __syncthreads();
    for (int idx = tid; idx < 64 * 125; idx += 512){
        int u = idx / 125, p = idx - (idx / 125) * 125;
        int k = drev125(p) + 125 * brev7(2 * u);
        int ad = (2 * u) * 126 + p;
        Xf[(size_t)b * KMAX + k] = make_float2(re[ad], im[ad]);
    }
}

// ---- env body, generalized: P5 in {125,25} radix-5 stage-1 over j,
// twiddle, radix-2 over k2, in-place |z|, Gaussian conv at stride D --------
template<int P5, int LQ>
__device__ __forceinline__ void env_body(const float2* __restrict__ Xfb,
                                         float* __restrict__ Schan,
                                         int fi, int b, int tid,
                                         float* Br, float* Bi,
                                         float* wPr, float* wPi,
                                         float* wNr, float* wNi,
                                         float* wQr, float* wQi,
                                         float* w5tr, float* w5ti,
                                         float* hfull, int* drevT, float* sred){
    constexpr int Q = 1 << LQ;
    constexpr int N = P5 * Q;
    constexpr int D = TLEN / N;

    const double xi_d = 0.35 * exp2(-(double)fi / 6.0);
    const double r_d  = exp2(1.0 / 6.0);
    const double sig_d = xi_d * (r_d - 1.0) / (r_d + 1.0);
    const float xi = (float)xi_d;
    const float centerT = (float)(xi_d * (double)TLEN);
    const float sigT = (float)(sig_d * (double)TLEN);
    int klo = (int)floorf(centerT - 5.0f * sigT); if (klo < 1) klo = 1;
    int khi = (int)ceilf(centerT + 5.0f * sigT);  if (khi > KMAX - 1) khi = KMAX - 1;
    const float inv2s2 = (float)(1.0 / (2.0 * sig_d * sig_d));

    for (int j = tid; j < P5; j += 512){
        double a = TWO_PI * (double)j / (double)P5;
        wPr[j] = (float)cos(a); wPi[j] = (float)sin(a);
        double a2 = TWO_PI * (double)j / (double)N;
        wNr[j] = (float)cos(a2); wNi[j] = (float)sin(a2);
        drevT[j] = (P5 == 125) ? drev125(j) : ((j % 5) * 5 + j / 5);
    }
    for (int j = tid; j < Q; j += 512){
        double a = TWO_PI * (double)j / (double)Q;
        wQr[j] = (float)cos(a); wQi[j] = (float)sin(a);
    }
    for (int j = tid; j < 25; j += 512){
        double a = TWO_PI * (double)(((j / 5) * (j % 5)) % 5) / 5.0;   // e^{+2pi(qr%5)/5}
        w5tr[j] = (float)cos(a); w5ti[j] = (float)sin(a);
    }
    for (int j = tid; j <= 2 * DHALF; j += 512){
        double st = 1.0 / (TWO_PI * (0.35 / 64.0));
        double dd = (double)(j - DHALF);
        hfull[j] = (float)((0.35 / 64.0) * sqrt(TWO_PI) * exp(-0.5 * dd * dd / (st * st)));
    }
    __syncthreads();
    // init B[j][k2] = psi-weighted C[k2 + Q j]
    for (int idx = tid; idx < N; idx += 512){
        int j = idx >> LQ, k2 = idx & (Q - 1);
        int gk = k2 + (j << LQ);
        float vr = 0.0f, vi = 0.0f;
        if (gk >= klo && gk <= khi){
            float fr = (float)gk * (1.0f / (float)TLEN);
            float d = fr - xi;
            float p = __expf(-d * d * inv2s2) * (1.0f / (float)TLEN);
            float2 Xv = Xfb[gk];
            vr = Xv.x * p; vi = Xv.y * p;
        }
        Br[idx] = vr; Bi[idx] = vi;
    }
    // radix-5 DIF stages over j (plus sign); jt = m*q*f < P5 always
    int f = 1;
    for (int s = P5 / 5; s >= 1; s /= 5, f *= 5){
        __syncthreads();
        for (int task = tid; task < (P5 / 5) * Q; task += 512){
            int u = task >> LQ, k2 = task & (Q - 1);
            int blk = u / s, m = u - blk * s;
            int base = (blk * 5 * s + m) * Q + k2;
            float xr[5], xi5[5];
            #pragma unroll
            for (int r = 0; r < 5; ++r){ xr[r] = Br[base + r * s * Q]; xi5[r] = Bi[base + r * s * Q]; }
            #pragma unroll
            for (int q = 0; q < 5; ++q){
                float cr = xr[0], ci = xi5[0];
                #pragma unroll
                for (int r = 1; r < 5; ++r){
                    float wr = w5tr[q * 5 + r], wi = w5ti[q * 5 + r];
                    cr += xr[r] * wr - xi5[r] * wi;
                    ci += xr[r] * wi + xi5[r] * wr;
                }
                int jt = m * q * f;           // < P5, no mod needed
                float tr = wPr[jt], ti = wPi[jt];
                Br[base + q * s * Q] = cr * tr - ci * ti;
                Bi[base + q * s * Q] = cr * ti + ci * tr;
            }
        }
    }
    __syncthreads();
    // twiddle W_N^{+k2 n1}, n1 = drevP5(p);  a = P5*qq + rr
    for (int idx = tid; idx < N; idx += 512){
        int p = idx >> LQ, k2 = idx & (Q - 1);
        int n1 = drevT[p];
        int a = k2 * n1;
        int qq = a / P5, rr = a - qq * P5;
        float tr = wQr[qq] * wNr[rr] - wQi[qq] * wNi[rr];
        float ti = wQr[qq] * wNi[rr] + wQi[qq] * wNr[rr];
        float ar = Br[idx], ai = Bi[idx];
        Br[idx] = ar * tr - ai * ti;
        Bi[idx] = ar * ti + ai * tr;
    }
    // radix-2 DIF over k2 (plus sign), per row p
    for (int span = Q / 2; span >= 1; span >>= 1){
        __syncthreads();
        for (int idx = tid; idx < P5 * (Q / 2); idx += 512){
            int p = idx / (Q / 2), u = idx - p * (Q / 2);
            int blkq = u / span, mm = u % span;
            int i0 = p * Q + blkq * 2 * span + mm, i1 = i0 + span;
            float ar = Br[i0], ai = Bi[i0], br = Br[i1], bi = Bi[i1];
            Br[i0] = ar + br; Bi[i0] = ai + bi;
            float dr = ar - br, di = ai - bi;
            int jt = mm * ((Q / 2) / span);
            Br[i1] = dr * wQr[jt] - di * wQi[jt];
            Bi[i1] = dr * wQi[jt] + di * wQr[jt];
        }
    }
    __syncthreads();
    // in-place |z| into Br
    for (int idx = tid; idx < N; idx += 512){
        float vr = Br[idx], vi = Bi[idx];
        Br[idx] = sqrtf(vr * vr + vi * vi);
    }
    __syncthreads();
    // conv: S1[t] = D * sum_n phi(64t - Dn) Br[map(n)], taps split 2 ways
    float acc = 0.0f;
    if (tid < 500){
        int t = tid - 250 * (tid / 250);
        int q = tid / 250;
        int m0 = 64 * t;
        int lo = m0 - DHALF;
        int nlo = (lo >= 0) ? ((lo + D - 1) / D) : -((-lo) / D);
        int nhi = (m0 + DHALF) / D;
        int n = nlo + q;
        if (n <= nhi){
            int np = n % N; if (np < 0) np += N;
            int n1 = np % P5, n2 = np / P5;
            int d = m0 - D * n + DHALF;
            for (; n <= nhi; n += 2){
                int p = drevT[n1];
                int s2 = (int)(__brev((unsigned)n2) >> (32 - LQ));
                acc += hfull[d] * Br[(p << LQ) + s2];
                d -= 2 * D;
                n1 += 2; if (n1 >= P5){ n1 -= P5; ++n2; if (n2 >= Q) n2 -= Q; }
            }
        }
        sred[tid] = acc;
    }
    __syncthreads();
    if (tid < 250)
        Schan[(b * NCH + 1 + fi) * NOUT + tid] = (sred[tid] + sred[tid + 250]) * (float)D;
}

// ---- K2: ALL 36 filter channels in one 2304-block dispatch ---------------
// Classes ordered by descending per-block cost (N): 8000,4000,3200,2000,1600.
__global__ __launch_bounds__(512, 4) void k_env_all(const float2* __restrict__ Xf,
                                                    float* __restrict__ Schan){
    __shared__ float Br[8000], Bi[8000];
    __shared__ float wPr[125], wPi[125];
    __shared__ float wNr[125], wNi[125];
    __shared__ float wQr[128], wQi[128];
    __shared__ float w5tr[25], w5ti[25];
    __shared__ float hfull[2 * DHALF + 1];
    __shared__ int   drevT[125];
    __shared__ float sred[500];

    const int bi = blockIdx.x;
    const int tid = threadIdx.x;
    if (bi < 448){                         // N=8000, D=2,  fi 0-6
        int fi = bi >> 6, b = bi & 63;
        env_body<125, 6>(Xf + (size_t)b * KMAX, Schan, fi, b, tid, Br, Bi,
                         wPr, wPi, wNr, wNi, wQr, wQi, w5tr, w5ti, hfull, drevT, sred);
    } else if (bi < 640){                  // N=4000, D=4,  fi 7-9
        int t = bi - 448;
        int fi = 7 + (t >> 6), b = t & 63;
        env_body<125, 5>(Xf + (size_t)b * KMAX, Schan, fi, b, tid, Br, Bi,
                         wPr, wPi, wNr, wNi, wQr, wQi, w5tr, w5ti, hfull, drevT, sred);
    } else if (bi < 1088){                 // N=3200, D=5,  fi 10-16
        int t = bi - 640;
        int fi = 10 + (t >> 6), b = t & 63;
        env_body<25, 7>(Xf + (size_t)b * KMAX, Schan, fi, b, tid, Br, Bi,
                        wPr, wPi, wNr, wNi, wQr, wQi, w5tr, w5ti, hfull, drevT, sred);
    } else if (bi < 1408){                 // N=2000, D=8,  fi 17-21
        int t = bi - 1088;
        int fi = 17 + (t >> 6), b = t & 63;
        env_body<125, 4>(Xf + (size_t)b * KMAX, Schan, fi, b, tid, Br, Bi,
                         wPr, wPi, wNr, wNi, wQr, wQi, w5tr, w5ti, hfull, drevT, sred);
    } else {                               // N=1600, D=10, fi 22-35
        int t = bi - 1408;
        int fi = 22 + (t >> 6), b = t & 63;
        env_body<25, 6>(Xf + (size_t)b * KMAX, Schan, fi, b, tid, Br, Bi,
                        wPr, wPi, wNr, wNi, wQr, wQi, w5tr, w5ti, hfull, drevT, sred);
    }
}

// ---- K3: S0 = (x * gaussian)[::64] directly from x -----------------------
__global__ __launch_bounds__(256) void k_s0(const float* __restrict__ x,
                                            float* __restrict__ Schan){
    __shared__ float hwin[DHALF + 1];
    const int b = blockIdx.x, tid = threadIdx.x;
    for (int j = tid; j <= DHALF; j += 256){
        double st = 1.0 / (TWO_PI * (0.35 / 64.0));
        hwin[j] = (float)((0.35 / 64.0) * sqrt(TWO_PI) * exp(-0.5 * (double)(j * j) / (st * st)));
    }
    __syncthreads();
    if (tid < NOUT){
        float acc = 0.0f;
        int n = 64 * tid - DHALF; if (n < 0) n += TLEN;
        for (int d = -DHALF; d <= DHALF; ++d){
            int ad = d < 0 ? -d : d;
            acc += hwin[ad] * x[b * TLEN + n];
            ++n; if (n == TLEN) n = 0;
        }
        Schan[(b * NCH + 0) * NOUT + tid] = acc;
    }
}

// ---- K4: channel-group means -> f32 --------------------------------------
__global__ __launch_bounds__(256) void k_reduce(const float* __restrict__ Schan,
                                                float* __restrict__ out){
    int o = blockIdx.x * 256 + threadIdx.x;
    if (o >= NBATCH * 3 * NOUT) return;
    int b = o / (3 * NOUT);
    int rem = o - b * 3 * NOUT;
    int g = rem / NOUT;
    int t = rem - g * NOUT;
    int c0 = (g == 0) ? 0 : (g == 1 ? 12 : 24);
    int c1 = (g == 0) ? 12 : (g == 1 ? 24 : 37);
    float s = 0.0f;
    for (int c = c0; c < c1; ++c) s += Schan[(b * NCH + c) * NOUT + t];
    out[o] = s / (float)(c1 - c0);
}

__global__ void k_fill_f32(float* out, int n, float v){
    int i = blockIdx.x * 256 + threadIdx.x;
    if (i < n) out[i] = v;
}

extern "C" void kernel_launch(void* const* d_in, const int* in_sizes, int n_in,
                              void* d_out, int out_size, void* d_ws, size_t ws_size,
                              hipStream_t stream) {
    const float* x = (const float*)d_in[0];
    float* out = (float*)d_out;
    const size_t xf_bytes = (size_t)NBATCH * KMAX * sizeof(float2);          // 4.10 MB
    const size_t schan_bytes = (size_t)NBATCH * NCH * NOUT * sizeof(float);  // 2.37 MB
    const size_t gtmp_bytes = (size_t)NBATCH * 16000 * sizeof(float2);       // 8.19 MB
    if (ws_size < xf_bytes + schan_bytes){
        k_fill_f32<<<(out_size + 255) / 256, 256, 0, stream>>>(out, out_size, 800.0f);
        return;
    }
    float2* Xf = (float2*)d_ws;
    float* Schan = (float*)((char*)d_ws + xf_bytes);

    if (ws_size >= xf_bytes + schan_bytes + gtmp_bytes){
        float2* Gtmp = (float2*)((char*)d_ws + xf_bytes + schan_bytes);
        k_ffta<<<NBATCH * 4, 256, 0, stream>>>(x, Gtmp);
        k_fftb<<<NBATCH * 5, 256, 0, stream>>>(Gtmp, Xf);
    } else {
        k_fft<<<NBATCH, 512, 0, stream>>>(x, Xf);
    }
    k_env_all<<<2304, 512, 0, stream>>>(Xf, Schan);
    k_s0<<<NBATCH, 256, 0, stream>>>(x, Schan);
    k_reduce<<<(NBATCH * 3 * NOUT + 255) / 256, 256, 0, stream>>>(Schan, out);
}

// Round 12
// 154.546 us; speedup vs baseline: 15.4322x; 1.1469x over previous
//
#include <hip/hip_runtime.h>
#include <hip/hip_bf16.h>

#define TLEN 16000
#define NPSI 36
#define NBATCH 64
#define NOUT 250
#define NCH 37
#define DHALF 176            // Gaussian lowpass half-width (6.05 sigma, sigma_t=29.1)
#define KMAX 8000
#define TWO_PI 6.283185307179586

__device__ __forceinline__ int brev7(int q){ return (int)(__brev((unsigned)q) >> 25); }
__device__ __forceinline__ int drev125(int p){
    return (p % 5) * 25 + ((p / 5) % 5) * 5 + (p / 25);
}

// ---- K1a (split): radix-5 over n1 for 32 n2-rows + W16000 twiddle --------
__global__ __launch_bounds__(256) void k_ffta(const float* __restrict__ x,
                                              float2* __restrict__ Gtmp){
    __shared__ float xr[32 * 126], xi[32 * 126];
    __shared__ float w125r[125], w125i[125];  // e^{-2pi j/125}
    __shared__ float w16r[125],  w16i[125];   // e^{-2pi j/16000}
    __shared__ float w128r[128], w128i[128];  // e^{-2pi j/128}
    const int b = blockIdx.x >> 2, g = blockIdx.x & 3, row0 = 32 * g;
    const int tid = threadIdx.x;

    for (int j = tid; j < 125; j += 256){
        double a = -TWO_PI * (double)j / 125.0;
        w125r[j] = (float)cos(a); w125i[j] = (float)sin(a);
        double a2 = -TWO_PI * (double)j / 16000.0;
        w16r[j] = (float)cos(a2); w16i[j] = (float)sin(a2);
    }
    for (int j = tid; j < 128; j += 256){
        double a = -TWO_PI * (double)j / 128.0;
        w128r[j] = (float)cos(a); w128i[j] = (float)sin(a);
    }
    for (int i = tid; i < 32 * 125; i += 256){
        int n1 = i >> 5, lr = i & 31;
        xr[lr * 126 + n1] = x[b * TLEN + 128 * n1 + row0 + lr];
        xi[lr * 126 + n1] = 0.0f;
    }
    int f = 1;
    for (int s = 25; s >= 1; s /= 5, f *= 5){
        __syncthreads();
        for (int task = tid; task < 25 * 32; task += 256){
            int u = task >> 5, lr = task & 31;
            int blk = u / s, m = u - blk * s;
            int base = lr * 126 + blk * 5 * s + m;
            float vr[5], vi[5];
            #pragma unroll
            for (int r = 0; r < 5; ++r){ vr[r] = xr[base + r * s]; vi[r] = xi[base + r * s]; }
            #pragma unroll
            for (int q = 0; q < 5; ++q){
                float cr = vr[0], ci = vi[0];
                #pragma unroll
                for (int r = 1; r < 5; ++r){
                    int w5 = 25 * ((q * r) % 5);
                    float wr = w125r[w5], wi = w125i[w5];
                    cr += vr[r] * wr - vi[r] * wi;
                    ci += vr[r] * wi + vi[r] * wr;
                }
                int jt = (m * q * f) % 125;
                float tr = w125r[jt], ti = w125i[jt];
                xr[base + q * s] = cr * tr - ci * ti;
                xi[base + q * s] = cr * ti + ci * tr;
            }
        }
    }
    __syncthreads();
    for (int i = tid; i < 125 * 32; i += 256){
        int p = i >> 5, lr = i & 31;
        int n2 = row0 + lr;
        int m = drev125(p);
        int a = m * n2;
        int qq = a / 125, rr = a - qq * 125;
        float tr = w16r[rr] * w128r[qq] - w16i[rr] * w128i[qq];
        float ti = w16r[rr] * w128i[qq] + w16i[rr] * w128r[qq];
        float ar = xr[lr * 126 + p], ai = xi[lr * 126 + p];
        Gtmp[((size_t)b * 125 + p) * 128 + n2] =
            make_float2(ar * tr - ai * ti, ar * ti + ai * tr);
    }
}

// ---- K1b (split): radix-2 over n2 for 25 phys cols; emit k<8000 ----------
__global__ __launch_bounds__(256) void k_fftb(const float2* __restrict__ Gtmp,
                                              float2* __restrict__ Xf){
    __shared__ float gr[128 * 26], gi[128 * 26];
    __shared__ float w128r[128], w128i[128];
    const int b = blockIdx.x / 5, p0 = (blockIdx.x % 5) * 25;
    const int tid = threadIdx.x;
    for (int j = tid; j < 128; j += 256){
        double a = -TWO_PI * (double)j / 128.0;
        w128r[j] = (float)cos(a); w128i[j] = (float)sin(a);
    }
    for (int i = tid; i < 25 * 128; i += 256){
        int ml = i >> 7, n2 = i & 127;
        float2 v = Gtmp[((size_t)b * 125 + p0 + ml) * 128 + n2];
        gr[n2 * 26 + ml] = v.x; gi[n2 * 26 + ml] = v.y;
    }
    for (int span = 64; span >= 1; span >>= 1){
        __syncthreads();
        for (int idx = tid; idx < 1600; idx += 256){
            int u = idx / 25, ml = idx - u * 25;
            int blkq = u / span, mm = u % span;
            int i0 = (blkq * 2 * span + mm) * 26 + ml, i1 = i0 + span * 26;
            float ar = gr[i0], ai = gi[i0], br = gr[i1], bi = gi[i1];
            gr[i0] = ar + br; gi[i0] = ai + bi;
            float dr = ar - br, di = ai - bi;
            int jt = mm * (64 / span);
            gr[i1] = dr * w128r[jt] - di * w128i[jt];
            gi[i1] = dr * w128i[jt] + di * w128r[jt];
        }
    }
    __syncthreads();
    for (int idx = tid; idx < 1600; idx += 256){
        int u = idx / 25, ml = idx - u * 25;
        int ad = (2 * u) * 26 + ml;
        int k = drev125(p0 + ml) + 125 * brev7(2 * u);
        Xf[(size_t)b * KMAX + k] = make_float2(gr[ad], gi[ad]);
    }
}

// ---- K1 fused fallback (used only if ws too small) -----------------------
__global__ __launch_bounds__(512) void k_fft(const float* __restrict__ x,
                                             float2* __restrict__ Xf){
    __shared__ float re[128 * 126];
    __shared__ float im[128 * 126];
    __shared__ float w125r[125], w125i[125];
    __shared__ float w16r[125],  w16i[125];
    __shared__ float w128r[128], w128i[128];
    const int b = blockIdx.x, tid = threadIdx.x;

    for (int j = tid; j < 125; j += 512){
        double a = -TWO_PI * (double)j / 125.0;
        w125r[j] = (float)cos(a); w125i[j] = (float)sin(a);
        double a2 = -TWO_PI * (double)j / 16000.0;
        w16r[j] = (float)cos(a2); w16i[j] = (float)sin(a2);
    }
    for (int j = tid; j < 128; j += 512){
        double a = -TWO_PI * (double)j / 128.0;
        w128r[j] = (float)cos(a); w128i[j] = (float)sin(a);
    }
    for (int gi = tid; gi < TLEN; gi += 512){
        int n2 = gi & 127, n1 = gi >> 7;
        re[n2 * 126 + n1] = x[b * TLEN + gi];
        im[n2 * 126 + n1] = 0.0f;
    }
    int f = 1;
    for (int s = 25; s >= 1; s /= 5, f *= 5){
        __syncthreads();
        for (int task = tid; task < 25 * 128; task += 512){
            int u = task >> 7, n2 = task & 127;
            int blk = u / s, m = u - blk * s;
            int base = n2 * 126 + blk * 5 * s + m;
            float xr[5], xi5[5];
            #pragma unroll
            for (int r = 0; r < 5; ++r){ xr[r] = re[base + r * s]; xi5[r] = im[base + r * s]; }
            #pragma unroll
            for (int q = 0; q < 5; ++q){
                float cr = xr[0], ci = xi5[0];
                #pragma unroll
                for (int r = 1; r < 5; ++r){
                    int w5 = 25 * ((q * r) % 5);
                    float wr = w125r[w5], wi = w125i[w5];
                    cr += xr[r] * wr - xi5[r] * wi;
                    ci += xr[r] * wi + xi5[r] * wr;
                }
                int jt = (m * q * f) % 125;
                float tr = w125r[jt], ti = w125i[jt];
                re[base + q * s] = cr * tr - ci * ti;
                im[base + q * s] = cr * ti + ci * tr;
            }
        }
    }
    __syncthreads();
    for (int idx = tid; idx < TLEN; idx += 512){
        int n2 = idx & 127, p = idx >> 7;
        int m = drev125(p);
        int a = n2 * m;
        int qq = a / 125, rr = a - qq * 125;
        float tr = w16r[rr] * w128r[qq] - w16i[rr] * w128i[qq];
        float ti = w16r[rr] * w128i[qq] + w16i[rr] * w128r[qq];
        int ad = n2 * 126 + p;
        float ar = re[ad], ai = im[ad];
        re[ad] = ar * tr - ai * ti;
        im[ad] = ar * ti + ai * tr;
    }
    for (int span = 64; span >= 1; span >>= 1){
        __syncthreads();
        for (int idx = tid; idx < 64 * 125; idx += 512){
            int u = idx / 125, p = idx - (idx / 125) * 125;
            int blkq = u / span, mm = u % span;
            int i0 = (blkq * 2 * span + mm) * 126 + p, i1 = i0 + span * 126;
            float ar = re[i0], ai = im[i0], br = re[i1], bi = im[i1];
            re[i0] = ar + br; im[i0] = ai + bi;
            float dr = ar - br, di = ai - bi;
            int jt = mm * (64 / span);
            re[i1] = dr * w128r[jt] - di * w128i[jt];
            im[i1] = dr * w128i[jt] + di * w128r[jt];
        }
    }
    __syncthreads();
    for (int idx = tid; idx < 64 * 125; idx += 512){
        int u = idx / 125, p = idx - (idx / 125) * 125;
        int k = drev125(p) + 125 * brev7(2 * u);
        int ad = (2 * u) * 126 + p;
        Xf[(size_t)b * KMAX + k] = make_float2(re[ad], im[ad]);
    }
}

// ---- env body: radix-5 over j, twiddle, radix-2 over k2, |z| staged to
// padded-linear layout in (dead) Bi, conflict-free Gaussian conv ----------
template<int P5, int LQ>
__device__ __forceinline__ void env_body(const float2* __restrict__ Xfb,
                                         float* __restrict__ Schan,
                                         int fi, int b, int tid,
                                         float* Br, float* Bi,
                                         float* wPr, float* wPi,
                                         float* wNr, float* wNi,
                                         float* wQr, float* wQi,
                                         float* w5tr, float* w5ti,
                                         float* hfull, int* drevT, float* sred){
    constexpr int Q = 1 << LQ;
    constexpr int N = P5 * Q;
    constexpr int D = TLEN / N;
    constexpr int NIT = (N + 511) / 512;

    const double xi_d = 0.35 * exp2(-(double)fi / 6.0);
    const double r_d  = exp2(1.0 / 6.0);
    const double sig_d = xi_d * (r_d - 1.0) / (r_d + 1.0);
    const float xi = (float)xi_d;
    const float centerT = (float)(xi_d * (double)TLEN);
    const float sigT = (float)(sig_d * (double)TLEN);
    int klo = (int)floorf(centerT - 5.0f * sigT); if (klo < 1) klo = 1;
    int khi = (int)ceilf(centerT + 5.0f * sigT);  if (khi > KMAX - 1) khi = KMAX - 1;
    const float inv2s2 = (float)(1.0 / (2.0 * sig_d * sig_d));

    for (int j = tid; j < P5; j += 512){
        double a = TWO_PI * (double)j / (double)P5;
        wPr[j] = (float)cos(a); wPi[j] = (float)sin(a);
        double a2 = TWO_PI * (double)j / (double)N;
        wNr[j] = (float)cos(a2); wNi[j] = (float)sin(a2);
        drevT[j] = (P5 == 125) ? drev125(j) : ((j % 5) * 5 + j / 5);
    }
    for (int j = tid; j < Q; j += 512){
        double a = TWO_PI * (double)j / (double)Q;
        wQr[j] = (float)cos(a); wQi[j] = (float)sin(a);
    }
    for (int j = tid; j < 25; j += 512){
        double a = TWO_PI * (double)(((j / 5) * (j % 5)) % 5) / 5.0;   // e^{+2pi(qr%5)/5}
        w5tr[j] = (float)cos(a); w5ti[j] = (float)sin(a);
    }
    for (int j = tid; j <= 2 * DHALF; j += 512){
        double st = 1.0 / (TWO_PI * (0.35 / 64.0));
        double dd = (double)(j - DHALF);
        hfull[j] = (float)((0.35 / 64.0) * sqrt(TWO_PI) * exp(-0.5 * dd * dd / (st * st)));
    }
    __syncthreads();
    // init B[j][k2] = psi-weighted C[k2 + Q j]
    for (int idx = tid; idx < N; idx += 512){
        int j = idx >> LQ, k2 = idx & (Q - 1);
        int gk = k2 + (j << LQ);
        float vr = 0.0f, vi = 0.0f;
        if (gk >= klo && gk <= khi){
            float fr = (float)gk * (1.0f / (float)TLEN);
            float d = fr - xi;
            float p = __expf(-d * d * inv2s2) * (1.0f / (float)TLEN);
            float2 Xv = Xfb[gk];
            vr = Xv.x * p; vi = Xv.y * p;
        }
        Br[idx] = vr; Bi[idx] = vi;
    }
    // radix-5 DIF stages over j (plus sign); jt = m*q*f < P5 always
    int f = 1;
    for (int s = P5 / 5; s >= 1; s /= 5, f *= 5){
        __syncthreads();
        for (int task = tid; task < (P5 / 5) * Q; task += 512){
            int u = task >> LQ, k2 = task & (Q - 1);
            int blk = u / s, m = u - blk * s;
            int base = (blk * 5 * s + m) * Q + k2;
            float xr[5], xi5[5];
            #pragma unroll
            for (int r = 0; r < 5; ++r){ xr[r] = Br[base + r * s * Q]; xi5[r] = Bi[base + r * s * Q]; }
            #pragma unroll
            for (int q = 0; q < 5; ++q){
                float cr = xr[0], ci = xi5[0];
                #pragma unroll
                for (int r = 1; r < 5; ++r){
                    float wr = w5tr[q * 5 + r], wi = w5ti[q * 5 + r];
                    cr += xr[r] * wr - xi5[r] * wi;
                    ci += xr[r] * wi + xi5[r] * wr;
                }
                int jt = m * q * f;           // < P5, no mod needed
                float tr = wPr[jt], ti = wPi[jt];
                Br[base + q * s * Q] = cr * tr - ci * ti;
                Bi[base + q * s * Q] = cr * ti + ci * tr;
            }
        }
    }
    __syncthreads();
    // twiddle W_N^{+k2 n1}, n1 = drevP5(p);  a = P5*qq + rr
    for (int idx = tid; idx < N; idx += 512){
        int p = idx >> LQ, k2 = idx & (Q - 1);
        int n1 = drevT[p];
        int a = k2 * n1;
        int qq = a / P5, rr = a - qq * P5;
        float tr = wQr[qq] * wNr[rr] - wQi[qq] * wNi[rr];
        float ti = wQr[qq] * wNi[rr] + wQi[qq] * wNr[rr];
        float ar = Br[idx], ai = Bi[idx];
        Br[idx] = ar * tr - ai * ti;
        Bi[idx] = ar * ti + ai * tr;
    }
    // radix-2 DIF over k2 (plus sign), per row p
    for (int span = Q / 2; span >= 1; span >>= 1){
        __syncthreads();
        for (int idx = tid; idx < P5 * (Q / 2); idx += 512){
            int p = idx / (Q / 2), u = idx - p * (Q / 2);
            int blkq = u / span, mm = u % span;
            int i0 = p * Q + blkq * 2 * span + mm, i1 = i0 + span;
            float ar = Br[i0], ai = Bi[i0], br = Br[i1], bi = Bi[i1];
            Br[i0] = ar + br; Bi[i0] = ai + bi;
            float dr = ar - br, di = ai - bi;
            int jt = mm * ((Q / 2) / span);
            Br[i1] = dr * wQr[jt] - di * wQi[jt];
            Bi[i1] = dr * wQi[jt] + di * wQr[jt];
        }
    }
    __syncthreads();
    // |z| -> registers (Bi about to be reused as padded-linear Mag)
    float magv[NIT];
    {
        int i = 0;
        for (int idx = tid; idx < N; idx += 512, ++i){
            float vr = Br[idx], vi = Bi[idx];
            magv[i] = sqrtf(vr * vr + vi * vi);
        }
    }
    __syncthreads();
    // scatter to Bi[np + np>>5], np = drevT[p] + P5*brevQ(u)
    {
        int i = 0;
        for (int idx = tid; idx < N; idx += 512, ++i){
            int p = idx >> LQ, u = idx & (Q - 1);
            int s2 = (int)(__brev((unsigned)u) >> (32 - LQ));
            int np = drevT[p] + P5 * s2;
            Bi[np + (np >> 5)] = magv[i];
        }
    }
    __syncthreads();
    // conv: S1[t] = D * sum_n phi(64t - Dn) Mag[n], taps split 2 ways;
    // lane-adjacent reads stride (64/D)+pad -> conflict-free
    float acc = 0.0f;
    if (tid < 500){
        int t = tid - 250 * (tid / 250);
        int q = tid / 250;
        int m0 = 64 * t;
        int lo = m0 - DHALF;
        int nlo = (lo >= 0) ? ((lo + D - 1) / D) : -((-lo) / D);
        int nhi = (m0 + DHALF) / D;
        int n = nlo + q;
        if (n <= nhi){
            int np = n % N; if (np < 0) np += N;
            int d = m0 - D * n + DHALF;
            for (; n <= nhi; n += 2){
                acc += hfull[d] * Bi[np + (np >> 5)];
                d -= 2 * D;
                np += 2; if (np >= N) np -= N;
            }
        }
        sred[tid] = acc;
    }
    __syncthreads();
    if (tid < 250)
        Schan[(b * NCH + 1 + fi) * NOUT + tid] = (sred[tid] + sred[tid + 250]) * (float)D;
}

// ---- K2: all 36 filter channels + S0 in one 2368-block dispatch ----------
__global__ __launch_bounds__(512, 4) void k_env_all(const float* __restrict__ x,
                                                    const float2* __restrict__ Xf,
                                                    float* __restrict__ Schan){
    __shared__ float Br[8000];
    __shared__ float Bi[8256];                 // complex plane, then padded Mag
    __shared__ float wPr[125], wPi[125];
    __shared__ float wNr[125], wNi[125];
    __shared__ float wQr[128], wQi[128];
    __shared__ float w5tr[25], w5ti[25];
    __shared__ float hfull[2 * DHALF + 1];
    __shared__ int   drevT[125];
    __shared__ float sred[500];

    const int bi = blockIdx.x;
    const int tid = threadIdx.x;
    if (bi < 448){                         // N=8000, D=2,  fi 0-6
        int fi = bi >> 6, b = bi & 63;
        env_body<125, 6>(Xf + (size_t)b * KMAX, Schan, fi, b, tid, Br, Bi,
                         wPr, wPi, wNr, wNi, wQr, wQi, w5tr, w5ti, hfull, drevT, sred);
    } else if (bi < 640){                  // N=4000, D=4,  fi 7-9
        int t = bi - 448;
        int fi = 7 + (t >> 6), b = t & 63;
        env_body<125, 5>(Xf + (size_t)b * KMAX, Schan, fi, b, tid, Br, Bi,
                         wPr, wPi, wNr, wNi, wQr, wQi, w5tr, w5ti, hfull, drevT, sred);
    } else if (bi < 1088){                 // N=3200, D=5,  fi 10-16
        int t = bi - 640;
        int fi = 10 + (t >> 6), b = t & 63;
        env_body<25, 7>(Xf + (size_t)b * KMAX, Schan, fi, b, tid, Br, Bi,
                        wPr, wPi, wNr, wNi, wQr, wQi, w5tr, w5ti, hfull, drevT, sred);
    } else if (bi < 1408){                 // N=2000, D=8,  fi 17-21
        int t = bi - 1088;
        int fi = 17 + (t >> 6), b = t & 63;
        env_body<125, 4>(Xf + (size_t)b * KMAX, Schan, fi, b, tid, Br, Bi,
                         wPr, wPi, wNr, wNi, wQr, wQi, w5tr, w5ti, hfull, drevT, sred);
    } else if (bi < 2304){                 // N=1600, D=10, fi 22-35
        int t = bi - 1408;
        int fi = 22 + (t >> 6), b = t & 63;
        env_body<25, 6>(Xf + (size_t)b * KMAX, Schan, fi, b, tid, Br, Bi,
                        wPr, wPi, wNr, wNi, wQr, wQi, w5tr, w5ti, hfull, drevT, sred);
    } else {                               // S0 channel, one block per batch
        int b = bi - 2304;
        const float* xb = x + (size_t)b * TLEN;
        for (int j = tid; j <= 2 * DHALF; j += 512){
            double st = 1.0 / (TWO_PI * (0.35 / 64.0));
            double dd = (double)(j - DHALF);
            hfull[j] = (float)((0.35 / 64.0) * sqrt(TWO_PI) * exp(-0.5 * dd * dd / (st * st)));
        }
        __syncthreads();
        float acc = 0.0f;
        if (tid < 500){
            int t = tid - 250 * (tid / 250);
            int q = tid / 250;
            int m0 = 64 * t;
            for (int j = q; j <= 2 * DHALF; j += 2){
                int n = m0 - DHALF + j;
                if (n < 0) n += TLEN; else if (n >= TLEN) n -= TLEN;
                acc += hfull[j] * xb[n];
            }
            sred[tid] = acc;
        }
        __syncthreads();
        if (tid < 250)
            Schan[(b * NCH + 0) * NOUT + tid] = sred[tid] + sred[tid + 250];
    }
}

// ---- K4: channel-group means -> f32 --------------------------------------
__global__ __launch_bounds__(256) void k_reduce(const float* __restrict__ Schan,
                                                float* __restrict__ out){
    int o = blockIdx.x * 256 + threadIdx.x;
    if (o >= NBATCH * 3 * NOUT) return;
    int b = o / (3 * NOUT);
    int rem = o - b * 3 * NOUT;
    int g = rem / NOUT;
    int t = rem - g * NOUT;
    int c0 = (g == 0) ? 0 : (g == 1 ? 12 : 24);
    int c1 = (g == 0) ? 12 : (g == 1 ? 24 : 37);
    float s = 0.0f;
    for (int c = c0; c < c1; ++c) s += Schan[(b * NCH + c) * NOUT + t];
    out[o] = s / (float)(c1 - c0);
}

__global__ void k_fill_f32(float* out, int n, float v){
    int i = blockIdx.x * 256 + threadIdx.x;
    if (i < n) out[i] = v;
}

extern "C" void kernel_launch(void* const* d_in, const int* in_sizes, int n_in,
                              void* d_out, int out_size, void* d_ws, size_t ws_size,
                              hipStream_t stream) {
    const float* x = (const float*)d_in[0];
    float* out = (float*)d_out;
    const size_t xf_bytes = (size_t)NBATCH * KMAX * sizeof(float2);          // 4.10 MB
    const size_t schan_bytes = (size_t)NBATCH * NCH * NOUT * sizeof(float);  // 2.37 MB
    const size_t gtmp_bytes = (size_t)NBATCH * 16000 * sizeof(float2);       // 8.19 MB
    if (ws_size < xf_bytes + schan_bytes){
        k_fill_f32<<<(out_size + 255) / 256, 256, 0, stream>>>(out, out_size, 800.0f);
        return;
    }
    float2* Xf = (float2*)d_ws;
    float* Schan = (float*)((char*)d_ws + xf_bytes);

    if (ws_size >= xf_bytes + schan_bytes + gtmp_bytes){
        float2* Gtmp = (float2*)((char*)d_ws + xf_bytes + schan_bytes);
        k_ffta<<<NBATCH * 4, 256, 0, stream>>>(x, Gtmp);
        k_fftb<<<NBATCH * 5, 256, 0, stream>>>(Gtmp, Xf);
    } else {
        k_fft<<<NBATCH, 512, 0, stream>>>(x, Xf);
    }
    k_env_all<<<2368, 512, 0, stream>>>(x, Xf, Schan);
    k_reduce<<<(NBATCH * 3 * NOUT + 255) / 256, 256, 0, stream>>>(Schan, out);
}

// Round 13
// 152.648 us; speedup vs baseline: 15.6240x; 1.0124x over previous
//
#include <hip/hip_runtime.h>
#include <hip/hip_bf16.h>

#define TLEN 16000
#define NPSI 36
#define NBATCH 64
#define NOUT 250
#define NCH 37
#define DHALF 176            // Gaussian lowpass half-width (6.05 sigma, sigma_t=29.1)
#define KMAX 8000
#define TWO_PI 6.283185307179586

__device__ __forceinline__ int brev7(int q){ return (int)(__brev((unsigned)q) >> 25); }
__device__ __forceinline__ int drev125(int p){
    return (p % 5) * 25 + ((p / 5) % 5) * 5 + (p / 25);
}

// ---- K1a (split): radix-5 over n1 for 32 n2-rows + W16000 twiddle --------
__global__ __launch_bounds__(256) void k_ffta(const float* __restrict__ x,
                                              float2* __restrict__ Gtmp){
    __shared__ float xr[32 * 126], xi[32 * 126];
    __shared__ float w125r[125], w125i[125];  // e^{-2pi j/125}
    __shared__ float w16r[125],  w16i[125];   // e^{-2pi j/16000}
    __shared__ float w128r[128], w128i[128];  // e^{-2pi j/128}
    const int b = blockIdx.x >> 2, g = blockIdx.x & 3, row0 = 32 * g;
    const int tid = threadIdx.x;

    for (int j = tid; j < 125; j += 256){
        double a = -TWO_PI * (double)j / 125.0;
        w125r[j] = (float)cos(a); w125i[j] = (float)sin(a);
        double a2 = -TWO_PI * (double)j / 16000.0;
        w16r[j] = (float)cos(a2); w16i[j] = (float)sin(a2);
    }
    for (int j = tid; j < 128; j += 256){
        double a = -TWO_PI * (double)j / 128.0;
        w128r[j] = (float)cos(a); w128i[j] = (float)sin(a);
    }
    for (int i = tid; i < 32 * 125; i += 256){
        int n1 = i >> 5, lr = i & 31;
        xr[lr * 126 + n1] = x[b * TLEN + 128 * n1 + row0 + lr];
        xi[lr * 126 + n1] = 0.0f;
    }
    int f = 1;
    for (int s = 25; s >= 1; s /= 5, f *= 5){
        __syncthreads();
        for (int task = tid; task < 25 * 32; task += 256){
            int u = task >> 5, lr = task & 31;
            int blk = u / s, m = u - blk * s;
            int base = lr * 126 + blk * 5 * s + m;
            float vr[5], vi[5];
            #pragma unroll
            for (int r = 0; r < 5; ++r){ vr[r] = xr[base + r * s]; vi[r] = xi[base + r * s]; }
            #pragma unroll
            for (int q = 0; q < 5; ++q){
                float cr = vr[0], ci = vi[0];
                #pragma unroll
                for (int r = 1; r < 5; ++r){
                    int w5 = 25 * ((q * r) % 5);
                    float wr = w125r[w5], wi = w125i[w5];
                    cr += vr[r] * wr - vi[r] * wi;
                    ci += vr[r] * wi + vi[r] * wr;
                }
                int jt = (m * q * f) % 125;
                float tr = w125r[jt], ti = w125i[jt];
                xr[base + q * s] = cr * tr - ci * ti;
                xi[base + q * s] = cr * ti + ci * tr;
            }
        }
    }
    __syncthreads();
    for (int i = tid; i < 125 * 32; i += 256){
        int p = i >> 5, lr = i & 31;
        int n2 = row0 + lr;
        int m = drev125(p);
        int a = m * n2;
        int qq = a / 125, rr = a - qq * 125;
        float tr = w16r[rr] * w128r[qq] - w16i[rr] * w128i[qq];
        float ti = w16r[rr] * w128i[qq] + w16i[rr] * w128r[qq];
        float ar = xr[lr * 126 + p], ai = xi[lr * 126 + p];
        Gtmp[((size_t)b * 125 + p) * 128 + n2] =
            make_float2(ar * tr - ai * ti, ar * ti + ai * tr);
    }
}

// ---- K1b (split): radix-2 over n2 for 25 phys cols; emit k<8000 ----------
__global__ __launch_bounds__(256) void k_fftb(const float2* __restrict__ Gtmp,
                                              float2* __restrict__ Xf){
    __shared__ float gr[128 * 26], gi[128 * 26];
    __shared__ float w128r[128], w128i[128];
    const int b = blockIdx.x / 5, p0 = (blockIdx.x % 5) * 25;
    const int tid = threadIdx.x;
    for (int j = tid; j < 128; j += 256){
        double a = -TWO_PI * (double)j / 128.0;
        w128r[j] = (float)cos(a); w128i[j] = (float)sin(a);
    }
    for (int i = tid; i < 25 * 128; i += 256){
        int ml = i >> 7, n2 = i & 127;
        float2 v = Gtmp[((size_t)b * 125 + p0 + ml) * 128 + n2];
        gr[n2 * 26 + ml] = v.x; gi[n2 * 26 + ml] = v.y;
    }
    for (int span = 64; span >= 1; span >>= 1){
        __syncthreads();
        for (int idx = tid; idx < 1600; idx += 256){
            int u = idx / 25, ml = idx - u * 25;
            int blkq = u / span, mm = u % span;
            int i0 = (blkq * 2 * span + mm) * 26 + ml, i1 = i0 + span * 26;
            float ar = gr[i0], ai = gi[i0], br = gr[i1], bi = gi[i1];
            gr[i0] = ar + br; gi[i0] = ai + bi;
            float dr = ar - br, di = ai - bi;
            int jt = mm * (64 / span);
            gr[i1] = dr * w128r[jt] - di * w128i[jt];
            gi[i1] = dr * w128i[jt] + di * w128r[jt];
        }
    }
    __syncthreads();
    for (int idx = tid; idx < 1600; idx += 256){
        int u = idx / 25, ml = idx - u * 25;
        int ad = (2 * u) * 26 + ml;
        int k = drev125(p0 + ml) + 125 * brev7(2 * u);
        Xf[(size_t)b * KMAX + k] = make_float2(gr[ad], gi[ad]);
    }
}

// ---- K1 fused fallback (used only if ws too small) -----------------------
__global__ __launch_bounds__(512) void k_fft(const float* __restrict__ x,
                                             float2* __restrict__ Xf){
    __shared__ float re[128 * 126];
    __shared__ float im[128 * 126];
    __shared__ float w125r[125], w125i[125];
    __shared__ float w16r[125],  w16i[125];
    __shared__ float w128r[128], w128i[128];
    const int b = blockIdx.x, tid = threadIdx.x;

    for (int j = tid; j < 125; j += 512){
        double a = -TWO_PI * (double)j / 125.0;
        w125r[j] = (float)cos(a); w125i[j] = (float)sin(a);
        double a2 = -TWO_PI * (double)j / 16000.0;
        w16r[j] = (float)cos(a2); w16i[j] = (float)sin(a2);
    }
    for (int j = tid; j < 128; j += 512){
        double a = -TWO_PI * (double)j / 128.0;
        w128r[j] = (float)cos(a); w128i[j] = (float)sin(a);
    }
    for (int gi = tid; gi < TLEN; gi += 512){
        int n2 = gi & 127, n1 = gi >> 7;
        re[n2 * 126 + n1] = x[b * TLEN + gi];
        im[n2 * 126 + n1] = 0.0f;
    }
    int f = 1;
    for (int s = 25; s >= 1; s /= 5, f *= 5){
        __syncthreads();
        for (int task = tid; task < 25 * 128; task += 512){
            int u = task >> 7, n2 = task & 127;
            int blk = u / s, m = u - blk * s;
            int base = n2 * 126 + blk * 5 * s + m;
            float xr[5], xi5[5];
            #pragma unroll
            for (int r = 0; r < 5; ++r){ xr[r] = re[base + r * s]; xi5[r] = im[base + r * s]; }
            #pragma unroll
            for (int q = 0; q < 5; ++q){
                float cr = xr[0], ci = xi5[0];
                #pragma unroll
                for (int r = 1; r < 5; ++r){
                    int w5 = 25 * ((q * r) % 5);
                    float wr = w125r[w5], wi = w125i[w5];
                    cr += xr[r] * wr - xi5[r] * wi;
                    ci += xr[r] * wi + xi5[r] * wr;
                }
                int jt = (m * q * f) % 125;
                float tr = w125r[jt], ti = w125i[jt];
                re[base + q * s] = cr * tr - ci * ti;
                im[base + q * s] = cr * ti + ci * tr;
            }
        }
    }
    __syncthreads();
    for (int idx = tid; idx < TLEN; idx += 512){
        int n2 = idx & 127, p = idx >> 7;
        int m = drev125(p);
        int a = n2 * m;
        int qq = a / 125, rr = a - qq * 125;
        float tr = w16r[rr] * w128r[qq] - w16i[rr] * w128i[qq];
        float ti = w16r[rr] * w128i[qq] + w16i[rr] * w128r[qq];
        int ad = n2 * 126 + p;
        float ar = re[ad], ai = im[ad];
        re[ad] = ar * tr - ai * ti;
        im[ad] = ar * ti + ai * tr;
    }
    for (int span = 64; span >= 1; span >>= 1){
        __syncthreads();
        for (int idx = tid; idx < 64 * 125; idx += 512){
            int u = idx / 125, p = idx - (idx / 125) * 125;
            int blkq = u / span, mm = u % span;
            int i0 = (blkq * 2 * span + mm) * 126 + p, i1 = i0 + span * 126;
            float ar = re[i0], ai = im[i0], br = re[i1], bi = im[i1];
            re[i0] = ar + br; im[i0] = ai + bi;
            float dr = ar - br, di = ai - bi;
            int jt = mm * (64 / span);
            re[i1] = dr * w128r[jt] - di * w128i[jt];
            im[i1] = dr * w128i[jt] + di * w128r[jt];
        }
    }
    __syncthreads();
    for (int idx = tid; idx < 64 * 125; idx += 512){
        int u = idx / 125, p = idx - (idx / 125) * 125;
        int k = drev125(p) + 125 * brev7(2 * u);
        int ad = (2 * u) * 126 + p;
        Xf[(size_t)b * KMAX + k] = make_float2(re[ad], im[ad]);
    }
}

// ---- env body: radix-5 over j, twiddle, radix-2 over k2, |z| staged to
// padded-linear layout in (dead) Bi via REGISTERS (static idx), conv ------
template<int P5, int LQ>
__device__ __forceinline__ void env_body(const float2* __restrict__ Xfb,
                                         float* __restrict__ Schan,
                                         int fi, int b, int tid,
                                         float* Br, float* Bi,
                                         float* wPr, float* wPi,
                                         float* wNr, float* wNi,
                                         float* wQr, float* wQi,
                                         float* w5tr, float* w5ti,
                                         float* hfull, int* drevT, float* sred){
    constexpr int Q = 1 << LQ;
    constexpr int N = P5 * Q;
    constexpr int D = TLEN / N;
    constexpr int NIT = (N + 511) / 512;

    const double xi_d = 0.35 * exp2(-(double)fi / 6.0);
    const double r_d  = exp2(1.0 / 6.0);
    const double sig_d = xi_d * (r_d - 1.0) / (r_d + 1.0);
    const float xi = (float)xi_d;
    const float centerT = (float)(xi_d * (double)TLEN);
    const float sigT = (float)(sig_d * (double)TLEN);
    int klo = (int)floorf(centerT - 5.0f * sigT); if (klo < 1) klo = 1;
    int khi = (int)ceilf(centerT + 5.0f * sigT);  if (khi > KMAX - 1) khi = KMAX - 1;
    const float inv2s2 = (float)(1.0 / (2.0 * sig_d * sig_d));

    for (int j = tid; j < P5; j += 512){
        double a = TWO_PI * (double)j / (double)P5;
        wPr[j] = (float)cos(a); wPi[j] = (float)sin(a);
        double a2 = TWO_PI * (double)j / (double)N;
        wNr[j] = (float)cos(a2); wNi[j] = (float)sin(a2);
        drevT[j] = (P5 == 125) ? drev125(j) : ((j % 5) * 5 + j / 5);
    }
    for (int j = tid; j < Q; j += 512){
        double a = TWO_PI * (double)j / (double)Q;
        wQr[j] = (float)cos(a); wQi[j] = (float)sin(a);
    }
    for (int j = tid; j < 25; j += 512){
        double a = TWO_PI * (double)(((j / 5) * (j % 5)) % 5) / 5.0;   // e^{+2pi(qr%5)/5}
        w5tr[j] = (float)cos(a); w5ti[j] = (float)sin(a);
    }
    for (int j = tid; j <= 2 * DHALF; j += 512){
        double st = 1.0 / (TWO_PI * (0.35 / 64.0));
        double dd = (double)(j - DHALF);
        hfull[j] = (float)((0.35 / 64.0) * sqrt(TWO_PI) * exp(-0.5 * dd * dd / (st * st)));
    }
    __syncthreads();
    // init B[j][k2] = psi-weighted C[k2 + Q j]
    for (int idx = tid; idx < N; idx += 512){
        int j = idx >> LQ, k2 = idx & (Q - 1);
        int gk = k2 + (j << LQ);
        float vr = 0.0f, vi = 0.0f;
        if (gk >= klo && gk <= khi){
            float fr = (float)gk * (1.0f / (float)TLEN);
            float d = fr - xi;
            float p = __expf(-d * d * inv2s2) * (1.0f / (float)TLEN);
            float2 Xv = Xfb[gk];
            vr = Xv.x * p; vi = Xv.y * p;
        }
        Br[idx] = vr; Bi[idx] = vi;
    }
    // radix-5 DIF stages over j (plus sign); jt = m*q*f < P5 always
    int f = 1;
    for (int s = P5 / 5; s >= 1; s /= 5, f *= 5){
        __syncthreads();
        for (int task = tid; task < (P5 / 5) * Q; task += 512){
            int u = task >> LQ, k2 = task & (Q - 1);
            int blk = u / s, m = u - blk * s;
            int base = (blk * 5 * s + m) * Q + k2;
            float xr[5], xi5[5];
            #pragma unroll
            for (int r = 0; r < 5; ++r){ xr[r] = Br[base + r * s * Q]; xi5[r] = Bi[base + r * s * Q]; }
            #pragma unroll
            for (int q = 0; q < 5; ++q){
                float cr = xr[0], ci = xi5[0];
                #pragma unroll
                for (int r = 1; r < 5; ++r){
                    float wr = w5tr[q * 5 + r], wi = w5ti[q * 5 + r];
                    cr += xr[r] * wr - xi5[r] * wi;
                    ci += xr[r] * wi + xi5[r] * wr;
                }
                int jt = m * q * f;           // < P5, no mod needed
                float tr = wPr[jt], ti = wPi[jt];
                Br[base + q * s * Q] = cr * tr - ci * ti;
                Bi[base + q * s * Q] = cr * ti + ci * tr;
            }
        }
    }
    __syncthreads();
    // twiddle W_N^{+k2 n1}, n1 = drevP5(p);  a = P5*qq + rr
    for (int idx = tid; idx < N; idx += 512){
        int p = idx >> LQ, k2 = idx & (Q - 1);
        int n1 = drevT[p];
        int a = k2 * n1;
        int qq = a / P5, rr = a - qq * P5;
        float tr = wQr[qq] * wNr[rr] - wQi[qq] * wNi[rr];
        float ti = wQr[qq] * wNi[rr] + wQi[qq] * wNr[rr];
        float ar = Br[idx], ai = Bi[idx];
        Br[idx] = ar * tr - ai * ti;
        Bi[idx] = ar * ti + ai * tr;
    }
    // radix-2 DIF over k2 (plus sign), per row p
    for (int span = Q / 2; span >= 1; span >>= 1){
        __syncthreads();
        for (int idx = tid; idx < P5 * (Q / 2); idx += 512){
            int p = idx / (Q / 2), u = idx - p * (Q / 2);
            int blkq = u / span, mm = u % span;
            int i0 = p * Q + blkq * 2 * span + mm, i1 = i0 + span;
            float ar = Br[i0], ai = Bi[i0], br = Br[i1], bi = Bi[i1];
            Br[i0] = ar + br; Bi[i0] = ai + bi;
            float dr = ar - br, di = ai - bi;
            int jt = mm * ((Q / 2) / span);
            Br[i1] = dr * wQr[jt] - di * wQi[jt];
            Bi[i1] = dr * wQi[jt] + di * wQr[jt];
        }
    }
    __syncthreads();
    // |z| -> REGISTERS with compile-time indexing (no scratch spill)
    float magv[NIT];
    #pragma unroll
    for (int i = 0; i < NIT; ++i){
        int idx = tid + 512 * i;
        if (idx < N){
            float vr = Br[idx], vi = Bi[idx];
            magv[i] = sqrtf(vr * vr + vi * vi);
        }
    }
    __syncthreads();
    // scatter to Bi[np + np>>5], np = drevT[p] + P5*brevQ(u)
    #pragma unroll
    for (int i = 0; i < NIT; ++i){
        int idx = tid + 512 * i;
        if (idx < N){
            int p = idx >> LQ, u = idx & (Q - 1);
            int s2 = (int)(__brev((unsigned)u) >> (32 - LQ));
            int np = drevT[p] + P5 * s2;
            Bi[np + (np >> 5)] = magv[i];
        }
    }
    __syncthreads();
    // conv: S1[t] = D * sum_n phi(64t - Dn) Mag[n], taps split 2 ways;
    // lane-adjacent reads stride (64/D)+pad -> conflict-free
    float acc = 0.0f;
    if (tid < 500){
        int t = tid - 250 * (tid / 250);
        int q = tid / 250;
        int m0 = 64 * t;
        int lo = m0 - DHALF;
        int nlo = (lo >= 0) ? ((lo + D - 1) / D) : -((-lo) / D);
        int nhi = (m0 + DHALF) / D;
        int n = nlo + q;
        if (n <= nhi){
            int np = n % N; if (np < 0) np += N;
            int d = m0 - D * n + DHALF;
            for (; n <= nhi; n += 2){
                acc += hfull[d] * Bi[np + (np >> 5)];
                d -= 2 * D;
                np += 2; if (np >= N) np -= N;
            }
        }
        sred[tid] = acc;
    }
    __syncthreads();
    if (tid < 250)
        Schan[(b * NCH + 1 + fi) * NOUT + tid] = (sred[tid] + sred[tid + 250]) * (float)D;
}

// ---- K2: all 36 filter channels + S0 in one 2368-block dispatch ----------
__global__ __launch_bounds__(512, 4) void k_env_all(const float* __restrict__ x,
                                                    const float2* __restrict__ Xf,
                                                    float* __restrict__ Schan){
    __shared__ float Br[8000];
    __shared__ float Bi[8256];                 // complex plane, then padded Mag
    __shared__ float wPr[125], wPi[125];
    __shared__ float wNr[125], wNi[125];
    __shared__ float wQr[128], wQi[128];
    __shared__ float w5tr[25], w5ti[25];
    __shared__ float hfull[2 * DHALF + 1];
    __shared__ int   drevT[125];
    __shared__ float sred[500];

    const int bi = blockIdx.x;
    const int tid = threadIdx.x;
    if (bi < 448){                         // N=8000, D=2,  fi 0-6
        int fi = bi >> 6, b = bi & 63;
        env_body<125, 6>(Xf + (size_t)b * KMAX, Schan, fi, b, tid, Br, Bi,
                         wPr, wPi, wNr, wNi, wQr, wQi, w5tr, w5ti, hfull, drevT, sred);
    } else if (bi < 640){                  // N=4000, D=4,  fi 7-9
        int t = bi - 448;
        int fi = 7 + (t >> 6), b = t & 63;
        env_body<125, 5>(Xf + (size_t)b * KMAX, Schan, fi, b, tid, Br, Bi,
                         wPr, wPi, wNr, wNi, wQr, wQi, w5tr, w5ti, hfull, drevT, sred);
    } else if (bi < 1088){                 // N=3200, D=5,  fi 10-16
        int t = bi - 640;
        int fi = 10 + (t >> 6), b = t & 63;
        env_body<25, 7>(Xf + (size_t)b * KMAX, Schan, fi, b, tid, Br, Bi,
                        wPr, wPi, wNr, wNi, wQr, wQi, w5tr, w5ti, hfull, drevT, sred);
    } else if (bi < 1408){                 // N=2000, D=8,  fi 17-21
        int t = bi - 1088;
        int fi = 17 + (t >> 6), b = t & 63;
        env_body<125, 4>(Xf + (size_t)b * KMAX, Schan, fi, b, tid, Br, Bi,
                         wPr, wPi, wNr, wNi, wQr, wQi, w5tr, w5ti, hfull, drevT, sred);
    } else if (bi < 2304){                 // N=1600, D=10, fi 22-35
        int t = bi - 1408;
        int fi = 22 + (t >> 6), b = t & 63;
        env_body<25, 6>(Xf + (size_t)b * KMAX, Schan, fi, b, tid, Br, Bi,
                        wPr, wPi, wNr, wNi, wQr, wQi, w5tr, w5ti, hfull, drevT, sred);
    } else {                               // S0 channel, one block per batch
        int b = bi - 2304;
        const float* xb = x + (size_t)b * TLEN;
        for (int j = tid; j <= 2 * DHALF; j += 512){
            double st = 1.0 / (TWO_PI * (0.35 / 64.0));
            double dd = (double)(j - DHALF);
            hfull[j] = (float)((0.35 / 64.0) * sqrt(TWO_PI) * exp(-0.5 * dd * dd / (st * st)));
        }
        __syncthreads();
        float acc = 0.0f;
        if (tid < 500){
            int t = tid - 250 * (tid / 250);
            int q = tid / 250;
            int m0 = 64 * t;
            for (int j = q; j <= 2 * DHALF; j += 2){
                int n = m0 - DHALF + j;
                if (n < 0) n += TLEN; else if (n >= TLEN) n -= TLEN;
                acc += hfull[j] * xb[n];
            }
            sred[tid] = acc;
        }
        __syncthreads();
        if (tid < 250)
            Schan[(b * NCH + 0) * NOUT + tid] = sred[tid] + sred[tid + 250];
    }
}

// ---- K4: channel-group means -> f32 --------------------------------------
__global__ __launch_bounds__(256) void k_reduce(const float* __restrict__ Schan,
                                                float* __restrict__ out){
    int o = blockIdx.x * 256 + threadIdx.x;
    if (o >= NBATCH * 3 * NOUT) return;
    int b = o / (3 * NOUT);
    int rem = o - b * 3 * NOUT;
    int g = rem / NOUT;
    int t = rem - g * NOUT;
    int c0 = (g == 0) ? 0 : (g == 1 ? 12 : 24);
    int c1 = (g == 0) ? 12 : (g == 1 ? 24 : 37);
    float s = 0.0f;
    for (int c = c0; c < c1; ++c) s += Schan[(b * NCH + c) * NOUT + t];
    out[o] = s / (float)(c1 - c0);
}

__global__ void k_fill_f32(float* out, int n, float v){
    int i = blockIdx.x * 256 + threadIdx.x;
    if (i < n) out[i] = v;
}

extern "C" void kernel_launch(void* const* d_in, const int* in_sizes, int n_in,
                              void* d_out, int out_size, void* d_ws, size_t ws_size,
                              hipStream_t stream) {
    const float* x = (const float*)d_in[0];
    float* out = (float*)d_out;
    const size_t xf_bytes = (size_t)NBATCH * KMAX * sizeof(float2);          // 4.10 MB
    const size_t schan_bytes = (size_t)NBATCH * NCH * NOUT * sizeof(float);  // 2.37 MB
    const size_t gtmp_bytes = (size_t)NBATCH * 16000 * sizeof(float2);       // 8.19 MB
    if (ws_size < xf_bytes + schan_bytes){
        k_fill_f32<<<(out_size + 255) / 256, 256, 0, stream>>>(out, out_size, 800.0f);
        return;
    }
    float2* Xf = (float2*)d_ws;
    float* Schan = (float*)((char*)d_ws + xf_bytes);

    if (ws_size >= xf_bytes + schan_bytes + gtmp_bytes){
        float2* Gtmp = (float2*)((char*)d_ws + xf_bytes + schan_bytes);
        k_ffta<<<NBATCH * 4, 256, 0, stream>>>(x, Gtmp);
        k_fftb<<<NBATCH * 5, 256, 0, stream>>>(Gtmp, Xf);
    } else {
        k_fft<<<NBATCH, 512, 0, stream>>>(x, Xf);
    }
    k_env_all<<<2368, 512, 0, stream>>>(x, Xf, Schan);
    k_reduce<<<(NBATCH * 3 * NOUT + 255) / 256, 256, 0, stream>>>(Schan, out);
}

// Round 14
// 144.832 us; speedup vs baseline: 16.4672x; 1.0540x over previous
//
#include <hip/hip_runtime.h>
#include <hip/hip_bf16.h>

#define TLEN 16000
#define NPSI 36
#define NBATCH 64
#define NOUT 250
#define NCH 37
#define DHALF 176            // Gaussian lowpass half-width (6.05 sigma, sigma_t=29.1)
#define KMAX 8000
#define TWO_PI 6.283185307179586

__device__ __forceinline__ int brev7(int q){ return (int)(__brev((unsigned)q) >> 25); }
__device__ __forceinline__ int drev125(int p){
    return (p % 5) * 25 + ((p / 5) % 5) * 5 + (p / 25);
}

// ---- K1a (split): radix-5 over n1 for 32 n2-rows + W16000 twiddle --------
__global__ __launch_bounds__(256) void k_ffta(const float* __restrict__ x,
                                              float2* __restrict__ Gtmp){
    __shared__ float xr[32 * 126], xi[32 * 126];
    __shared__ float w125r[125], w125i[125];  // e^{-2pi j/125}
    __shared__ float w16r[125],  w16i[125];   // e^{-2pi j/16000}
    __shared__ float w128r[128], w128i[128];  // e^{-2pi j/128}
    const int b = blockIdx.x >> 2, g = blockIdx.x & 3, row0 = 32 * g;
    const int tid = threadIdx.x;

    for (int j = tid; j < 125; j += 256){
        double a = -TWO_PI * (double)j / 125.0;
        w125r[j] = (float)cos(a); w125i[j] = (float)sin(a);
        double a2 = -TWO_PI * (double)j / 16000.0;
        w16r[j] = (float)cos(a2); w16i[j] = (float)sin(a2);
    }
    for (int j = tid; j < 128; j += 256){
        double a = -TWO_PI * (double)j / 128.0;
        w128r[j] = (float)cos(a); w128i[j] = (float)sin(a);
    }
    for (int i = tid; i < 32 * 125; i += 256){
        int n1 = i >> 5, lr = i & 31;
        xr[lr * 126 + n1] = x[b * TLEN + 128 * n1 + row0 + lr];
        xi[lr * 126 + n1] = 0.0f;
    }
    int f = 1;
    for (int s = 25; s >= 1; s /= 5, f *= 5){
        __syncthreads();
        for (int task = tid; task < 25 * 32; task += 256){
            int u = task >> 5, lr = task & 31;
            int blk = u / s, m = u - blk * s;
            int base = lr * 126 + blk * 5 * s + m;
            float vr[5], vi[5];
            #pragma unroll
            for (int r = 0; r < 5; ++r){ vr[r] = xr[base + r * s]; vi[r] = xi[base + r * s]; }
            #pragma unroll
            for (int q = 0; q < 5; ++q){
                float cr = vr[0], ci = vi[0];
                #pragma unroll
                for (int r = 1; r < 5; ++r){
                    int w5 = 25 * ((q * r) % 5);
                    float wr = w125r[w5], wi = w125i[w5];
                    cr += vr[r] * wr - vi[r] * wi;
                    ci += vr[r] * wi + vi[r] * wr;
                }
                int jt = (m * q * f) % 125;
                float tr = w125r[jt], ti = w125i[jt];
                xr[base + q * s] = cr * tr - ci * ti;
                xi[base + q * s] = cr * ti + ci * tr;
            }
        }
    }
    __syncthreads();
    for (int i = tid; i < 125 * 32; i += 256){
        int p = i >> 5, lr = i & 31;
        int n2 = row0 + lr;
        int m = drev125(p);
        int a = m * n2;
        int qq = a / 125, rr = a - qq * 125;
        float tr = w16r[rr] * w128r[qq] - w16i[rr] * w128i[qq];
        float ti = w16r[rr] * w128i[qq] + w16i[rr] * w128r[qq];
        float ar = xr[lr * 126 + p], ai = xi[lr * 126 + p];
        Gtmp[((size_t)b * 125 + p) * 128 + n2] =
            make_float2(ar * tr - ai * ti, ar * ti + ai * tr);
    }
}

// ---- K1b (split): radix-2 over n2 for 25 phys cols; emit k<8000 ----------
__global__ __launch_bounds__(256) void k_fftb(const float2* __restrict__ Gtmp,
                                              float2* __restrict__ Xf){
    __shared__ float gr[128 * 26], gi[128 * 26];
    __shared__ float w128r[128], w128i[128];
    const int b = blockIdx.x / 5, p0 = (blockIdx.x % 5) * 25;
    const int tid = threadIdx.x;
    for (int j = tid; j < 128; j += 256){
        double a = -TWO_PI * (double)j / 128.0;
        w128r[j] = (float)cos(a); w128i[j] = (float)sin(a);
    }
    for (int i = tid; i < 25 * 128; i += 256){
        int ml = i >> 7, n2 = i & 127;
        float2 v = Gtmp[((size_t)b * 125 + p0 + ml) * 128 + n2];
        gr[n2 * 26 + ml] = v.x; gi[n2 * 26 + ml] = v.y;
    }
    for (int span = 64; span >= 1; span >>= 1){
        __syncthreads();
        for (int idx = tid; idx < 1600; idx += 256){
            int u = idx / 25, ml = idx - u * 25;
            int blkq = u / span, mm = u % span;
            int i0 = (blkq * 2 * span + mm) * 26 + ml, i1 = i0 + span * 26;
            float ar = gr[i0], ai = gi[i0], br = gr[i1], bi = gi[i1];
            gr[i0] = ar + br; gi[i0] = ai + bi;
            float dr = ar - br, di = ai - bi;
            int jt = mm * (64 / span);
            gr[i1] = dr * w128r[jt] - di * w128i[jt];
            gi[i1] = dr * w128i[jt] + di * w128r[jt];
        }
    }
    __syncthreads();
    for (int idx = tid; idx < 1600; idx += 256){
        int u = idx / 25, ml = idx - u * 25;
        int ad = (2 * u) * 26 + ml;
        int k = drev125(p0 + ml) + 125 * brev7(2 * u);
        Xf[(size_t)b * KMAX + k] = make_float2(gr[ad], gi[ad]);
    }
}

// ---- env body: fused init+radix-5, fused twiddle, radix-4 over k2, |z|
// staged to padded-linear Bi, conflict-free Gaussian conv ------------------
template<int P5, int LQ>
__device__ __forceinline__ void env_body(const float2* __restrict__ Xfb,
                                         float* __restrict__ Schan,
                                         int fi, int b, int tid,
                                         float* Br, float* Bi,
                                         float* wPr, float* wPi,
                                         float* wNr, float* wNi,
                                         float* wQr, float* wQi,
                                         float* w5tr, float* w5ti,
                                         float* hfull, int* drevT, float* sred){
    constexpr int Q = 1 << LQ;
    constexpr int N = P5 * Q;
    constexpr int D = TLEN / N;
    constexpr int S1 = P5 / 5;
    constexpr int NIT = (N + 511) / 512;

    const double xi_d = 0.35 * exp2(-(double)fi / 6.0);
    const double r_d  = exp2(1.0 / 6.0);
    const double sig_d = xi_d * (r_d - 1.0) / (r_d + 1.0);
    const float xi = (float)xi_d;
    const float centerT = (float)(xi_d * (double)TLEN);
    const float sigT = (float)(sig_d * (double)TLEN);
    int klo = (int)floorf(centerT - 5.0f * sigT); if (klo < 1) klo = 1;
    int khi = (int)ceilf(centerT + 5.0f * sigT);  if (khi > KMAX - 1) khi = KMAX - 1;
    const float inv2s2 = (float)(1.0 / (2.0 * sig_d * sig_d));

    for (int j = tid; j < P5; j += 512){
        double a = TWO_PI * (double)j / (double)P5;
        wPr[j] = (float)cos(a); wPi[j] = (float)sin(a);
        double a2 = TWO_PI * (double)j / (double)N;
        wNr[j] = (float)cos(a2); wNi[j] = (float)sin(a2);
        drevT[j] = (P5 == 125) ? drev125(j) : ((j % 5) * 5 + j / 5);
    }
    for (int j = tid; j < Q; j += 512){
        double a = TWO_PI * (double)j / (double)Q;
        wQr[j] = (float)cos(a); wQi[j] = (float)sin(a);
    }
    for (int j = tid; j < 25; j += 512){
        double a = TWO_PI * (double)(((j / 5) * (j % 5)) % 5) / 5.0;   // e^{+2pi(qr%5)/5}
        w5tr[j] = (float)cos(a); w5ti[j] = (float)sin(a);
    }
    for (int j = tid; j <= 2 * DHALF; j += 512){
        double st = 1.0 / (TWO_PI * (0.35 / 64.0));
        double dd = (double)(j - DHALF);
        hfull[j] = (float)((0.35 / 64.0) * sqrt(TWO_PI) * exp(-0.5 * dd * dd / (st * st)));
    }
    __syncthreads();
    // ---- radix-5 stage 1 over j, FUSED with global init (blk=0, f=1):
    // rows m + r*S1; inputs = psi-weighted Xf, straight from L2 -----------
    for (int task = tid; task < S1 * Q; task += 512){
        int m = task >> LQ, k2 = task & (Q - 1);
        float vr[5], vi[5];
        #pragma unroll
        for (int r = 0; r < 5; ++r){
            int gk = k2 + ((m + r * S1) << LQ);
            float ur = 0.0f, ui = 0.0f;
            if (gk >= klo && gk <= khi){
                float fr = (float)gk * (1.0f / (float)TLEN);
                float d = fr - xi;
                float p = __expf(-d * d * inv2s2) * (1.0f / (float)TLEN);
                float2 Xv = Xfb[gk];
                ur = Xv.x * p; ui = Xv.y * p;
            }
            vr[r] = ur; vi[r] = ui;
        }
        int base = m * Q + k2;
        #pragma unroll
        for (int q = 0; q < 5; ++q){
            float cr = vr[0], ci = vi[0];
            #pragma unroll
            for (int r = 1; r < 5; ++r){
                float wr = w5tr[q * 5 + r], wi = w5ti[q * 5 + r];
                cr += vr[r] * wr - vi[r] * wi;
                ci += vr[r] * wi + vi[r] * wr;
            }
            int jt = m * q;                   // f = 1
            float tr = wPr[jt], ti = wPi[jt];
            Br[base + q * S1 * Q] = cr * tr - ci * ti;
            Bi[base + q * S1 * Q] = cr * ti + ci * tr;
        }
    }
    // ---- middle radix-5 stage (P5=125 only): s=5, f=5 --------------------
    if (P5 == 125){
        __syncthreads();
        for (int task = tid; task < 25 * Q; task += 512){
            int u = task >> LQ, k2 = task & (Q - 1);
            int blk = u / 5, m = u - blk * 5;
            int base = (blk * 25 + m) * Q + k2;
            float vr[5], vi[5];
            #pragma unroll
            for (int r = 0; r < 5; ++r){ vr[r] = Br[base + r * 5 * Q]; vi[r] = Bi[base + r * 5 * Q]; }
            #pragma unroll
            for (int q = 0; q < 5; ++q){
                float cr = vr[0], ci = vi[0];
                #pragma unroll
                for (int r = 1; r < 5; ++r){
                    float wr = w5tr[q * 5 + r], wi = w5ti[q * 5 + r];
                    cr += vr[r] * wr - vi[r] * wi;
                    ci += vr[r] * wi + vi[r] * wr;
                }
                int jt = m * q * 5;           // < 125
                float tr = wPr[jt], ti = wPi[jt];
                Br[base + q * 5 * Q] = cr * tr - ci * ti;
                Bi[base + q * 5 * Q] = cr * ti + ci * tr;
            }
        }
    }
    // ---- final radix-5 stage (s=1, m=0 -> no stage twiddle), FUSED with
    // W_N^{+k2 n1} output twiddle (n1 = drevT[row]) ------------------------
    __syncthreads();
    for (int task = tid; task < S1 * Q; task += 512){
        int u = task >> LQ, k2 = task & (Q - 1);
        int base = (u * 5) * Q + k2;
        float vr[5], vi[5];
        #pragma unroll
        for (int r = 0; r < 5; ++r){ vr[r] = Br[base + r * Q]; vi[r] = Bi[base + r * Q]; }
        #pragma unroll
        for (int q = 0; q < 5; ++q){
            float cr = vr[0], ci = vi[0];
            #pragma unroll
            for (int r = 1; r < 5; ++r){
                float wr = w5tr[q * 5 + r], wi = w5ti[q * 5 + r];
                cr += vr[r] * wr - vi[r] * wi;
                ci += vr[r] * wi + vi[r] * wr;
            }
            int n1 = drevT[5 * u + q];
            int a = k2 * n1;                  // < N = P5*qq + rr
            int qq = a / P5, rr = a - qq * P5;
            float tr = wQr[qq] * wNr[rr] - wQi[qq] * wNi[rr];
            float ti = wQr[qq] * wNi[rr] + wQi[qq] * wNr[rr];
            Br[base + q * Q] = cr * tr - ci * ti;
            Bi[base + q * Q] = cr * ti + ci * tr;
        }
    }
    // ---- radix-4 passes over k2 (fused radix-2 pairs, plus sign) ---------
    #pragma unroll
    for (int pass = 0; pass < LQ / 2; ++pass){
        const int Sp = Q >> (1 + 2 * pass);   // spans (Sp, Sp/2)
        const int half = Sp >> 1;
        __syncthreads();
        for (int task = tid; task < P5 * (Q / 4); task += 512){
            int prow = task / (Q / 4), v = task & (Q / 4 - 1);
            int blkq = v / half, m = v - blkq * half;
            int base = prow * Q + blkq * 2 * Sp + m;
            float Ar = Br[base],           Ai = Bi[base];
            float B2r = Br[base + half],   B2i = Bi[base + half];
            float Cr = Br[base + Sp],      Ci = Bi[base + Sp];
            float D2r = Br[base + Sp + half], D2i = Bi[base + Sp + half];
            int jt1 = m * ((Q / 2) / Sp);
            float w1r = wQr[jt1], w1i = wQi[jt1];
            float w2r = wQr[2 * jt1], w2i = wQi[2 * jt1];
            // stage 1 (span Sp): (A,C) twiddle W1; (B,D) twiddle W1*i
            float A1r = Ar + Cr, A1i = Ai + Ci;
            float t1r = Ar - Cr, t1i = Ai - Ci;
            float C1r = t1r * w1r - t1i * w1i, C1i = t1r * w1i + t1i * w1r;
            float B1r = B2r + D2r, B1i = B2i + D2i;
            float t2r = B2r - D2r, t2i = B2i - D2i;
            float t3r = -t2i, t3i = t2r;      // * i (plus sign)
            float D1r = t3r * w1r - t3i * w1i, D1i = t3r * w1i + t3i * w1r;
            // stage 2 (span Sp/2): twiddle W2 = W^{2 jt1}
            Br[base] = A1r + B1r;  Bi[base] = A1i + B1i;
            float u1r = A1r - B1r, u1i = A1i - B1i;
            Br[base + half] = u1r * w2r - u1i * w2i;
            Bi[base + half] = u1r * w2i + u1i * w2r;
            Br[base + Sp] = C1r + D1r;  Bi[base + Sp] = C1i + D1i;
            float u2r = C1r - D1r, u2i = C1i - D1i;
            Br[base + Sp + half] = u2r * w2r - u2i * w2i;
            Bi[base + Sp + half] = u2r * w2i + u2i * w2r;
        }
    }
    if (LQ & 1){                              // leftover span=1 radix-2 (W=1)
        __syncthreads();
        for (int idx = tid; idx < P5 * (Q / 2); idx += 512){
            int p = idx / (Q / 2), u = idx - p * (Q / 2);
            int i0 = p * Q + 2 * u, i1 = i0 + 1;
            float ar = Br[i0], ai = Bi[i0], br2 = Br[i1], bi2 = Bi[i1];
            Br[i0] = ar + br2; Bi[i0] = ai + bi2;
            Br[i1] = ar - br2; Bi[i1] = ai - bi2;
        }
    }
    __syncthreads();
    // ---- |z| -> registers (static idx), then padded-linear scatter to Bi -
    float magv[NIT];
    #pragma unroll
    for (int i = 0; i < NIT; ++i){
        int idx = tid + 512 * i;
        if (idx < N){
            float vr = Br[idx], vi = Bi[idx];
            magv[i] = sqrtf(vr * vr + vi * vi);
        }
    }
    __syncthreads();
    #pragma unroll
    for (int i = 0; i < NIT; ++i){
        int idx = tid + 512 * i;
        if (idx < N){
            int p = idx >> LQ, u = idx & (Q - 1);
            int s2 = (int)(__brev((unsigned)u) >> (32 - LQ));
            int np = drevT[p] + P5 * s2;
            Bi[np + (np >> 5)] = magv[i];
        }
    }
    __syncthreads();
    // ---- conv: S1[t] = D * sum_n phi(64t - Dn) Mag[n], 2-way tap split ---
    float acc = 0.0f;
    if (tid < 500){
        int t = tid - 250 * (tid / 250);
        int q = tid / 250;
        int m0 = 64 * t;
        int lo = m0 - DHALF;
        int nlo = (lo >= 0) ? ((lo + D - 1) / D) : -((-lo) / D);
        int nhi = (m0 + DHALF) / D;
        int n = nlo + q;
        if (n <= nhi){
            int np = n % N; if (np < 0) np += N;
            int d = m0 - D * n + DHALF;
            for (; n <= nhi; n += 2){
                acc += hfull[d] * Bi[np + (np >> 5)];
                d -= 2 * D;
                np += 2; if (np >= N) np -= N;
            }
        }
        sred[tid] = acc;
    }
    __syncthreads();
    if (tid < 250)
        Schan[(b * NCH + 1 + fi) * NOUT + tid] = (sred[tid] + sred[tid + 250]) * (float)D;
}

// ---- K2: all 36 filter channels + S0 in one 2368-block dispatch ----------
__global__ __launch_bounds__(512, 4) void k_env_all(const float* __restrict__ x,
                                                    const float2* __restrict__ Xf,
                                                    float* __restrict__ Schan){
    __shared__ float Br[8000];
    __shared__ float Bi[8256];                 // complex plane, then padded Mag
    __shared__ float wPr[125], wPi[125];
    __shared__ float wNr[125], wNi[125];
    __shared__ float wQr[128], wQi[128];
    __shared__ float w5tr[25], w5ti[25];
    __shared__ float hfull[2 * DHALF + 1];
    __shared__ int   drevT[125];
    __shared__ float sred[500];

    const int bi = blockIdx.x;
    const int tid = threadIdx.x;
    if (bi < 448){                         // N=8000, D=2,  fi 0-6
        int fi = bi >> 6, b = bi & 63;
        env_body<125, 6>(Xf + (size_t)b * KMAX, Schan, fi, b, tid, Br, Bi,
                         wPr, wPi, wNr, wNi, wQr, wQi, w5tr, w5ti, hfull, drevT, sred);
    } else if (bi < 640){                  // N=4000, D=4,  fi 7-9
        int t = bi - 448;
        int fi = 7 + (t >> 6), b = t & 63;
        env_body<125, 5>(Xf + (size_t)b * KMAX, Schan, fi, b, tid, Br, Bi,
                         wPr, wPi, wNr, wNi, wQr, wQi, w5tr, w5ti, hfull, drevT, sred);
    } else if (bi < 1088){                 // N=3200, D=5,  fi 10-16
        int t = bi - 640;
        int fi = 10 + (t >> 6), b = t & 63;
        env_body<25, 7>(Xf + (size_t)b * KMAX, Schan, fi, b, tid, Br, Bi,
                        wPr, wPi, wNr, wNi, wQr, wQi, w5tr, w5ti, hfull, drevT, sred);
    } else if (bi < 1408){                 // N=2000, D=8,  fi 17-21
        int t = bi - 1088;
        int fi = 17 + (t >> 6), b = t & 63;
        env_body<125, 4>(Xf + (size_t)b * KMAX, Schan, fi, b, tid, Br, Bi,
                         wPr, wPi, wNr, wNi, wQr, wQi, w5tr, w5ti, hfull, drevT, sred);
    } else if (bi < 2304){                 // N=1600, D=10, fi 22-35
        int t = bi - 1408;
        int fi = 22 + (t >> 6), b = t & 63;
        env_body<25, 6>(Xf + (size_t)b * KMAX, Schan, fi, b, tid, Br, Bi,
                        wPr, wPi, wNr, wNi, wQr, wQi, w5tr, w5ti, hfull, drevT, sred);
    } else {                               // S0 channel, one block per batch
        int b = bi - 2304;
        const float* xb = x + (size_t)b * TLEN;
        for (int j = tid; j <= 2 * DHALF; j += 512){
            double st = 1.0 / (TWO_PI * (0.35 / 64.0));
            double dd = (double)(j - DHALF);
            hfull[j] = (float)((0.35 / 64.0) * sqrt(TWO_PI) * exp(-0.5 * dd * dd / (st * st)));
        }
        __syncthreads();
        float acc = 0.0f;
        if (tid < 500){
            int t = tid - 250 * (tid / 250);
            int q = tid / 250;
            int m0 = 64 * t;
            for (int j = q; j <= 2 * DHALF; j += 2){
                int n = m0 - DHALF + j;
                if (n < 0) n += TLEN; else if (n >= TLEN) n -= TLEN;
                acc += hfull[j] * xb[n];
            }
            sred[tid] = acc;
        }
        __syncthreads();
        if (tid < 250)
            Schan[(b * NCH + 0) * NOUT + tid] = sred[tid] + sred[tid + 250];
    }
}

// ---- K4: channel-group means -> f32 --------------------------------------
__global__ __launch_bounds__(256) void k_reduce(const float* __restrict__ Schan,
                                                float* __restrict__ out){
    int o = blockIdx.x * 256 + threadIdx.x;
    if (o >= NBATCH * 3 * NOUT) return;
    int b = o / (3 * NOUT);
    int rem = o - b * 3 * NOUT;
    int g = rem / NOUT;
    int t = rem - g * NOUT;
    int c0 = (g == 0) ? 0 : (g == 1 ? 12 : 24);
    int c1 = (g == 0) ? 12 : (g == 1 ? 24 : 37);
    float s = 0.0f;
    for (int c = c0; c < c1; ++c) s += Schan[(b * NCH + c) * NOUT + t];
    out[o] = s / (float)(c1 - c0);
}

__global__ void k_fill_f32(float* out, int n, float v){
    int i = blockIdx.x * 256 + threadIdx.x;
    if (i < n) out[i] = v;
}

extern "C" void kernel_launch(void* const* d_in, const int* in_sizes, int n_in,
                              void* d_out, int out_size, void* d_ws, size_t ws_size,
                              hipStream_t stream) {
    const float* x = (const float*)d_in[0];
    float* out = (float*)d_out;
    const size_t xf_bytes = (size_t)NBATCH * KMAX * sizeof(float2);          // 4.10 MB
    const size_t schan_bytes = (size_t)NBATCH * NCH * NOUT * sizeof(float);  // 2.37 MB
    const size_t gtmp_bytes = (size_t)NBATCH * 16000 * sizeof(float2);       // 8.19 MB
    if (ws_size < xf_bytes + schan_bytes + gtmp_bytes){
        k_fill_f32<<<(out_size + 255) / 256, 256, 0, stream>>>(out, out_size, 800.0f);
        return;
    }
    float2* Xf = (float2*)d_ws;
    float* Schan = (float*)((char*)d_ws + xf_bytes);
    float2* Gtmp = (float2*)((char*)d_ws + xf_bytes + schan_bytes);

    k_ffta<<<NBATCH * 4, 256, 0, stream>>>(x, Gtmp);
    k_fftb<<<NBATCH * 5, 256, 0, stream>>>(Gtmp, Xf);
    k_env_all<<<2368, 512, 0, stream>>>(x, Xf, Schan);
    k_reduce<<<(NBATCH * 3 * NOUT + 255) / 256, 256, 0, stream>>>(Schan, out);
}